// Round 1
// baseline (397.585 us; speedup 1.0000x reference)
//
#include <hip/hip_runtime.h>
#include <math.h>

// Problem constants
constexpr int BSZ   = 16;
constexpr int NDET  = 48;
constexpr int PAIRS = NDET * (NDET - 1);      // 2256
constexpr int ROWS  = BSZ * PAIRS;            // 36096
constexpr int DF    = 2048;
constexpr int DH    = 1024;
constexpr int DE    = 512;
constexpr int EHALF = 256;
constexpr int NCLS  = 92;
constexpr int NEXT  = DE + 128;               // 640: valid so/re width incl. classifier cols
constexpr int NPAD  = 768;                    // 256-tile-padded B rows for so/re GEMM
constexpr int LABW  = 1 + 92 + 40;            // 133

typedef __attribute__((ext_vector_type(8))) short bf16x8;   // 8 bf16 in 4 VGPRs
typedef __attribute__((ext_vector_type(4))) float f32x4;

__device__ __forceinline__ short f2bf(float f) {
    union { float f; unsigned u; } a; a.f = f;
    unsigned r = a.u + 0x7fffu + ((a.u >> 16) & 1u);   // RNE
    return (short)(r >> 16);
}
__device__ __forceinline__ float bf2f(short h) {
    union { unsigned u; float f; } x;
    x.u = ((unsigned)(unsigned short)h) << 16;
    return x.f;
}

// ---------------------------------------------------------------------------
// Merged prep. Elementwise ranges: det conv | cwt build | W3->bf16 | R2->bf16;
// then 5-job transpose (W1 top/bot, W2, W3, R2).
// ---------------------------------------------------------------------------
constexpr int N4DET = BSZ * NDET * DF / 4;    // 393216
constexpr int N4CWT = 128 * DE / 4;           // 16384
constexpr int N4W3  = DH * DE / 4;            // 131072
constexpr int N4R2  = 256 * DE / 4;           // 32768
constexpr int NCONVB = (N4DET + N4CWT + N4W3 + N4R2) / 256;   // 2240

struct TransJobs {
    const float* src[5];
    short*       dst[5];
    int K[5], N[5];
    int cum[6];
};

__global__ __launch_bounds__(256) void prep_kernel(
    const float* __restrict__ det, short* __restrict__ det_bf,
    const float* __restrict__ cw, short* __restrict__ cwt,
    const float* __restrict__ W3, short* __restrict__ W3bf,
    const float* __restrict__ R2, short* __restrict__ R2bf,
    TransJobs jobs)
{
    if (blockIdx.x < NCONVB) {
        int i = blockIdx.x * 256 + threadIdx.x;
        const float* src; short* dst; int k;
        if (i < N4DET) { src = det; dst = det_bf; k = i; }
        else if (i < N4DET + N4CWT) {
            k = i - N4DET;
            int n = (k * 4) >> 9;
            short4 o = {0, 0, 0, 0};
            if (n < NCLS) {
                float4 v = ((const float4*)cw)[k];
                o.x = f2bf(v.x); o.y = f2bf(v.y); o.z = f2bf(v.z); o.w = f2bf(v.w);
            }
            ((short4*)cwt)[k] = o;
            return;
        }
        else if (i < N4DET + N4CWT + N4W3) { src = W3; dst = W3bf; k = i - N4DET - N4CWT; }
        else { src = R2; dst = R2bf; k = i - N4DET - N4CWT - N4W3; }
        float4 v = ((const float4*)src)[k];
        short4 o;
        o.x = f2bf(v.x); o.y = f2bf(v.y); o.z = f2bf(v.z); o.w = f2bf(v.w);
        ((short4*)dst)[k] = o;
        return;
    }
    __shared__ float tile[32][33];
    int t = blockIdx.x - NCONVB;
    int j = 0;
    while (t >= jobs.cum[j + 1]) ++j;
    int lt = t - jobs.cum[j];
    int K = jobs.K[j], N = jobs.N[j];
    int nx = N >> 5;
    int ky = lt / nx, nxi = lt - ky * nx;
    int n0 = nxi * 32, k0 = ky * 32;
    const float* src = jobs.src[j];
    short* dst = jobs.dst[j];
    int tx = threadIdx.x & 31, ty = threadIdx.x >> 5;
#pragma unroll
    for (int i = ty; i < 32; i += 8)
        tile[i][tx] = src[(size_t)(k0 + i) * N + n0 + tx];
    __syncthreads();
#pragma unroll
    for (int i = ty; i < 32; i += 8)
        dst[(size_t)(n0 + i) * K + k0 + tx] = f2bf(tile[tx][i]);
}

__device__ __forceinline__ void load16_lds(const void* g, void* l) {
    __builtin_amdgcn_global_load_lds(
        (const __attribute__((address_space(1))) unsigned int*)g,
        (__attribute__((address_space(3))) unsigned int*)l, 16, 0, 0);
}

#define MFMA16 __builtin_amdgcn_mfma_f32_16x16x32_bf16

// ---------------------------------------------------------------------------
// R14: 256x256x64 8-phase GEMM (plain-HIP port of the m201 template).
//  - 512 thr / 8 waves (2Mx4N), interleaved fragment map:
//      row(fm) = (fm*2 + wr)*16, col(fn) = (fn*4 + wc)*16
//    so A/B half-tiles (128 contiguous rows) line up with phase liveness.
//  - LDS 128KiB: 2 buffers x (A 256x64 | B 256x64) bf16.
//  - XOR-swizzle: 16B-chunk index ^= (row&7); applied BOTH on the
//    global_load_lds source chunk and the ds_read address (linear LDS dest).
//  - Per K-tile 4 phases: {ds_read subtile; stage 1 half-tile; bar;
//    lgkmcnt(0); setprio(1); 16 MFMA; setprio(0); bar}. Half-tile issue
//    order A-lo,B-lo,B-hi,A-hi matches register-holding liveness
//    (af held p0-p1, bq0 held p0-p2, bq1 held p1-p3).
//  - Counted s_waitcnt vmcnt(6) once per K-tile (phase 3); vmcnt(0) only
//    at tile NT-2; nothing at NT-1.
// ---------------------------------------------------------------------------
template <bool BIAS, bool RELU, bool DUAL>
__global__ __launch_bounds__(512, 2) void gemm256(
    const short* __restrict__ A, const short* __restrict__ Bt,
    const float* __restrict__ bias, short* __restrict__ C,
    int M, int NV, int K, int lda, int ldb, int ntn, int nsplit,
    const short* A2, const short* Bt2, short* C2,
    int M2, int NV2, int K2, int lda2, int ldb2, int ntn2)
{
    __shared__ __align__(16) short smem[2 * 32768];   // 128 KiB

    int bid = blockIdx.x;
    if (DUAL && bid >= nsplit) {
        bid -= nsplit;
        A = A2; Bt = Bt2; C = C2;
        M = M2; NV = NV2; K = K2; lda = lda2; ldb = ldb2; ntn = ntn2;
    }
    const int by = bid / ntn;
    const int bx = bid - by * ntn;
    const int m0 = by * 256;
    const int n0 = bx * 256;

    const int tid  = threadIdx.x;
    const int wid  = tid >> 6;
    const int lane = tid & 63;
    const int wr = wid >> 2;
    const int wc = wid & 3;
    const int q  = lane >> 4;
    const int lm = lane & 15;

    // staging: wave w stages 8 rows/call; lane l -> row w*8+(l>>3),
    // dest chunk l&7, source chunk (l&7)^((l>>3)&7)  (inverse swizzle)
    const int rowoff = wid * 8 + ((tid & 63) >> 3);
    const int cs8    = ((tid & 7) ^ ((tid >> 3) & 7)) * 8;
    // ds_read swizzled k-chunk offsets (shorts): chunk (s*4+q) ^ (row&7)
    const int kc0 = ((q)     ^ (lm & 7)) * 8;
    const int kc1 = ((4 + q) ^ (lm & 7)) * 8;
    const int NT  = K >> 6;
    const int Mm1 = M - 1;

    auto stA = [&](int buf, int r0, int kt) {
        int gm = m0 + r0 + rowoff; if (gm > Mm1) gm = Mm1;
        load16_lds(A + (size_t)gm * lda + kt * 64 + cs8,
                   smem + buf * 32768 + (r0 + wid * 8) * 64);
    };
    auto stB = [&](int buf, int r0, int kt) {
        int gn = n0 + r0 + rowoff;                 // B rows padded: no clamp
        load16_lds(Bt + (size_t)gn * ldb + kt * 64 + cs8,
                   smem + buf * 32768 + 16384 + (r0 + wid * 8) * 64);
    };

    // prologue: tile0 (A-lo,B-lo,B-hi,A-hi) + tile1 (A-lo,B-lo,B-hi)
    stA(0, 0, 0);   stA(0, 64, 0);
    stB(0, 0, 0);   stB(0, 64, 0);
    stB(0, 128, 0); stB(0, 192, 0);
    stA(0, 128, 0); stA(0, 192, 0);
    if (NT > 1) {
        stA(1, 0, 1);   stA(1, 64, 1);
        stB(1, 0, 1);   stB(1, 64, 1);
        stB(1, 128, 1); stB(1, 192, 1);
        asm volatile("s_waitcnt vmcnt(6)" ::: "memory");   // tile0 complete
    } else {
        asm volatile("s_waitcnt vmcnt(0)" ::: "memory");
    }
    __builtin_amdgcn_s_barrier();

    f32x4 acc[8][4] = {};
    bf16x8 af[4][2], bq0[2][2], bq1[2][2];

    for (int t = 0; t < NT; ++t) {
        const short* Ab = smem + (t & 1) * 32768;
        const short* Bb = Ab + 16384;
        const int bufc = t & 1, bufn = bufc ^ 1;
        const bool s1 = (t + 1 < NT);
        const bool s2 = (t + 2 < NT);

        // ---- phase 0: read af(qa0)+bq0(qb0); stage A-hi of t+1 ----
#pragma unroll
        for (int i = 0; i < 4; ++i) {
            const short* r = Ab + ((i * 2 + wr) * 16 + lm) * 64;
            af[i][0] = *(const bf16x8*)(r + kc0);
            af[i][1] = *(const bf16x8*)(r + kc1);
        }
#pragma unroll
        for (int j = 0; j < 2; ++j) {
            const short* r = Bb + ((j * 4 + wc) * 16 + lm) * 64;
            bq0[j][0] = *(const bf16x8*)(r + kc0);
            bq0[j][1] = *(const bf16x8*)(r + kc1);
        }
        if (s1) { stA(bufn, 128, t + 1); stA(bufn, 192, t + 1); }
        __builtin_amdgcn_s_barrier();
        asm volatile("s_waitcnt lgkmcnt(0)");
        __builtin_amdgcn_s_setprio(1);
#pragma unroll
        for (int i = 0; i < 4; ++i)
#pragma unroll
            for (int j = 0; j < 2; ++j) {
                acc[i][j] = MFMA16(af[i][0], bq0[j][0], acc[i][j], 0, 0, 0);
                acc[i][j] = MFMA16(af[i][1], bq0[j][1], acc[i][j], 0, 0, 0);
            }
        __builtin_amdgcn_s_setprio(0);
        __builtin_amdgcn_s_barrier();

        // ---- phase 1: read bq1(qb1); stage A-lo of t+2 (A-lo dead) ----
#pragma unroll
        for (int j = 0; j < 2; ++j) {
            const short* r = Bb + (((j + 2) * 4 + wc) * 16 + lm) * 64;
            bq1[j][0] = *(const bf16x8*)(r + kc0);
            bq1[j][1] = *(const bf16x8*)(r + kc1);
        }
        if (s2) { stA(bufc, 0, t + 2); stA(bufc, 64, t + 2); }
        __builtin_amdgcn_s_barrier();
        asm volatile("s_waitcnt lgkmcnt(0)");
        __builtin_amdgcn_s_setprio(1);
#pragma unroll
        for (int i = 0; i < 4; ++i)
#pragma unroll
            for (int j = 0; j < 2; ++j) {
                acc[i][j + 2] = MFMA16(af[i][0], bq1[j][0], acc[i][j + 2], 0, 0, 0);
                acc[i][j + 2] = MFMA16(af[i][1], bq1[j][1], acc[i][j + 2], 0, 0, 0);
            }
        __builtin_amdgcn_s_setprio(0);
        __builtin_amdgcn_s_barrier();

        // ---- phase 2: read af(qa1); stage B-lo of t+2 (B-lo dead) ----
#pragma unroll
        for (int i = 0; i < 4; ++i) {
            const short* r = Ab + (((i + 4) * 2 + wr) * 16 + lm) * 64;
            af[i][0] = *(const bf16x8*)(r + kc0);
            af[i][1] = *(const bf16x8*)(r + kc1);
        }
        if (s2) { stB(bufc, 0, t + 2); stB(bufc, 64, t + 2); }
        __builtin_amdgcn_s_barrier();
        asm volatile("s_waitcnt lgkmcnt(0)");
        __builtin_amdgcn_s_setprio(1);
#pragma unroll
        for (int i = 0; i < 4; ++i)
#pragma unroll
            for (int j = 0; j < 2; ++j) {
                acc[i + 4][j] = MFMA16(af[i][0], bq0[j][0], acc[i + 4][j], 0, 0, 0);
                acc[i + 4][j] = MFMA16(af[i][1], bq0[j][1], acc[i + 4][j], 0, 0, 0);
            }
        __builtin_amdgcn_s_setprio(0);
        __builtin_amdgcn_s_barrier();

        // ---- phase 3: stage B-hi of t+2 (B-hi dead); counted vmcnt ----
        if (s2) { stB(bufc, 128, t + 2); stB(bufc, 192, t + 2); }
        if (s2)      asm volatile("s_waitcnt vmcnt(6)" ::: "memory");
        else if (s1) asm volatile("s_waitcnt vmcnt(0)" ::: "memory");
        __builtin_amdgcn_s_barrier();
        __builtin_amdgcn_s_setprio(1);
#pragma unroll
        for (int i = 0; i < 4; ++i)
#pragma unroll
            for (int j = 0; j < 2; ++j) {
                acc[i + 4][j + 2] = MFMA16(af[i][0], bq1[j][0], acc[i + 4][j + 2], 0, 0, 0);
                acc[i + 4][j + 2] = MFMA16(af[i][1], bq1[j][1], acc[i + 4][j + 2], 0, 0, 0);
            }
        __builtin_amdgcn_s_setprio(0);
        __builtin_amdgcn_s_barrier();
    }

    // Epilogue: per-wave LDS repack (buffers dead; last bar2 passed by all).
    // C/D layout: col=lane&15, row=(lane>>4)*4+reg (m89-verified).
    float bv[4] = {0.0f, 0.0f, 0.0f, 0.0f};
    if (BIAS) {
#pragma unroll
        for (int fn = 0; fn < 4; ++fn)
            bv[fn] = bias[n0 + fn * 64 + wc * 16 + lm];
    }
    float* scratch = (float*)smem + wid * (16 * 68);
    const int c0   = (lane & 7) * 8;
    const int gcol = n0 + (c0 >> 4) * 64 + wc * 16 + (c0 & 8);
#pragma unroll
    for (int fm = 0; fm < 8; ++fm) {
#pragma unroll
        for (int fn = 0; fn < 4; ++fn)
#pragma unroll
            for (int r = 0; r < 4; ++r) {
                float v = acc[fm][fn][r] + bv[fn];
                if (RELU) v = fmaxf(v, 0.0f);
                scratch[(q * 4 + r) * 68 + fn * 16 + lm] = v;
            }
        // wave-private scratch: same-wave LDS instrs are in-order (lgkm deps)
#pragma unroll
        for (int p = 0; p < 2; ++p) {
            int row16 = (lane >> 3) + p * 8;
            int grow  = m0 + (fm * 2 + wr) * 16 + row16;
            if (grow < M && gcol < NV) {
                float4 v0 = *(float4*)&scratch[row16 * 68 + c0];
                float4 v1 = *(float4*)&scratch[row16 * 68 + c0 + 4];
                bf16x8 o;
                o[0] = f2bf(v0.x); o[1] = f2bf(v0.y);
                o[2] = f2bf(v0.z); o[3] = f2bf(v0.w);
                o[4] = f2bf(v1.x); o[5] = f2bf(v1.y);
                o[6] = f2bf(v1.z); o[7] = f2bf(v1.w);
                *(bf16x8*)(C + (size_t)grow * NV + gcol) = o;
            }
        }
    }
}

// ---------------------------------------------------------------------------
// Multi-job GEMM (up to 4 independent bf16-out jobs, flat 1-D grid).
// Kept for the small UV / classifier-projection jobs (128-tile shapes).
// ---------------------------------------------------------------------------
struct GemmJobs {
    const short* A[4]; const short* Bt[4]; short* C[4];
    int M[4], N[4], K[4], lda[4], ldb[4];
    int cum[5];
};

__global__ __launch_bounds__(256, 4) void mfma_gemm_multi(GemmJobs jobs)
{
    __shared__ __align__(16) char smem_raw[32768];
    short* As = (short*)smem_raw;
    short* Bs = As + 128 * 64;

    int bid = blockIdx.x;
    int j = 0;
    while (bid >= jobs.cum[j + 1]) ++j;             // <=4, block-uniform
    int lt = bid - jobs.cum[j];
    const short* A  = jobs.A[j];
    const short* Bt = jobs.Bt[j];
    short* C = jobs.C[j];
    int M = jobs.M[j], N = jobs.N[j], K = jobs.K[j];
    int lda = jobs.lda[j], ldb = jobs.ldb[j];
    int ncols = N >> 7;
    int by = lt / ncols;
    int bx = lt - by * ncols;

    const int tid  = threadIdx.x;
    const int wave = tid >> 6;
    const int lane = tid & 63;
    const int m0 = by * 128;
    const int n0 = bx * 128;
    const int wm = (wave & 1) * 64;
    const int wn = (wave >> 1) * 64;

    f32x4 acc[4][4] = {};
    const int q  = lane >> 4;
    const int lm = lane & 15;

    for (int k0 = 0; k0 < K; k0 += 64) {
#pragma unroll
        for (int it = 0; it < 4; ++it) {
            int c    = (it & 1) * 256 + tid;
            int half = it >> 1;
            int row  = c >> 2;
            int kk   = (c & 3) * 8 + half * 32;
            int ldsc = half * 4096 + ((it & 1) * 256 + wave * 64) * 8;
            int gm = m0 + row; if (gm >= M) gm = M - 1;
            load16_lds(A + (size_t)gm * lda + k0 + kk, As + ldsc);
            load16_lds(Bt + (size_t)(n0 + row) * ldb + k0 + kk, Bs + ldsc);
        }
        __syncthreads();
#pragma unroll
        for (int half = 0; half < 2; ++half) {
            const short* Ah = As + half * 4096;
            const short* Bh = Bs + half * 4096;
            bf16x8 af[4], bfr[4];
#pragma unroll
            for (int t = 0; t < 4; ++t) {
                af[t]  = *(const bf16x8*)(Ah + (wm + t * 16 + lm) * 32 + q * 8);
                bfr[t] = *(const bf16x8*)(Bh + (wn + t * 16 + lm) * 32 + q * 8);
            }
#pragma unroll
            for (int tm = 0; tm < 4; ++tm)
#pragma unroll
                for (int tn = 0; tn < 4; ++tn)
                    acc[tm][tn] = MFMA16(af[tm], bfr[tn], acc[tm][tn], 0, 0, 0);
        }
        __syncthreads();
    }

    float* scratch = (float*)smem_raw + wave * (16 * 68);
#pragma unroll
    for (int tm = 0; tm < 4; ++tm) {
        __syncthreads();
#pragma unroll
        for (int tn = 0; tn < 4; ++tn)
#pragma unroll
            for (int r = 0; r < 4; ++r)
                scratch[(q * 4 + r) * 68 + tn * 16 + lm] = acc[tm][tn][r];
        __syncthreads();
#pragma unroll
        for (int p = 0; p < 2; ++p) {
            int row16 = (lane >> 3) + p * 8;
            int c0 = (lane & 7) * 8;
            float4 v0 = *(float4*)&scratch[row16 * 68 + c0];
            float4 v1 = *(float4*)&scratch[row16 * 68 + c0 + 4];
            bf16x8 o;
            o[0] = f2bf(v0.x); o[1] = f2bf(v0.y); o[2] = f2bf(v0.z); o[3] = f2bf(v0.w);
            o[4] = f2bf(v1.x); o[5] = f2bf(v1.y); o[6] = f2bf(v1.z); o[7] = f2bf(v1.w);
            int grow = m0 + wm + tm * 16 + row16;
            if (grow < M)
                *(bf16x8*)(C + (size_t)grow * N + n0 + wn + c0) = o;
        }
    }
}

// ---------------------------------------------------------------------------
// UV merge (in-place): UVa = UVa + UVb + b1 (U-half cols only).
// ---------------------------------------------------------------------------
constexpr int N4UV = BSZ * NDET * 2048 / 4;   // 393216 short4s
__global__ __launch_bounds__(256) void uvmerge_kernel(
    short* __restrict__ UVa, const short* __restrict__ UVb,
    const float* __restrict__ b1)
{
    int i = blockIdx.x * 256 + threadIdx.x;
    if (i >= N4UV) return;
    short4 a = ((const short4*)UVa)[i];
    short4 b = ((const short4*)UVb)[i];
    int col4 = i & 511;
    float4 bb = {0.0f, 0.0f, 0.0f, 0.0f};
    if (col4 < 256) bb = ((const float4*)b1)[col4];
    short4 o;
    o.x = f2bf(bf2f(a.x) + bf2f(b.x) + bb.x);
    o.y = f2bf(bf2f(a.y) + bf2f(b.y) + bb.y);
    o.z = f2bf(bf2f(a.z) + bf2f(b.z) + bb.z);
    o.w = f2bf(bf2f(a.w) + bf2f(b.w) + bb.w);
    ((short4*)UVa)[i] = o;
}

// ---------------------------------------------------------------------------
// Fused pairs + rh: wave-per-row.
// ---------------------------------------------------------------------------
__global__ __launch_bounds__(256) void pairs_rh_kernel(
    const short* __restrict__ UVs,
    const int* __restrict__ sids, const int* __restrict__ oids,
    short* __restrict__ h1,
    const float* __restrict__ rp, const float* __restrict__ R1,
    const float* __restrict__ rb1, short* __restrict__ rh, int b0)
{
    int wave = threadIdx.x >> 6, lane = threadIdx.x & 63;
    int r = blockIdx.x * 4 + wave;
    int b = b0 + r / PAIRS;
    int p = r % PAIRS;

    const bf16x8* us = (const bf16x8*)(UVs + (size_t)(b * NDET + sids[p]) * 2048);
    const bf16x8* uo = (const bf16x8*)(UVs + (size_t)(b * NDET + oids[p]) * 2048 + 1024);
    bf16x8* hrow = (bf16x8*)(h1 + (size_t)r * DH);
#pragma unroll
    for (int i = 0; i < 2; ++i) {
        int idx = lane + i * 64;            // 128 bf16x8 per 1024-elem row
        bf16x8 a = us[idx], c = uo[idx];
        bf16x8 h;
#pragma unroll
        for (int e = 0; e < 8; ++e)
            h[e] = f2bf(fmaxf(bf2f(a[e]) + bf2f(c[e]), 0.0f));
        hrow[idx] = h;
    }

    int rg = b0 * PAIRS + r;
    const float* rowp = rp + (size_t)rg * 12;
    float4 acc = ((const float4*)rb1)[lane];
#pragma unroll
    for (int k = 0; k < 12; ++k) {
        float rv = rowp[k];
        float4 w = ((const float4*)(R1 + k * 256))[lane];
        acc.x = fmaf(rv, w.x, acc.x);
        acc.y = fmaf(rv, w.y, acc.y);
        acc.z = fmaf(rv, w.z, acc.z);
        acc.w = fmaf(rv, w.w, acc.w);
    }
    short4 o;
    o.x = f2bf(fmaxf(acc.x, 0.0f));
    o.y = f2bf(fmaxf(acc.y, 0.0f));
    o.z = f2bf(fmaxf(acc.z, 0.0f));
    o.w = f2bf(fmaxf(acc.w, 0.0f));
    ((short4*)(rh + (size_t)r * 256))[lane] = o;
}

// ---------------------------------------------------------------------------
// Fused row_prep + focal: wave-per-row (logits from extended GEMM columns;
// ||comb||^2 = 2 + 2*rho/(||so||*||re||)).
// ---------------------------------------------------------------------------
__global__ __launch_bounds__(256) void rowprep_focal_kernel(
    const short* __restrict__ so_ext, const short* __restrict__ re_ext,
    const float* __restrict__ traj, const float* __restrict__ temperature,
    const int* __restrict__ sids, const int* __restrict__ oids,
    const int* __restrict__ labels,
    float4* __restrict__ pn, float* __restrict__ dist_arr, int b0)
{
    int wave = threadIdx.x >> 6, lane = threadIdx.x & 63;
    int r = blockIdx.x * 4 + wave;
    int rg = b0 * PAIRS + r;
    int b = b0 + r / PAIRS;
    int p = r % PAIRS;

    const short* srow = so_ext + (size_t)r * NEXT;
    const short* rrow = re_ext + (size_t)r * NEXT;
    bf16x8 sv = *(const bf16x8*)(srow + lane * 8);
    bf16x8 uv = *(const bf16x8*)(rrow + lane * 8);
    float s[8], u[8];
#pragma unroll
    for (int i = 0; i < 8; ++i) { s[i] = bf2f(sv[i]); u[i] = bf2f(uv[i]); }

    const float* tsrc = (lane < 32)
        ? (traj + (size_t)(b * NDET + sids[p]) * EHALF + lane * 8)
        : (traj + (size_t)(b * NDET + oids[p]) * EHALF + (lane - 32) * 8);
    float4 t0 = ((const float4*)tsrc)[0], t1 = ((const float4*)tsrc)[1];
    float t[8] = {t0.x, t0.y, t0.z, t0.w, t1.x, t1.y, t1.z, t1.w};

    float ss = 0.0f, sr = 0.0f, rho = 0.0f, sd = 0.0f;
#pragma unroll
    for (int i = 0; i < 8; ++i) {
        ss  += s[i] * s[i];
        sr  += u[i] * u[i];
        rho += s[i] * u[i];
        sd  += fabsf(t[i] - s[i]);
    }
#pragma unroll
    for (int m = 1; m < 64; m <<= 1) {
        ss  += __shfl_xor(ss, m);
        sr  += __shfl_xor(sr, m);
        rho += __shfl_xor(rho, m);
        sd  += __shfl_xor(sd, m);
    }
    float inv_s = 1.0f / fmaxf(sqrtf(ss), 1e-12f);
    float inv_r = 1.0f / fmaxf(sqrtf(sr), 1e-12f);
    float ncomb = sqrtf(fmaxf(2.0f + 2.0f * rho * inv_s * inv_r, 0.0f));
    float scale = 1.0f / (fmaxf(ncomb, 1e-12f) * temperature[0]);

    float flp = 0.0f, fln = 0.0f, fm = 0.0f;
    size_t labbase = (size_t)rg * LABW;
#pragma unroll
    for (int h = 0; h < 2; ++h) {
        int c = lane + h * 64;
        if (c < NCLS) {
            float l = (bf2f(srow[DE + c]) * inv_s + bf2f(rrow[DE + c]) * inv_r) * scale;
            int tl = labels[labbase + 1 + c];
            if (tl > 0) fm = 1.0f;
            float tf = (float)tl;
            float pr = 1.0f / (1.0f + expf(-l));
            float lg = log1pf(expf(-fabsf(l)));
            float ce = fmaxf(l, 0.0f) - l * tf + lg;
            float pt = pr * tf + (1.0f - pr) * (1.0f - tf);
            float om = 1.0f - pt;
            float at = 0.25f * tf + 0.75f * (1.0f - tf);
            flp += at * ce * om * om;
            float ce0 = fmaxf(l, 0.0f) + lg;
            fln += 0.75f * ce0 * pr * pr;
        }
    }
#pragma unroll
    for (int m = 1; m < 64; m <<= 1) {
        flp += __shfl_xor(flp, m);
        fln += __shfl_xor(fln, m);
        fm  += __shfl_xor(fm, m);
    }
    if (lane == 0) {
        int posf = (fm > 0.5f) ? 1 : 0;
        int negf = (labels[labbase] > 0) ? 1 : 0;
        pn[rg] = make_float4(posf ? flp : 0.0f, negf ? fln : 0.0f, 0.0f,
                             (float)(posf + 2 * negf));
        dist_arr[rg] = sd;
    }
}

// ---------------------------------------------------------------------------
// Two-stage final reduce.
// ---------------------------------------------------------------------------
struct RedRec { double sp, sn, sd; int cp, cn; };
constexpr int RED1 = 64;
constexpr int ROWS_PER_RED = ROWS / RED1;           // 564

__global__ __launch_bounds__(256) void reduce1_kernel(
    const float4* __restrict__ pn, const float* __restrict__ dist_arr,
    RedRec* __restrict__ scratch)
{
    int tid = threadIdx.x;
    int base = blockIdx.x * ROWS_PER_RED;
    double sp = 0.0, sn = 0.0, sd = 0.0;
    int cp = 0, cn = 0;
    for (int i = tid; i < ROWS_PER_RED; i += 256) {
        float4 v = pn[base + i];
        sp += (double)v.x; sn += (double)v.y; sd += (double)dist_arr[base + i];
        int f = (int)v.w;
        cp += f & 1; cn += (f >> 1) & 1;
    }
    __shared__ double A[256], B[256], C[256];
    __shared__ int I[256], J[256];
    A[tid] = sp; B[tid] = sn; C[tid] = sd; I[tid] = cp; J[tid] = cn;
    __syncthreads();
    for (int st = 128; st > 0; st >>= 1) {
        if (tid < st) { A[tid] += A[tid + st]; B[tid] += B[tid + st]; C[tid] += C[tid + st];
                        I[tid] += I[tid + st]; J[tid] += J[tid + st]; }
        __syncthreads();
    }
    if (tid == 0) {
        RedRec rec; rec.sp = A[0]; rec.sn = B[0]; rec.sd = C[0];
        rec.cp = I[0]; rec.cn = J[0];
        scratch[blockIdx.x] = rec;
    }
}

__global__ __launch_bounds__(64) void reduce2_kernel(
    const RedRec* __restrict__ scratch, float* __restrict__ out)
{
    int lane = threadIdx.x;
    RedRec rec = scratch[lane];
    double sp = rec.sp, sn = rec.sn, sd = rec.sd;
    int cp = rec.cp, cn = rec.cn;
#pragma unroll
    for (int m = 1; m < 64; m <<= 1) {
        sp += __shfl_xor(sp, m);
        sn += __shfl_xor(sn, m);
        sd += __shfl_xor(sd, m);
        cp += __shfl_xor(cp, m);
        cn += __shfl_xor(cn, m);
    }
    if (lane == 0) {
        int cpv = cp < 1 ? 1 : cp;
        int cnv = cn < 1 ? 1 : cn;
        out[0] = (float)(sp / ((double)cpv * NCLS) +
                         sn / ((double)cnv * NCLS) +
                         sd / ((double)ROWS * DE));
    }
}

extern "C" void kernel_launch(void* const* d_in, const int* in_sizes, int n_in,
                              void* d_out, int out_size, void* d_ws, size_t ws_size,
                              hipStream_t stream)
{
    const float* det    = (const float*)d_in[0];
    const float* traj   = (const float*)d_in[1];
    const float* relpos = (const float*)d_in[2];
    const float* cw     = (const float*)d_in[3];
    const float* W1     = (const float*)d_in[4];
    const float* b1     = (const float*)d_in[5];
    const float* W2     = (const float*)d_in[6];
    const float* b2     = (const float*)d_in[7];
    const float* W3     = (const float*)d_in[8];
    const float* R1     = (const float*)d_in[9];
    const float* rb1    = (const float*)d_in[10];
    const float* R2     = (const float*)d_in[11];
    const float* temp   = (const float*)d_in[12];
    const int*   labels = (const int*)d_in[13];
    const int*   sids   = (const int*)d_in[14];
    const int*   oids   = (const int*)d_in[15];
    float* out = (float*)d_out;

    // ---- Workspace carve --------------------------------------------------
    char* ws = (char*)d_ws;
    size_t off = 0;
    auto carve = [&](size_t bytes) -> char* {
        char* p = ws + off;
        off = (off + bytes + 255) & ~(size_t)255;
        return p;
    };
    float4* pn       = (float4*)carve((size_t)ROWS * 16);
    float*  dist_arr = (float*)carve((size_t)ROWS * 4);
    short*  det_bf   = (short*)carve((size_t)BSZ * NDET * DF * 2);
    short*  W1t      = (short*)carve((size_t)2048 * 2048 * 2);
    short*  W2t      = (short*)carve((size_t)DH * DH * 2);
    short*  W3t      = (short*)carve((size_t)NPAD * DH * 2);      // [768][1024], rows 640+ garbage
    short*  R2t      = (short*)carve((size_t)NPAD * 256 * 2);     // [768][256],  rows 640+ garbage
    short*  cwt      = (short*)carve((size_t)128 * DE * 2);
    short*  W3bf     = (short*)carve((size_t)DH * DE * 2);
    short*  R2bf     = (short*)carve((size_t)256 * DE * 2);
    short*  UVa      = (short*)carve((size_t)BSZ * NDET * 2048 * 2);
    short*  UVb      = (short*)carve((size_t)BSZ * NDET * 2048 * 2);
    RedRec* red_scratch = (RedRec*)carve((size_t)RED1 * sizeof(RedRec));
    size_t fixed_off = off;

    int b_ch = 1;
    for (int cand : {16, 8, 4, 2, 1}) {
        size_t rows  = (size_t)cand * PAIRS;
        size_t bytes = fixed_off + rows * 2048 + 256 + rows * 2048 + 256
                     + rows * 512 + 256 + rows * 1280 + 256;
        if (bytes <= ws_size) { b_ch = cand; break; }
    }
    const int chunk_rows = b_ch * PAIRS;
    const int n_chunks = BSZ / b_ch;
    char* reg1 = carve((size_t)chunk_rows * 2048);
    char* reg2 = carve((size_t)chunk_rows * 2048);
    char* reg3 = carve((size_t)chunk_rows * 512);
    char* reg4 = carve((size_t)chunk_rows * 1280);

    short* h1     = (short*)reg1;
    short* h2     = (short*)reg2;
    short* so_ext = (short*)reg1;     // overwrites h1 (dead after h2 GEMM)
    short* rh     = (short*)reg3;
    short* re_ext = (short*)reg4;     // own region (R10 race fix)

    // ---- Prep (1 launch) --------------------------------------------------
    TransJobs tj;
    tj.src[0] = W1;                    tj.dst[0] = W1t;                   tj.K[0] = DF;  tj.N[0] = DH;
    tj.src[1] = W1 + (size_t)DF * DH;  tj.dst[1] = W1t + (size_t)DH * DF; tj.K[1] = DF;  tj.N[1] = DH;
    tj.src[2] = W2;                    tj.dst[2] = W2t;                   tj.K[2] = DH;  tj.N[2] = DH;
    tj.src[3] = W3;                    tj.dst[3] = W3t;                   tj.K[3] = DH;  tj.N[3] = DE;
    tj.src[4] = R2;                    tj.dst[4] = R2t;                   tj.K[4] = 256; tj.N[4] = DE;
    tj.cum[0] = 0;
    for (int i = 0; i < 5; ++i)
        tj.cum[i + 1] = tj.cum[i] + (tj.K[i] / 32) * (tj.N[i] / 32);
    prep_kernel<<<NCONVB + tj.cum[5], 256, 0, stream>>>(
        det, det_bf, cw, cwt, W3, W3bf, R2, R2bf, tj);

    // One multi-job GEMM launch: UV split-K halves + classifier projections.
    GemmJobs gj;
    gj.A[0] = det_bf;        gj.Bt[0] = W1t;        gj.C[0] = UVa;
    gj.M[0] = BSZ * NDET;    gj.N[0] = 2048;        gj.K[0] = 1024;
    gj.lda[0] = 2048;        gj.ldb[0] = 2048;
    gj.A[1] = det_bf + 1024; gj.Bt[1] = W1t + 1024; gj.C[1] = UVb;
    gj.M[1] = BSZ * NDET;    gj.N[1] = 2048;        gj.K[1] = 1024;
    gj.lda[1] = 2048;        gj.ldb[1] = 2048;
    gj.A[2] = cwt;           gj.Bt[2] = W3bf;       gj.C[2] = W3t + (size_t)512 * DH;
    gj.M[2] = 128;           gj.N[2] = 1024;        gj.K[2] = 512;
    gj.lda[2] = 512;         gj.ldb[2] = 512;
    gj.A[3] = cwt;           gj.Bt[3] = R2bf;       gj.C[3] = R2t + (size_t)512 * 256;
    gj.M[3] = 128;           gj.N[3] = 256;         gj.K[3] = 512;
    gj.lda[3] = 512;         gj.ldb[3] = 512;
    gj.cum[0] = 0;
    for (int i = 0; i < 4; ++i)
        gj.cum[i + 1] = gj.cum[i] + (gj.N[i] / 128) * ((gj.M[i] + 127) / 128);
    mfma_gemm_multi<<<gj.cum[4], 256, 0, stream>>>(gj);   // 202 blocks

    // Merge: UVa += UVb + b1 (in-place)
    uvmerge_kernel<<<(N4UV + 255) / 256, 256, 0, stream>>>(UVa, UVb, b1);

    const int mt = (chunk_rows + 255) / 256;          // 256-row tiles

    for (int c = 0; c < n_chunks; ++c) {
        int b0 = c * b_ch;

        pairs_rh_kernel<<<chunk_rows / 4, 256, 0, stream>>>(
            UVa, sids, oids, h1, relpos, R1, rb1, rh, b0);

        // h2 = bf16(relu(h1 @ W2 + b2))  — 8-phase 256^2
        gemm256<true, true, false><<<mt * 4, 512, 0, stream>>>(
            h1, W2t, b2, h2, chunk_rows, DH, DH, DH, DH, 4, 0,
            nullptr, nullptr, nullptr, 0, 0, 0, 0, 0, 0);

        // so_ext = bf16(h2 @ [W3 | W3·cw^T]) ; re_ext = bf16(rh @ [R2 | R2·cw^T])
        // B padded to 768 rows; epilogue masks cols >= 640. so first (long K).
        gemm256<false, false, true><<<mt * 6, 512, 0, stream>>>(
            h2, W3t, nullptr, so_ext, chunk_rows, NEXT, DH, DH, DH, 3, mt * 3,
            rh, R2t, re_ext, chunk_rows, NEXT, 256, 256, 256, 3);

        rowprep_focal_kernel<<<chunk_rows / 4, 256, 0, stream>>>(
            so_ext, re_ext, traj, temp, sids, oids, labels, pn, dist_arr, b0);
    }

    reduce1_kernel<<<RED1, 256, 0, stream>>>(pn, dist_arr, red_scratch);
    reduce2_kernel<<<1, 64, 0, stream>>>(red_scratch, out);
}

// Round 2
// 387.914 us; speedup vs baseline: 1.0249x; 1.0249x over previous
//
#include <hip/hip_runtime.h>
#include <math.h>

// Problem constants
constexpr int BSZ   = 16;
constexpr int NDET  = 48;
constexpr int PAIRS = NDET * (NDET - 1);      // 2256
constexpr int ROWS  = BSZ * PAIRS;            // 36096
constexpr int DF    = 2048;
constexpr int DH    = 1024;
constexpr int DE    = 512;
constexpr int EHALF = 256;
constexpr int NCLS  = 92;
constexpr int NEXT  = DE + 128;               // 640: valid so/re width incl. classifier cols
constexpr int NPAD  = 768;                    // 256-tile-padded B rows for so/re GEMM
constexpr int LABW  = 1 + 92 + 40;            // 133

typedef __attribute__((ext_vector_type(8))) short bf16x8;   // 8 bf16 in 4 VGPRs
typedef __attribute__((ext_vector_type(4))) float f32x4;

__device__ __forceinline__ short f2bf(float f) {
    union { float f; unsigned u; } a; a.f = f;
    unsigned r = a.u + 0x7fffu + ((a.u >> 16) & 1u);   // RNE
    return (short)(r >> 16);
}
__device__ __forceinline__ float bf2f(short h) {
    union { unsigned u; float f; } x;
    x.u = ((unsigned)(unsigned short)h) << 16;
    return x.f;
}

// ---------------------------------------------------------------------------
// Merged prep. Elementwise ranges: det conv | cwt build | W3->bf16 | R2->bf16;
// then 5-job transpose (W1 top/bot, W2, W3, R2).
// ---------------------------------------------------------------------------
constexpr int N4DET = BSZ * NDET * DF / 4;    // 393216
constexpr int N4CWT = 128 * DE / 4;           // 16384
constexpr int N4W3  = DH * DE / 4;            // 131072
constexpr int N4R2  = 256 * DE / 4;           // 32768
constexpr int NCONVB = (N4DET + N4CWT + N4W3 + N4R2) / 256;   // 2240

struct TransJobs {
    const float* src[5];
    short*       dst[5];
    int K[5], N[5];
    int cum[6];
};

__global__ __launch_bounds__(256) void prep_kernel(
    const float* __restrict__ det, short* __restrict__ det_bf,
    const float* __restrict__ cw, short* __restrict__ cwt,
    const float* __restrict__ W3, short* __restrict__ W3bf,
    const float* __restrict__ R2, short* __restrict__ R2bf,
    TransJobs jobs)
{
    if (blockIdx.x < NCONVB) {
        int i = blockIdx.x * 256 + threadIdx.x;
        const float* src; short* dst; int k;
        if (i < N4DET) { src = det; dst = det_bf; k = i; }
        else if (i < N4DET + N4CWT) {
            k = i - N4DET;
            int n = (k * 4) >> 9;
            short4 o = {0, 0, 0, 0};
            if (n < NCLS) {
                float4 v = ((const float4*)cw)[k];
                o.x = f2bf(v.x); o.y = f2bf(v.y); o.z = f2bf(v.z); o.w = f2bf(v.w);
            }
            ((short4*)cwt)[k] = o;
            return;
        }
        else if (i < N4DET + N4CWT + N4W3) { src = W3; dst = W3bf; k = i - N4DET - N4CWT; }
        else { src = R2; dst = R2bf; k = i - N4DET - N4CWT - N4W3; }
        float4 v = ((const float4*)src)[k];
        short4 o;
        o.x = f2bf(v.x); o.y = f2bf(v.y); o.z = f2bf(v.z); o.w = f2bf(v.w);
        ((short4*)dst)[k] = o;
        return;
    }
    __shared__ float tile[32][33];
    int t = blockIdx.x - NCONVB;
    int j = 0;
    while (t >= jobs.cum[j + 1]) ++j;
    int lt = t - jobs.cum[j];
    int K = jobs.K[j], N = jobs.N[j];
    int nx = N >> 5;
    int ky = lt / nx, nxi = lt - ky * nx;
    int n0 = nxi * 32, k0 = ky * 32;
    const float* src = jobs.src[j];
    short* dst = jobs.dst[j];
    int tx = threadIdx.x & 31, ty = threadIdx.x >> 5;
#pragma unroll
    for (int i = ty; i < 32; i += 8)
        tile[i][tx] = src[(size_t)(k0 + i) * N + n0 + tx];
    __syncthreads();
#pragma unroll
    for (int i = ty; i < 32; i += 8)
        dst[(size_t)(n0 + i) * K + k0 + tx] = f2bf(tile[tx][i]);
}

__device__ __forceinline__ void load16_lds(const void* g, void* l) {
    __builtin_amdgcn_global_load_lds(
        (const __attribute__((address_space(1))) unsigned int*)g,
        (__attribute__((address_space(3))) unsigned int*)l, 16, 0, 0);
}

// m204 bijective chunked XCD map: physical o (XCD = o%8) -> logical tile id
// such that each XCD owns a CONTIGUOUS run of tiles (L2 A-panel locality).
__device__ __forceinline__ int chunkmap(int o, int n) {
    int x = o & 7, q = n >> 3, r = n & 7;
    int base = (x < r) ? x * (q + 1) : r * (q + 1) + (x - r) * q;
    return base + (o >> 3);
}

#define MFMA16 __builtin_amdgcn_mfma_f32_16x16x32_bf16

// ---------------------------------------------------------------------------
// R15: 256x256x64 4-phase GEMM, relaxed schedule.
// Changes vs R14 (which measured 702 TF, MfmaUtil 28%):
//  - XCD chunked swizzle (m204), per-job in DUAL (FETCH was 2x A without it).
//  - ONE barrier per phase (was 2) and NO explicit lgkmcnt(0): ds_reads are
//    plain C++ loads, so the compiler emits counted lgkm waits per consuming
//    MFMA -> LDS reads overlap MFMA instead of strictly alternating.
//    Hazard audit: every phase's ds_reads are consumed by that phase's MFMAs
//    (issued before the phase barrier), and every LDS region has >=1 barrier
//    between its last read and the stage that overwrites it.
//  - vmcnt(6) after phase-3 MFMA (MFMA doesn't depend on it).
// ---------------------------------------------------------------------------
template <bool BIAS, bool RELU, bool DUAL>
__global__ __launch_bounds__(512, 2) void gemm256(
    const short* __restrict__ A, const short* __restrict__ Bt,
    const float* __restrict__ bias, short* __restrict__ C,
    int M, int NV, int K, int lda, int ldb, int ntn, int nsplit,
    const short* A2, const short* Bt2, short* C2,
    int M2, int NV2, int K2, int lda2, int ldb2, int ntn2)
{
    __shared__ __align__(16) short smem[2 * 32768];   // 128 KiB

    int o = blockIdx.x;
    int bid;
    if (DUAL) {
        // chunk-swizzle each job's physical range separately: chunking across
        // the so/re boundary would give whole XCDs only-re (4x less work).
        if (o < nsplit) bid = chunkmap(o, nsplit);
        else            bid = nsplit + chunkmap(o - nsplit, gridDim.x - nsplit);
    } else {
        bid = chunkmap(o, gridDim.x);
    }
    if (DUAL && bid >= nsplit) {
        bid -= nsplit;
        A = A2; Bt = Bt2; C = C2;
        M = M2; NV = NV2; K = K2; lda = lda2; ldb = ldb2; ntn = ntn2;
    }
    const int by = bid / ntn;
    const int bx = bid - by * ntn;
    const int m0 = by * 256;
    const int n0 = bx * 256;

    const int tid  = threadIdx.x;
    const int wid  = tid >> 6;
    const int lane = tid & 63;
    const int wr = wid >> 2;
    const int wc = wid & 3;
    const int q  = lane >> 4;
    const int lm = lane & 15;

    // staging: wave w stages 8 rows/call; lane l -> row w*8+(l>>3),
    // dest chunk l&7, source chunk (l&7)^((l>>3)&7)  (inverse swizzle)
    const int rowoff = wid * 8 + ((tid & 63) >> 3);
    const int cs8    = ((tid & 7) ^ ((tid >> 3) & 7)) * 8;
    // ds_read swizzled k-chunk offsets (shorts): chunk (s*4+q) ^ (row&7)
    const int kc0 = ((q)     ^ (lm & 7)) * 8;
    const int kc1 = ((4 + q) ^ (lm & 7)) * 8;
    const int NT  = K >> 6;
    const int Mm1 = M - 1;

    auto stA = [&](int buf, int r0, int kt) {
        int gm = m0 + r0 + rowoff; if (gm > Mm1) gm = Mm1;
        load16_lds(A + (size_t)gm * lda + kt * 64 + cs8,
                   smem + buf * 32768 + (r0 + wid * 8) * 64);
    };
    auto stB = [&](int buf, int r0, int kt) {
        int gn = n0 + r0 + rowoff;                 // B rows padded: no clamp
        load16_lds(Bt + (size_t)gn * ldb + kt * 64 + cs8,
                   smem + buf * 32768 + 16384 + (r0 + wid * 8) * 64);
    };

    // prologue: tile0 (A-lo,B-lo,B-hi,A-hi) + tile1 (A-lo,B-lo,B-hi)
    stA(0, 0, 0);   stA(0, 64, 0);
    stB(0, 0, 0);   stB(0, 64, 0);
    stB(0, 128, 0); stB(0, 192, 0);
    stA(0, 128, 0); stA(0, 192, 0);
    if (NT > 1) {
        stA(1, 0, 1);   stA(1, 64, 1);
        stB(1, 0, 1);   stB(1, 64, 1);
        stB(1, 128, 1); stB(1, 192, 1);
        asm volatile("s_waitcnt vmcnt(6)" ::: "memory");   // tile0 complete
    } else {
        asm volatile("s_waitcnt vmcnt(0)" ::: "memory");
    }
    __builtin_amdgcn_s_barrier();

    f32x4 acc[8][4] = {};
    bf16x8 af[4][2], bq0[2][2], bq1[2][2];

    for (int t = 0; t < NT; ++t) {
        const short* Ab = smem + (t & 1) * 32768;
        const short* Bb = Ab + 16384;
        const int bufc = t & 1, bufn = bufc ^ 1;
        const bool s1 = (t + 1 < NT);
        const bool s2 = (t + 2 < NT);

        // ---- phase 0: stage A-hi(t+1); read af-lo + bq0; MFMA q00 ----
        if (s1) { stA(bufn, 128, t + 1); stA(bufn, 192, t + 1); }
        {
            // read order: af[0], bq0[0], bq0[1], af[1..3] -> first MFMA can
            // start on counted lgkm wait while 6 reads still in flight.
            const short* r0 = Ab + ((0 * 2 + wr) * 16 + lm) * 64;
            af[0][0] = *(const bf16x8*)(r0 + kc0);
            af[0][1] = *(const bf16x8*)(r0 + kc1);
#pragma unroll
            for (int j = 0; j < 2; ++j) {
                const short* r = Bb + ((j * 4 + wc) * 16 + lm) * 64;
                bq0[j][0] = *(const bf16x8*)(r + kc0);
                bq0[j][1] = *(const bf16x8*)(r + kc1);
            }
#pragma unroll
            for (int i = 1; i < 4; ++i) {
                const short* r = Ab + ((i * 2 + wr) * 16 + lm) * 64;
                af[i][0] = *(const bf16x8*)(r + kc0);
                af[i][1] = *(const bf16x8*)(r + kc1);
            }
        }
        __builtin_amdgcn_s_setprio(1);
#pragma unroll
        for (int i = 0; i < 4; ++i)
#pragma unroll
            for (int j = 0; j < 2; ++j) {
                acc[i][j] = MFMA16(af[i][0], bq0[j][0], acc[i][j], 0, 0, 0);
                acc[i][j] = MFMA16(af[i][1], bq0[j][1], acc[i][j], 0, 0, 0);
            }
        __builtin_amdgcn_s_setprio(0);
        __builtin_amdgcn_s_barrier();

        // ---- phase 1: stage A-lo(t+2) (A-lo dead); read bq1; MFMA q01 ----
        if (s2) { stA(bufc, 0, t + 2); stA(bufc, 64, t + 2); }
#pragma unroll
        for (int j = 0; j < 2; ++j) {
            const short* r = Bb + (((j + 2) * 4 + wc) * 16 + lm) * 64;
            bq1[j][0] = *(const bf16x8*)(r + kc0);
            bq1[j][1] = *(const bf16x8*)(r + kc1);
        }
        __builtin_amdgcn_s_setprio(1);
#pragma unroll
        for (int i = 0; i < 4; ++i)
#pragma unroll
            for (int j = 0; j < 2; ++j) {
                acc[i][j + 2] = MFMA16(af[i][0], bq1[j][0], acc[i][j + 2], 0, 0, 0);
                acc[i][j + 2] = MFMA16(af[i][1], bq1[j][1], acc[i][j + 2], 0, 0, 0);
            }
        __builtin_amdgcn_s_setprio(0);
        __builtin_amdgcn_s_barrier();

        // ---- phase 2: stage B-lo(t+2) (B-lo dead); read af-hi; MFMA q10 ----
        if (s2) { stB(bufc, 0, t + 2); stB(bufc, 64, t + 2); }
#pragma unroll
        for (int i = 0; i < 4; ++i) {
            const short* r = Ab + (((i + 4) * 2 + wr) * 16 + lm) * 64;
            af[i][0] = *(const bf16x8*)(r + kc0);
            af[i][1] = *(const bf16x8*)(r + kc1);
        }
        __builtin_amdgcn_s_setprio(1);
#pragma unroll
        for (int i = 0; i < 4; ++i)
#pragma unroll
            for (int j = 0; j < 2; ++j) {
                acc[i + 4][j] = MFMA16(af[i][0], bq0[j][0], acc[i + 4][j], 0, 0, 0);
                acc[i + 4][j] = MFMA16(af[i][1], bq0[j][1], acc[i + 4][j], 0, 0, 0);
            }
        __builtin_amdgcn_s_setprio(0);
        __builtin_amdgcn_s_barrier();

        // ---- phase 3: stage B-hi(t+2) (B-hi dead); MFMA q11; counted vmcnt ----
        if (s2) { stB(bufc, 128, t + 2); stB(bufc, 192, t + 2); }
        __builtin_amdgcn_s_setprio(1);
#pragma unroll
        for (int i = 0; i < 4; ++i)
#pragma unroll
            for (int j = 0; j < 2; ++j) {
                acc[i + 4][j + 2] = MFMA16(af[i][0], bq1[j][0], acc[i + 4][j + 2], 0, 0, 0);
                acc[i + 4][j + 2] = MFMA16(af[i][1], bq1[j][1], acc[i + 4][j + 2], 0, 0, 0);
            }
        __builtin_amdgcn_s_setprio(0);
        if (s2)      asm volatile("s_waitcnt vmcnt(6)" ::: "memory");
        else if (s1) asm volatile("s_waitcnt vmcnt(0)" ::: "memory");
        __builtin_amdgcn_s_barrier();
    }

    // Epilogue: per-wave LDS repack (buffers dead; final barrier passed by all).
    // C/D layout: col=lane&15, row=(lane>>4)*4+reg (m89-verified).
    float bv[4] = {0.0f, 0.0f, 0.0f, 0.0f};
    if (BIAS) {
#pragma unroll
        for (int fn = 0; fn < 4; ++fn)
            bv[fn] = bias[n0 + fn * 64 + wc * 16 + lm];
    }
    float* scratch = (float*)smem + wid * (16 * 68);
    const int c0   = (lane & 7) * 8;
    const int gcol = n0 + (c0 >> 4) * 64 + wc * 16 + (c0 & 8);
#pragma unroll
    for (int fm = 0; fm < 8; ++fm) {
#pragma unroll
        for (int fn = 0; fn < 4; ++fn)
#pragma unroll
            for (int r = 0; r < 4; ++r) {
                float v = acc[fm][fn][r] + bv[fn];
                if (RELU) v = fmaxf(v, 0.0f);
                scratch[(q * 4 + r) * 68 + fn * 16 + lm] = v;
            }
        // wave-private scratch: same-wave LDS instrs ordered by lgkm deps
#pragma unroll
        for (int p = 0; p < 2; ++p) {
            int row16 = (lane >> 3) + p * 8;
            int grow  = m0 + (fm * 2 + wr) * 16 + row16;
            if (grow < M && gcol < NV) {
                float4 v0 = *(float4*)&scratch[row16 * 68 + c0];
                float4 v1 = *(float4*)&scratch[row16 * 68 + c0 + 4];
                bf16x8 o;
                o[0] = f2bf(v0.x); o[1] = f2bf(v0.y);
                o[2] = f2bf(v0.z); o[3] = f2bf(v0.w);
                o[4] = f2bf(v1.x); o[5] = f2bf(v1.y);
                o[6] = f2bf(v1.z); o[7] = f2bf(v1.w);
                *(bf16x8*)(C + (size_t)grow * NV + gcol) = o;
            }
        }
    }
}

// ---------------------------------------------------------------------------
// Multi-job GEMM (up to 4 independent bf16-out jobs, flat 1-D grid).
// Kept for the small UV / classifier-projection jobs (128-tile shapes).
// ---------------------------------------------------------------------------
struct GemmJobs {
    const short* A[4]; const short* Bt[4]; short* C[4];
    int M[4], N[4], K[4], lda[4], ldb[4];
    int cum[5];
};

__global__ __launch_bounds__(256, 4) void mfma_gemm_multi(GemmJobs jobs)
{
    __shared__ __align__(16) char smem_raw[32768];
    short* As = (short*)smem_raw;
    short* Bs = As + 128 * 64;

    int bid = blockIdx.x;
    int j = 0;
    while (bid >= jobs.cum[j + 1]) ++j;             // <=4, block-uniform
    int lt = bid - jobs.cum[j];
    const short* A  = jobs.A[j];
    const short* Bt = jobs.Bt[j];
    short* C = jobs.C[j];
    int M = jobs.M[j], N = jobs.N[j], K = jobs.K[j];
    int lda = jobs.lda[j], ldb = jobs.ldb[j];
    int ncols = N >> 7;
    int by = lt / ncols;
    int bx = lt - by * ncols;

    const int tid  = threadIdx.x;
    const int wave = tid >> 6;
    const int lane = tid & 63;
    const int m0 = by * 128;
    const int n0 = bx * 128;
    const int wm = (wave & 1) * 64;
    const int wn = (wave >> 1) * 64;

    f32x4 acc[4][4] = {};
    const int q  = lane >> 4;
    const int lm = lane & 15;

    for (int k0 = 0; k0 < K; k0 += 64) {
#pragma unroll
        for (int it = 0; it < 4; ++it) {
            int c    = (it & 1) * 256 + tid;
            int half = it >> 1;
            int row  = c >> 2;
            int kk   = (c & 3) * 8 + half * 32;
            int ldsc = half * 4096 + ((it & 1) * 256 + wave * 64) * 8;
            int gm = m0 + row; if (gm >= M) gm = M - 1;
            load16_lds(A + (size_t)gm * lda + k0 + kk, As + ldsc);
            load16_lds(Bt + (size_t)(n0 + row) * ldb + k0 + kk, Bs + ldsc);
        }
        __syncthreads();
#pragma unroll
        for (int half = 0; half < 2; ++half) {
            const short* Ah = As + half * 4096;
            const short* Bh = Bs + half * 4096;
            bf16x8 af[4], bfr[4];
#pragma unroll
            for (int t = 0; t < 4; ++t) {
                af[t]  = *(const bf16x8*)(Ah + (wm + t * 16 + lm) * 32 + q * 8);
                bfr[t] = *(const bf16x8*)(Bh + (wn + t * 16 + lm) * 32 + q * 8);
            }
#pragma unroll
            for (int tm = 0; tm < 4; ++tm)
#pragma unroll
                for (int tn = 0; tn < 4; ++tn)
                    acc[tm][tn] = MFMA16(af[tm], bfr[tn], acc[tm][tn], 0, 0, 0);
        }
        __syncthreads();
    }

    float* scratch = (float*)smem_raw + wave * (16 * 68);
#pragma unroll
    for (int tm = 0; tm < 4; ++tm) {
        __syncthreads();
#pragma unroll
        for (int tn = 0; tn < 4; ++tn)
#pragma unroll
            for (int r = 0; r < 4; ++r)
                scratch[(q * 4 + r) * 68 + tn * 16 + lm] = acc[tm][tn][r];
        __syncthreads();
#pragma unroll
        for (int p = 0; p < 2; ++p) {
            int row16 = (lane >> 3) + p * 8;
            int c0 = (lane & 7) * 8;
            float4 v0 = *(float4*)&scratch[row16 * 68 + c0];
            float4 v1 = *(float4*)&scratch[row16 * 68 + c0 + 4];
            bf16x8 o;
            o[0] = f2bf(v0.x); o[1] = f2bf(v0.y); o[2] = f2bf(v0.z); o[3] = f2bf(v0.w);
            o[4] = f2bf(v1.x); o[5] = f2bf(v1.y); o[6] = f2bf(v1.z); o[7] = f2bf(v1.w);
            int grow = m0 + wm + tm * 16 + row16;
            if (grow < M)
                *(bf16x8*)(C + (size_t)grow * N + n0 + wn + c0) = o;
        }
    }
}

// ---------------------------------------------------------------------------
// UV merge (in-place): UVa = UVa + UVb + b1 (U-half cols only).
// ---------------------------------------------------------------------------
constexpr int N4UV = BSZ * NDET * 2048 / 4;   // 393216 short4s
__global__ __launch_bounds__(256) void uvmerge_kernel(
    short* __restrict__ UVa, const short* __restrict__ UVb,
    const float* __restrict__ b1)
{
    int i = blockIdx.x * 256 + threadIdx.x;
    if (i >= N4UV) return;
    short4 a = ((const short4*)UVa)[i];
    short4 b = ((const short4*)UVb)[i];
    int col4 = i & 511;
    float4 bb = {0.0f, 0.0f, 0.0f, 0.0f};
    if (col4 < 256) bb = ((const float4*)b1)[col4];
    short4 o;
    o.x = f2bf(bf2f(a.x) + bf2f(b.x) + bb.x);
    o.y = f2bf(bf2f(a.y) + bf2f(b.y) + bb.y);
    o.z = f2bf(bf2f(a.z) + bf2f(b.z) + bb.z);
    o.w = f2bf(bf2f(a.w) + bf2f(b.w) + bb.w);
    ((short4*)UVa)[i] = o;
}

// ---------------------------------------------------------------------------
// Fused pairs + rh: wave-per-row.
// ---------------------------------------------------------------------------
__global__ __launch_bounds__(256) void pairs_rh_kernel(
    const short* __restrict__ UVs,
    const int* __restrict__ sids, const int* __restrict__ oids,
    short* __restrict__ h1,
    const float* __restrict__ rp, const float* __restrict__ R1,
    const float* __restrict__ rb1, short* __restrict__ rh, int b0)
{
    int wave = threadIdx.x >> 6, lane = threadIdx.x & 63;
    int r = blockIdx.x * 4 + wave;
    int b = b0 + r / PAIRS;
    int p = r % PAIRS;

    const bf16x8* us = (const bf16x8*)(UVs + (size_t)(b * NDET + sids[p]) * 2048);
    const bf16x8* uo = (const bf16x8*)(UVs + (size_t)(b * NDET + oids[p]) * 2048 + 1024);
    bf16x8* hrow = (bf16x8*)(h1 + (size_t)r * DH);
#pragma unroll
    for (int i = 0; i < 2; ++i) {
        int idx = lane + i * 64;            // 128 bf16x8 per 1024-elem row
        bf16x8 a = us[idx], c = uo[idx];
        bf16x8 h;
#pragma unroll
        for (int e = 0; e < 8; ++e)
            h[e] = f2bf(fmaxf(bf2f(a[e]) + bf2f(c[e]), 0.0f));
        hrow[idx] = h;
    }

    int rg = b0 * PAIRS + r;
    const float* rowp = rp + (size_t)rg * 12;
    float4 acc = ((const float4*)rb1)[lane];
#pragma unroll
    for (int k = 0; k < 12; ++k) {
        float rv = rowp[k];
        float4 w = ((const float4*)(R1 + k * 256))[lane];
        acc.x = fmaf(rv, w.x, acc.x);
        acc.y = fmaf(rv, w.y, acc.y);
        acc.z = fmaf(rv, w.z, acc.z);
        acc.w = fmaf(rv, w.w, acc.w);
    }
    short4 o;
    o.x = f2bf(fmaxf(acc.x, 0.0f));
    o.y = f2bf(fmaxf(acc.y, 0.0f));
    o.z = f2bf(fmaxf(acc.z, 0.0f));
    o.w = f2bf(fmaxf(acc.w, 0.0f));
    ((short4*)(rh + (size_t)r * 256))[lane] = o;
}

// ---------------------------------------------------------------------------
// Fused row_prep + focal: wave-per-row (logits from extended GEMM columns;
// ||comb||^2 = 2 + 2*rho/(||so||*||re||)).
// ---------------------------------------------------------------------------
__global__ __launch_bounds__(256) void rowprep_focal_kernel(
    const short* __restrict__ so_ext, const short* __restrict__ re_ext,
    const float* __restrict__ traj, const float* __restrict__ temperature,
    const int* __restrict__ sids, const int* __restrict__ oids,
    const int* __restrict__ labels,
    float4* __restrict__ pn, float* __restrict__ dist_arr, int b0)
{
    int wave = threadIdx.x >> 6, lane = threadIdx.x & 63;
    int r = blockIdx.x * 4 + wave;
    int rg = b0 * PAIRS + r;
    int b = b0 + r / PAIRS;
    int p = r % PAIRS;

    const short* srow = so_ext + (size_t)r * NEXT;
    const short* rrow = re_ext + (size_t)r * NEXT;
    bf16x8 sv = *(const bf16x8*)(srow + lane * 8);
    bf16x8 uv = *(const bf16x8*)(rrow + lane * 8);
    float s[8], u[8];
#pragma unroll
    for (int i = 0; i < 8; ++i) { s[i] = bf2f(sv[i]); u[i] = bf2f(uv[i]); }

    const float* tsrc = (lane < 32)
        ? (traj + (size_t)(b * NDET + sids[p]) * EHALF + lane * 8)
        : (traj + (size_t)(b * NDET + oids[p]) * EHALF + (lane - 32) * 8);
    float4 t0 = ((const float4*)tsrc)[0], t1 = ((const float4*)tsrc)[1];
    float t[8] = {t0.x, t0.y, t0.z, t0.w, t1.x, t1.y, t1.z, t1.w};

    float ss = 0.0f, sr = 0.0f, rho = 0.0f, sd = 0.0f;
#pragma unroll
    for (int i = 0; i < 8; ++i) {
        ss  += s[i] * s[i];
        sr  += u[i] * u[i];
        rho += s[i] * u[i];
        sd  += fabsf(t[i] - s[i]);
    }
#pragma unroll
    for (int m = 1; m < 64; m <<= 1) {
        ss  += __shfl_xor(ss, m);
        sr  += __shfl_xor(sr, m);
        rho += __shfl_xor(rho, m);
        sd  += __shfl_xor(sd, m);
    }
    float inv_s = 1.0f / fmaxf(sqrtf(ss), 1e-12f);
    float inv_r = 1.0f / fmaxf(sqrtf(sr), 1e-12f);
    float ncomb = sqrtf(fmaxf(2.0f + 2.0f * rho * inv_s * inv_r, 0.0f));
    float scale = 1.0f / (fmaxf(ncomb, 1e-12f) * temperature[0]);

    float flp = 0.0f, fln = 0.0f, fm = 0.0f;
    size_t labbase = (size_t)rg * LABW;
#pragma unroll
    for (int h = 0; h < 2; ++h) {
        int c = lane + h * 64;
        if (c < NCLS) {
            float l = (bf2f(srow[DE + c]) * inv_s + bf2f(rrow[DE + c]) * inv_r) * scale;
            int tl = labels[labbase + 1 + c];
            if (tl > 0) fm = 1.0f;
            float tf = (float)tl;
            float pr = 1.0f / (1.0f + expf(-l));
            float lg = log1pf(expf(-fabsf(l)));
            float ce = fmaxf(l, 0.0f) - l * tf + lg;
            float pt = pr * tf + (1.0f - pr) * (1.0f - tf);
            float om = 1.0f - pt;
            float at = 0.25f * tf + 0.75f * (1.0f - tf);
            flp += at * ce * om * om;
            float ce0 = fmaxf(l, 0.0f) + lg;
            fln += 0.75f * ce0 * pr * pr;
        }
    }
#pragma unroll
    for (int m = 1; m < 64; m <<= 1) {
        flp += __shfl_xor(flp, m);
        fln += __shfl_xor(fln, m);
        fm  += __shfl_xor(fm, m);
    }
    if (lane == 0) {
        int posf = (fm > 0.5f) ? 1 : 0;
        int negf = (labels[labbase] > 0) ? 1 : 0;
        pn[rg] = make_float4(posf ? flp : 0.0f, negf ? fln : 0.0f, 0.0f,
                             (float)(posf + 2 * negf));
        dist_arr[rg] = sd;
    }
}

// ---------------------------------------------------------------------------
// Two-stage final reduce.
// ---------------------------------------------------------------------------
struct RedRec { double sp, sn, sd; int cp, cn; };
constexpr int RED1 = 64;
constexpr int ROWS_PER_RED = ROWS / RED1;           // 564

__global__ __launch_bounds__(256) void reduce1_kernel(
    const float4* __restrict__ pn, const float* __restrict__ dist_arr,
    RedRec* __restrict__ scratch)
{
    int tid = threadIdx.x;
    int base = blockIdx.x * ROWS_PER_RED;
    double sp = 0.0, sn = 0.0, sd = 0.0;
    int cp = 0, cn = 0;
    for (int i = tid; i < ROWS_PER_RED; i += 256) {
        float4 v = pn[base + i];
        sp += (double)v.x; sn += (double)v.y; sd += (double)dist_arr[base + i];
        int f = (int)v.w;
        cp += f & 1; cn += (f >> 1) & 1;
    }
    __shared__ double A[256], B[256], C[256];
    __shared__ int I[256], J[256];
    A[tid] = sp; B[tid] = sn; C[tid] = sd; I[tid] = cp; J[tid] = cn;
    __syncthreads();
    for (int st = 128; st > 0; st >>= 1) {
        if (tid < st) { A[tid] += A[tid + st]; B[tid] += B[tid + st]; C[tid] += C[tid + st];
                        I[tid] += I[tid + st]; J[tid] += J[tid + st]; }
        __syncthreads();
    }
    if (tid == 0) {
        RedRec rec; rec.sp = A[0]; rec.sn = B[0]; rec.sd = C[0];
        rec.cp = I[0]; rec.cn = J[0];
        scratch[blockIdx.x] = rec;
    }
}

__global__ __launch_bounds__(64) void reduce2_kernel(
    const RedRec* __restrict__ scratch, float* __restrict__ out)
{
    int lane = threadIdx.x;
    RedRec rec = scratch[lane];
    double sp = rec.sp, sn = rec.sn, sd = rec.sd;
    int cp = rec.cp, cn = rec.cn;
#pragma unroll
    for (int m = 1; m < 64; m <<= 1) {
        sp += __shfl_xor(sp, m);
        sn += __shfl_xor(sn, m);
        sd += __shfl_xor(sd, m);
        cp += __shfl_xor(cp, m);
        cn += __shfl_xor(cn, m);
    }
    if (lane == 0) {
        int cpv = cp < 1 ? 1 : cp;
        int cnv = cn < 1 ? 1 : cn;
        out[0] = (float)(sp / ((double)cpv * NCLS) +
                         sn / ((double)cnv * NCLS) +
                         sd / ((double)ROWS * DE));
    }
}

extern "C" void kernel_launch(void* const* d_in, const int* in_sizes, int n_in,
                              void* d_out, int out_size, void* d_ws, size_t ws_size,
                              hipStream_t stream)
{
    const float* det    = (const float*)d_in[0];
    const float* traj   = (const float*)d_in[1];
    const float* relpos = (const float*)d_in[2];
    const float* cw     = (const float*)d_in[3];
    const float* W1     = (const float*)d_in[4];
    const float* b1     = (const float*)d_in[5];
    const float* W2     = (const float*)d_in[6];
    const float* b2     = (const float*)d_in[7];
    const float* W3     = (const float*)d_in[8];
    const float* R1     = (const float*)d_in[9];
    const float* rb1    = (const float*)d_in[10];
    const float* R2     = (const float*)d_in[11];
    const float* temp   = (const float*)d_in[12];
    const int*   labels = (const int*)d_in[13];
    const int*   sids   = (const int*)d_in[14];
    const int*   oids   = (const int*)d_in[15];
    float* out = (float*)d_out;

    // ---- Workspace carve --------------------------------------------------
    char* ws = (char*)d_ws;
    size_t off = 0;
    auto carve = [&](size_t bytes) -> char* {
        char* p = ws + off;
        off = (off + bytes + 255) & ~(size_t)255;
        return p;
    };
    float4* pn       = (float4*)carve((size_t)ROWS * 16);
    float*  dist_arr = (float*)carve((size_t)ROWS * 4);
    short*  det_bf   = (short*)carve((size_t)BSZ * NDET * DF * 2);
    short*  W1t      = (short*)carve((size_t)2048 * 2048 * 2);
    short*  W2t      = (short*)carve((size_t)DH * DH * 2);
    short*  W3t      = (short*)carve((size_t)NPAD * DH * 2);      // [768][1024], rows 640+ garbage
    short*  R2t      = (short*)carve((size_t)NPAD * 256 * 2);     // [768][256],  rows 640+ garbage
    short*  cwt      = (short*)carve((size_t)128 * DE * 2);
    short*  W3bf     = (short*)carve((size_t)DH * DE * 2);
    short*  R2bf     = (short*)carve((size_t)256 * DE * 2);
    short*  UVa      = (short*)carve((size_t)BSZ * NDET * 2048 * 2);
    short*  UVb      = (short*)carve((size_t)BSZ * NDET * 2048 * 2);
    RedRec* red_scratch = (RedRec*)carve((size_t)RED1 * sizeof(RedRec));
    size_t fixed_off = off;

    int b_ch = 1;
    for (int cand : {16, 8, 4, 2, 1}) {
        size_t rows  = (size_t)cand * PAIRS;
        size_t bytes = fixed_off + rows * 2048 + 256 + rows * 2048 + 256
                     + rows * 512 + 256 + rows * 1280 + 256;
        if (bytes <= ws_size) { b_ch = cand; break; }
    }
    const int chunk_rows = b_ch * PAIRS;
    const int n_chunks = BSZ / b_ch;
    char* reg1 = carve((size_t)chunk_rows * 2048);
    char* reg2 = carve((size_t)chunk_rows * 2048);
    char* reg3 = carve((size_t)chunk_rows * 512);
    char* reg4 = carve((size_t)chunk_rows * 1280);

    short* h1     = (short*)reg1;
    short* h2     = (short*)reg2;
    short* so_ext = (short*)reg1;     // overwrites h1 (dead after h2 GEMM)
    short* rh     = (short*)reg3;
    short* re_ext = (short*)reg4;     // own region (R10 race fix)

    // ---- Prep (1 launch) --------------------------------------------------
    TransJobs tj;
    tj.src[0] = W1;                    tj.dst[0] = W1t;                   tj.K[0] = DF;  tj.N[0] = DH;
    tj.src[1] = W1 + (size_t)DF * DH;  tj.dst[1] = W1t + (size_t)DH * DF; tj.K[1] = DF;  tj.N[1] = DH;
    tj.src[2] = W2;                    tj.dst[2] = W2t;                   tj.K[2] = DH;  tj.N[2] = DH;
    tj.src[3] = W3;                    tj.dst[3] = W3t;                   tj.K[3] = DH;  tj.N[3] = DE;
    tj.src[4] = R2;                    tj.dst[4] = R2t;                   tj.K[4] = 256; tj.N[4] = DE;
    tj.cum[0] = 0;
    for (int i = 0; i < 5; ++i)
        tj.cum[i + 1] = tj.cum[i] + (tj.K[i] / 32) * (tj.N[i] / 32);
    prep_kernel<<<NCONVB + tj.cum[5], 256, 0, stream>>>(
        det, det_bf, cw, cwt, W3, W3bf, R2, R2bf, tj);

    // One multi-job GEMM launch: UV split-K halves + classifier projections.
    GemmJobs gj;
    gj.A[0] = det_bf;        gj.Bt[0] = W1t;        gj.C[0] = UVa;
    gj.M[0] = BSZ * NDET;    gj.N[0] = 2048;        gj.K[0] = 1024;
    gj.lda[0] = 2048;        gj.ldb[0] = 2048;
    gj.A[1] = det_bf + 1024; gj.Bt[1] = W1t + 1024; gj.C[1] = UVb;
    gj.M[1] = BSZ * NDET;    gj.N[1] = 2048;        gj.K[1] = 1024;
    gj.lda[1] = 2048;        gj.ldb[1] = 2048;
    gj.A[2] = cwt;           gj.Bt[2] = W3bf;       gj.C[2] = W3t + (size_t)512 * DH;
    gj.M[2] = 128;           gj.N[2] = 1024;        gj.K[2] = 512;
    gj.lda[2] = 512;         gj.ldb[2] = 512;
    gj.A[3] = cwt;           gj.Bt[3] = R2bf;       gj.C[3] = R2t + (size_t)512 * 256;
    gj.M[3] = 128;           gj.N[3] = 256;         gj.K[3] = 512;
    gj.lda[3] = 512;         gj.ldb[3] = 512;
    gj.cum[0] = 0;
    for (int i = 0; i < 4; ++i)
        gj.cum[i + 1] = gj.cum[i] + (gj.N[i] / 128) * ((gj.M[i] + 127) / 128);
    mfma_gemm_multi<<<gj.cum[4], 256, 0, stream>>>(gj);   // 202 blocks

    // Merge: UVa += UVb + b1 (in-place)
    uvmerge_kernel<<<(N4UV + 255) / 256, 256, 0, stream>>>(UVa, UVb, b1);

    const int mt = (chunk_rows + 255) / 256;          // 256-row tiles

    for (int c = 0; c < n_chunks; ++c) {
        int b0 = c * b_ch;

        pairs_rh_kernel<<<chunk_rows / 4, 256, 0, stream>>>(
            UVa, sids, oids, h1, relpos, R1, rb1, rh, b0);

        // h2 = bf16(relu(h1 @ W2 + b2))  — 4-phase 256^2, XCD-chunked
        gemm256<true, true, false><<<mt * 4, 512, 0, stream>>>(
            h1, W2t, b2, h2, chunk_rows, DH, DH, DH, DH, 4, 0,
            nullptr, nullptr, nullptr, 0, 0, 0, 0, 0, 0);

        // so_ext = bf16(h2 @ [W3 | W3·cw^T]) ; re_ext = bf16(rh @ [R2 | R2·cw^T])
        // B padded to 768 rows; epilogue masks cols >= 640. so first (long K).
        gemm256<false, false, true><<<mt * 6, 512, 0, stream>>>(
            h2, W3t, nullptr, so_ext, chunk_rows, NEXT, DH, DH, DH, 3, mt * 3,
            rh, R2t, re_ext, chunk_rows, NEXT, 256, 256, 256, 3);

        rowprep_focal_kernel<<<chunk_rows / 4, 256, 0, stream>>>(
            so_ext, re_ext, traj, temp, sids, oids, labels, pn, dist_arr, b0);
    }

    reduce1_kernel<<<RED1, 256, 0, stream>>>(pn, dist_arr, red_scratch);
    reduce2_kernel<<<1, 64, 0, stream>>>(red_scratch, out);
}

// Round 3
// 385.670 us; speedup vs baseline: 1.0309x; 1.0058x over previous
//
#include <hip/hip_runtime.h>
#include <math.h>

// Problem constants
constexpr int BSZ   = 16;
constexpr int NDET  = 48;
constexpr int PAIRS = NDET * (NDET - 1);      // 2256
constexpr int ROWS  = BSZ * PAIRS;            // 36096
constexpr int DF    = 2048;
constexpr int DH    = 1024;
constexpr int DE    = 512;
constexpr int EHALF = 256;
constexpr int NCLS  = 92;
constexpr int NEXT  = DE + 128;               // 640: so/re GEMM width incl. classifier cols
constexpr int LABW  = 1 + 92 + 40;            // 133

typedef __attribute__((ext_vector_type(8))) short bf16x8;   // 8 bf16 in 4 VGPRs
typedef __attribute__((ext_vector_type(4))) float f32x4;

__device__ __forceinline__ short f2bf(float f) {
    union { float f; unsigned u; } a; a.f = f;
    unsigned r = a.u + 0x7fffu + ((a.u >> 16) & 1u);   // RNE
    return (short)(r >> 16);
}
__device__ __forceinline__ float bf2f(short h) {
    union { unsigned u; float f; } x;
    x.u = ((unsigned)(unsigned short)h) << 16;
    return x.f;
}

// ---------------------------------------------------------------------------
// Merged prep. Elementwise ranges: det conv | cwt build | W3->bf16 | R2->bf16;
// then 5-job transpose (W1 top/bot, W2, W3, R2).
// ---------------------------------------------------------------------------
constexpr int N4DET = BSZ * NDET * DF / 4;    // 393216
constexpr int N4CWT = 128 * DE / 4;           // 16384
constexpr int N4W3  = DH * DE / 4;            // 131072
constexpr int N4R2  = 256 * DE / 4;           // 32768
constexpr int NCONVB = (N4DET + N4CWT + N4W3 + N4R2) / 256;   // 2240

struct TransJobs {
    const float* src[5];
    short*       dst[5];
    int K[5], N[5];
    int cum[6];
};

__global__ __launch_bounds__(256) void prep_kernel(
    const float* __restrict__ det, short* __restrict__ det_bf,
    const float* __restrict__ cw, short* __restrict__ cwt,
    const float* __restrict__ W3, short* __restrict__ W3bf,
    const float* __restrict__ R2, short* __restrict__ R2bf,
    TransJobs jobs)
{
    if (blockIdx.x < NCONVB) {
        int i = blockIdx.x * 256 + threadIdx.x;
        const float* src; short* dst; int k;
        if (i < N4DET) { src = det; dst = det_bf; k = i; }
        else if (i < N4DET + N4CWT) {
            k = i - N4DET;
            int n = (k * 4) >> 9;
            short4 o = {0, 0, 0, 0};
            if (n < NCLS) {
                float4 v = ((const float4*)cw)[k];
                o.x = f2bf(v.x); o.y = f2bf(v.y); o.z = f2bf(v.z); o.w = f2bf(v.w);
            }
            ((short4*)cwt)[k] = o;
            return;
        }
        else if (i < N4DET + N4CWT + N4W3) { src = W3; dst = W3bf; k = i - N4DET - N4CWT; }
        else { src = R2; dst = R2bf; k = i - N4DET - N4CWT - N4W3; }
        float4 v = ((const float4*)src)[k];
        short4 o;
        o.x = f2bf(v.x); o.y = f2bf(v.y); o.z = f2bf(v.z); o.w = f2bf(v.w);
        ((short4*)dst)[k] = o;
        return;
    }
    __shared__ float tile[32][33];
    int t = blockIdx.x - NCONVB;
    int j = 0;
    while (t >= jobs.cum[j + 1]) ++j;
    int lt = t - jobs.cum[j];
    int K = jobs.K[j], N = jobs.N[j];
    int nx = N >> 5;
    int ky = lt / nx, nxi = lt - ky * nx;
    int n0 = nxi * 32, k0 = ky * 32;
    const float* src = jobs.src[j];
    short* dst = jobs.dst[j];
    int tx = threadIdx.x & 31, ty = threadIdx.x >> 5;
#pragma unroll
    for (int i = ty; i < 32; i += 8)
        tile[i][tx] = src[(size_t)(k0 + i) * N + n0 + tx];
    __syncthreads();
#pragma unroll
    for (int i = ty; i < 32; i += 8)
        dst[(size_t)(n0 + i) * K + k0 + tx] = f2bf(tile[tx][i]);
}

// ---------------------------------------------------------------------------
// MFMA GEMM (BK=64 as two 128x32 halves; R9-verified 2-phase 128^2 structure;
// measured 847 TF on the h2 shape — the proven baseline).
// ---------------------------------------------------------------------------
__device__ __forceinline__ void load16_lds(const void* g, void* l) {
    __builtin_amdgcn_global_load_lds(
        (const __attribute__((address_space(1))) unsigned int*)g,
        (__attribute__((address_space(3))) unsigned int*)l, 16, 0, 0);
}

#define MFMA16 __builtin_amdgcn_mfma_f32_16x16x32_bf16

template <bool BIAS, bool RELU, bool OUTBF16, bool SWIZZLE, bool DUAL>
__global__ __launch_bounds__(256, 4) void mfma_gemm(
    const short* __restrict__ A, const short* __restrict__ Bt,
    const float* __restrict__ bias, void* __restrict__ C,
    int M, int N, int K, int lda, int ldb,
    const short* A2, const short* Bt2, void* C2, int nsplit,
    int K2, int lda2, int ldb2, int N2)
{
    __shared__ __align__(16) char smem_raw[32768];   // As 16KB | Bs 16KB
    short* As = (short*)smem_raw;
    short* Bs = As + 128 * 64;

    int bx, by;
    if (SWIZZLE) {
        int nb  = gridDim.x;
        int gid = blockIdx.y * nb + blockIdx.x;
        int xcd = gid & 7;
        int j   = gid >> 3;
        int rows_per = gridDim.y >> 3;
        int lr  = j / nb;
        bx = j - lr * nb;
        by = xcd * rows_per + lr;
    } else {
        bx = blockIdx.x; by = blockIdx.y;
    }
    if (DUAL && bx >= nsplit) {
        bx -= nsplit; A = A2; Bt = Bt2; C = C2;
        K = K2; lda = lda2; ldb = ldb2; N = N2;
    }
    if (by * 128 >= M) return;                      // padded tail

    const int tid  = threadIdx.x;
    const int wave = tid >> 6;
    const int lane = tid & 63;
    const int m0 = by * 128;
    const int n0 = bx * 128;
    const int wm = (wave & 1) * 64;
    const int wn = (wave >> 1) * 64;

    f32x4 acc[4][4] = {};

    const int q  = lane >> 4;
    const int lm = lane & 15;

    for (int k0 = 0; k0 < K; k0 += 64) {
#pragma unroll
        for (int it = 0; it < 4; ++it) {
            int c    = (it & 1) * 256 + tid;
            int half = it >> 1;
            int row  = c >> 2;
            int kk   = (c & 3) * 8 + half * 32;
            int ldsc = half * 4096 + ((it & 1) * 256 + wave * 64) * 8;
            int gm = m0 + row; if (gm >= M) gm = M - 1;
            load16_lds(A + (size_t)gm * lda + k0 + kk, As + ldsc);
            int gn = n0 + row;                       // N%128==0: no tail
            load16_lds(Bt + (size_t)gn * ldb + k0 + kk, Bs + ldsc);
        }
        __syncthreads();

#pragma unroll
        for (int half = 0; half < 2; ++half) {
            const short* Ah = As + half * 4096;
            const short* Bh = Bs + half * 4096;
            bf16x8 af[4], bfr[4];
#pragma unroll
            for (int t = 0; t < 4; ++t) {
                af[t]  = *(const bf16x8*)(Ah + (wm + t * 16 + lm) * 32 + q * 8);
                bfr[t] = *(const bf16x8*)(Bh + (wn + t * 16 + lm) * 32 + q * 8);
            }
#pragma unroll
            for (int tm = 0; tm < 4; ++tm)
#pragma unroll
                for (int tn = 0; tn < 4; ++tn)
                    acc[tm][tn] = MFMA16(af[tm], bfr[tn], acc[tm][tn], 0, 0, 0);
        }
        __syncthreads();
    }

    // C/D layout: col=lane&15, row=(lane>>4)*4+reg (m89-verified)
    if (OUTBF16) {
        float* scratch = (float*)smem_raw + wave * (16 * 68);
#pragma unroll
        for (int tm = 0; tm < 4; ++tm) {
            __syncthreads();
#pragma unroll
            for (int tn = 0; tn < 4; ++tn) {
                float bv = BIAS ? bias[n0 + wn + tn * 16 + lm] : 0.0f;
#pragma unroll
                for (int r = 0; r < 4; ++r) {
                    float v = acc[tm][tn][r] + bv;
                    if (RELU) v = fmaxf(v, 0.0f);
                    scratch[(q * 4 + r) * 68 + tn * 16 + lm] = v;
                }
            }
            __syncthreads();
#pragma unroll
            for (int p = 0; p < 2; ++p) {
                int row16 = (lane >> 3) + p * 8;
                int c0 = (lane & 7) * 8;
                float4 v0 = *(float4*)&scratch[row16 * 68 + c0];
                float4 v1 = *(float4*)&scratch[row16 * 68 + c0 + 4];
                bf16x8 o;
                o[0] = f2bf(v0.x); o[1] = f2bf(v0.y); o[2] = f2bf(v0.z); o[3] = f2bf(v0.w);
                o[4] = f2bf(v1.x); o[5] = f2bf(v1.y); o[6] = f2bf(v1.z); o[7] = f2bf(v1.w);
                int grow = m0 + wm + tm * 16 + row16;
                if (grow < M)
                    *(bf16x8*)((short*)C + (size_t)grow * N + n0 + wn + c0) = o;
            }
        }
    } else {
#pragma unroll
        for (int tm = 0; tm < 4; ++tm)
#pragma unroll
            for (int tn = 0; tn < 4; ++tn) {
                int col = n0 + wn + tn * 16 + lm;
#pragma unroll
                for (int r = 0; r < 4; ++r) {
                    int row = m0 + wm + tm * 16 + q * 4 + r;
                    if (row < M) {
                        float v = acc[tm][tn][r];
                        if (BIAS) v += bias[col];
                        if (RELU) v = fmaxf(v, 0.0f);
                        ((float*)C)[(size_t)row * N + col] = v;
                    }
                }
            }
    }
}

// ---------------------------------------------------------------------------
// R16: h2 GEMM with FUSED A-staging. A-row r = relu(U[b,s[p]] + V[b,o[p]])
// built on the fly from the merged UV buffer (3.1 MB, L2-hot) — h1 (74 MB)
// is never materialized. Bit-identical math to the old pairs_rh h1 path.
// B-side stays global_load_lds. __launch_bounds__(256,3): fused staging adds
// ~40 VGPRs over the base kernel's 124 unified (which sat at the 4-wave cap).
// ---------------------------------------------------------------------------
__global__ __launch_bounds__(256, 3) void gemm_h2f(
    const short* __restrict__ UV,
    const int* __restrict__ sids, const int* __restrict__ oids,
    const short* __restrict__ Bt, const float* __restrict__ bias,
    short* __restrict__ C, int M, int rowbase)
{
    __shared__ __align__(16) char smem_raw[32768];   // As 16KB | Bs 16KB
    short* As = (short*)smem_raw;
    short* Bs = As + 128 * 64;

    int nb  = gridDim.x;
    int gid = blockIdx.y * nb + blockIdx.x;
    int xcd = gid & 7;
    int j   = gid >> 3;
    int rows_per = gridDim.y >> 3;
    int lr  = j / nb;
    int bx = j - lr * nb;
    int by = xcd * rows_per + lr;
    if (by * 128 >= M) return;

    const int tid  = threadIdx.x;
    const int wave = tid >> 6;
    const int lane = tid & 63;
    const int m0 = by * 128;
    const int n0 = bx * 128;
    const int wm = (wave & 1) * 64;
    const int wn = (wave >> 1) * 64;

    // fused-A setup: thread owns tile rows (tid>>2) and (tid>>2)+64 at
    // k-chunk cq = tid&3 (kk = cq*8 and cq*8+32 per 64-wide K-step).
    const int cq = tid & 3;
    int lr0 = m0 + (tid >> 2); if (lr0 >= M) lr0 = M - 1;
    int lr1 = lr0 + 64;        if (lr1 >= M) lr1 = M - 1;
    int rg0 = rowbase + lr0, rg1 = rowbase + lr1;
    int b0 = rg0 / PAIRS, p0 = rg0 - b0 * PAIRS;
    int b1 = rg1 / PAIRS, p1 = rg1 - b1 * PAIRS;
    const short* u0 = UV + (size_t)(b0 * NDET + sids[p0]) * 2048;
    const short* v0 = UV + (size_t)(b0 * NDET + oids[p0]) * 2048 + 1024;
    const short* u1 = UV + (size_t)(b1 * NDET + sids[p1]) * 2048;
    const short* v1 = UV + (size_t)(b1 * NDET + oids[p1]) * 2048 + 1024;

    f32x4 acc[4][4] = {};
    const int q  = lane >> 4;
    const int lm = lane & 15;

    for (int k0 = 0; k0 < DH; k0 += 64) {
        // B staging: 4x global_load_lds (unchanged layout)
#pragma unroll
        for (int it = 0; it < 4; ++it) {
            int c    = (it & 1) * 256 + tid;
            int half = it >> 1;
            int row  = c >> 2;
            int kk   = (c & 3) * 8 + half * 32;
            int ldsc = half * 4096 + ((it & 1) * 256 + wave * 64) * 8;
            load16_lds(Bt + (size_t)(n0 + row) * DH + k0 + kk, Bs + ldsc);
        }
        // A fused: 8 reg loads (L2-hot UV), add+relu+RNE-pack, 4 ds_writes.
        int ka = k0 + cq * 8;
        bf16x8 ua0 = *(const bf16x8*)(u0 + ka),      va0 = *(const bf16x8*)(v0 + ka);
        bf16x8 ua1 = *(const bf16x8*)(u1 + ka),      va1 = *(const bf16x8*)(v1 + ka);
        bf16x8 ub0 = *(const bf16x8*)(u0 + ka + 32), vb0 = *(const bf16x8*)(v0 + ka + 32);
        bf16x8 ub1 = *(const bf16x8*)(u1 + ka + 32), vb1 = *(const bf16x8*)(v1 + ka + 32);
        bf16x8 w0, w1, w2, w3;
#pragma unroll
        for (int e = 0; e < 8; ++e) {
            w0[e] = f2bf(fmaxf(bf2f(ua0[e]) + bf2f(va0[e]), 0.0f));
            w1[e] = f2bf(fmaxf(bf2f(ua1[e]) + bf2f(va1[e]), 0.0f));
            w2[e] = f2bf(fmaxf(bf2f(ub0[e]) + bf2f(vb0[e]), 0.0f));
            w3[e] = f2bf(fmaxf(bf2f(ub1[e]) + bf2f(vb1[e]), 0.0f));
        }
        // slot LDS short-offset = half*4096 + c*8  (c = (it&1)*256 + tid)
        *(bf16x8*)(As + tid * 8)                = w0;
        *(bf16x8*)(As + (256 + tid) * 8)        = w1;
        *(bf16x8*)(As + 4096 + tid * 8)         = w2;
        *(bf16x8*)(As + 4096 + (256 + tid) * 8) = w3;
        __syncthreads();

#pragma unroll
        for (int half = 0; half < 2; ++half) {
            const short* Ah = As + half * 4096;
            const short* Bh = Bs + half * 4096;
            bf16x8 af[4], bfr[4];
#pragma unroll
            for (int t = 0; t < 4; ++t) {
                af[t]  = *(const bf16x8*)(Ah + (wm + t * 16 + lm) * 32 + q * 8);
                bfr[t] = *(const bf16x8*)(Bh + (wn + t * 16 + lm) * 32 + q * 8);
            }
#pragma unroll
            for (int tm = 0; tm < 4; ++tm)
#pragma unroll
                for (int tn = 0; tn < 4; ++tn)
                    acc[tm][tn] = MFMA16(af[tm], bfr[tn], acc[tm][tn], 0, 0, 0);
        }
        __syncthreads();
    }

    // epilogue: bias+relu, bf16 out (h2)
    float* scratch = (float*)smem_raw + wave * (16 * 68);
#pragma unroll
    for (int tm = 0; tm < 4; ++tm) {
        __syncthreads();
#pragma unroll
        for (int tn = 0; tn < 4; ++tn) {
            float bv = bias[n0 + wn + tn * 16 + lm];
#pragma unroll
            for (int r = 0; r < 4; ++r) {
                float v = fmaxf(acc[tm][tn][r] + bv, 0.0f);
                scratch[(q * 4 + r) * 68 + tn * 16 + lm] = v;
            }
        }
        __syncthreads();
#pragma unroll
        for (int p = 0; p < 2; ++p) {
            int row16 = (lane >> 3) + p * 8;
            int c0 = (lane & 7) * 8;
            float4 x0 = *(float4*)&scratch[row16 * 68 + c0];
            float4 x1 = *(float4*)&scratch[row16 * 68 + c0 + 4];
            bf16x8 o;
            o[0] = f2bf(x0.x); o[1] = f2bf(x0.y); o[2] = f2bf(x0.z); o[3] = f2bf(x0.w);
            o[4] = f2bf(x1.x); o[5] = f2bf(x1.y); o[6] = f2bf(x1.z); o[7] = f2bf(x1.w);
            int grow = m0 + wm + tm * 16 + row16;
            if (grow < M)
                *(bf16x8*)(C + (size_t)grow * DH + n0 + wn + c0) = o;
        }
    }
}

// ---------------------------------------------------------------------------
// Multi-job GEMM (up to 4 independent bf16-out jobs, flat 1-D grid).
// ---------------------------------------------------------------------------
struct GemmJobs {
    const short* A[4]; const short* Bt[4]; short* C[4];
    int M[4], N[4], K[4], lda[4], ldb[4];
    int cum[5];
};

__global__ __launch_bounds__(256, 4) void mfma_gemm_multi(GemmJobs jobs)
{
    __shared__ __align__(16) char smem_raw[32768];
    short* As = (short*)smem_raw;
    short* Bs = As + 128 * 64;

    int bid = blockIdx.x;
    int j = 0;
    while (bid >= jobs.cum[j + 1]) ++j;             // <=4, block-uniform
    int lt = bid - jobs.cum[j];
    const short* A  = jobs.A[j];
    const short* Bt = jobs.Bt[j];
    short* C = jobs.C[j];
    int M = jobs.M[j], N = jobs.N[j], K = jobs.K[j];
    int lda = jobs.lda[j], ldb = jobs.ldb[j];
    int ncols = N >> 7;
    int by = lt / ncols;
    int bx = lt - by * ncols;

    const int tid  = threadIdx.x;
    const int wave = tid >> 6;
    const int lane = tid & 63;
    const int m0 = by * 128;
    const int n0 = bx * 128;
    const int wm = (wave & 1) * 64;
    const int wn = (wave >> 1) * 64;

    f32x4 acc[4][4] = {};
    const int q  = lane >> 4;
    const int lm = lane & 15;

    for (int k0 = 0; k0 < K; k0 += 64) {
#pragma unroll
        for (int it = 0; it < 4; ++it) {
            int c    = (it & 1) * 256 + tid;
            int half = it >> 1;
            int row  = c >> 2;
            int kk   = (c & 3) * 8 + half * 32;
            int ldsc = half * 4096 + ((it & 1) * 256 + wave * 64) * 8;
            int gm = m0 + row; if (gm >= M) gm = M - 1;
            load16_lds(A + (size_t)gm * lda + k0 + kk, As + ldsc);
            load16_lds(Bt + (size_t)(n0 + row) * ldb + k0 + kk, Bs + ldsc);
        }
        __syncthreads();
#pragma unroll
        for (int half = 0; half < 2; ++half) {
            const short* Ah = As + half * 4096;
            const short* Bh = Bs + half * 4096;
            bf16x8 af[4], bfr[4];
#pragma unroll
            for (int t = 0; t < 4; ++t) {
                af[t]  = *(const bf16x8*)(Ah + (wm + t * 16 + lm) * 32 + q * 8);
                bfr[t] = *(const bf16x8*)(Bh + (wn + t * 16 + lm) * 32 + q * 8);
            }
#pragma unroll
            for (int tm = 0; tm < 4; ++tm)
#pragma unroll
                for (int tn = 0; tn < 4; ++tn)
                    acc[tm][tn] = MFMA16(af[tm], bfr[tn], acc[tm][tn], 0, 0, 0);
        }
        __syncthreads();
    }

    float* scratch = (float*)smem_raw + wave * (16 * 68);
#pragma unroll
    for (int tm = 0; tm < 4; ++tm) {
        __syncthreads();
#pragma unroll
        for (int tn = 0; tn < 4; ++tn)
#pragma unroll
            for (int r = 0; r < 4; ++r)
                scratch[(q * 4 + r) * 68 + tn * 16 + lm] = acc[tm][tn][r];
        __syncthreads();
#pragma unroll
        for (int p = 0; p < 2; ++p) {
            int row16 = (lane >> 3) + p * 8;
            int c0 = (lane & 7) * 8;
            float4 v0 = *(float4*)&scratch[row16 * 68 + c0];
            float4 v1 = *(float4*)&scratch[row16 * 68 + c0 + 4];
            bf16x8 o;
            o[0] = f2bf(v0.x); o[1] = f2bf(v0.y); o[2] = f2bf(v0.z); o[3] = f2bf(v0.w);
            o[4] = f2bf(v1.x); o[5] = f2bf(v1.y); o[6] = f2bf(v1.z); o[7] = f2bf(v1.w);
            int grow = m0 + wm + tm * 16 + row16;
            if (grow < M)
                *(bf16x8*)(C + (size_t)grow * N + n0 + wn + c0) = o;
        }
    }
}

// ---------------------------------------------------------------------------
// UV merge (in-place): UVa = UVa + UVb + b1 (U-half cols only).
// ---------------------------------------------------------------------------
constexpr int N4UV = BSZ * NDET * 2048 / 4;   // 393216 short4s
__global__ __launch_bounds__(256) void uvmerge_kernel(
    short* __restrict__ UVa, const short* __restrict__ UVb,
    const float* __restrict__ b1)
{
    int i = blockIdx.x * 256 + threadIdx.x;
    if (i >= N4UV) return;
    short4 a = ((const short4*)UVa)[i];
    short4 b = ((const short4*)UVb)[i];
    int col4 = i & 511;
    float4 bb = {0.0f, 0.0f, 0.0f, 0.0f};
    if (col4 < 256) bb = ((const float4*)b1)[col4];
    short4 o;
    o.x = f2bf(bf2f(a.x) + bf2f(b.x) + bb.x);
    o.y = f2bf(bf2f(a.y) + bf2f(b.y) + bb.y);
    o.z = f2bf(bf2f(a.z) + bf2f(b.z) + bb.z);
    o.w = f2bf(bf2f(a.w) + bf2f(b.w) + bb.w);
    ((short4*)UVa)[i] = o;
}

// ---------------------------------------------------------------------------
// rh only (h1 now fused into gemm_h2f): wave-per-row R1 matvec.
// ---------------------------------------------------------------------------
__global__ __launch_bounds__(256) void rh_kernel(
    const float* __restrict__ rp, const float* __restrict__ R1,
    const float* __restrict__ rb1, short* __restrict__ rh, int b0)
{
    int wave = threadIdx.x >> 6, lane = threadIdx.x & 63;
    int r = blockIdx.x * 4 + wave;
    int rg = b0 * PAIRS + r;

    const float* rowp = rp + (size_t)rg * 12;
    float4 acc = ((const float4*)rb1)[lane];
#pragma unroll
    for (int k = 0; k < 12; ++k) {
        float rv = rowp[k];
        float4 w = ((const float4*)(R1 + k * 256))[lane];
        acc.x = fmaf(rv, w.x, acc.x);
        acc.y = fmaf(rv, w.y, acc.y);
        acc.z = fmaf(rv, w.z, acc.z);
        acc.w = fmaf(rv, w.w, acc.w);
    }
    short4 o;
    o.x = f2bf(fmaxf(acc.x, 0.0f));
    o.y = f2bf(fmaxf(acc.y, 0.0f));
    o.z = f2bf(fmaxf(acc.z, 0.0f));
    o.w = f2bf(fmaxf(acc.w, 0.0f));
    ((short4*)(rh + (size_t)r * 256))[lane] = o;
}

// ---------------------------------------------------------------------------
// Fused row_prep + focal: wave-per-row (logits from extended GEMM columns;
// ||comb||^2 = 2 + 2*rho/(||so||*||re||)).
// ---------------------------------------------------------------------------
__global__ __launch_bounds__(256) void rowprep_focal_kernel(
    const short* __restrict__ so_ext, const short* __restrict__ re_ext,
    const float* __restrict__ traj, const float* __restrict__ temperature,
    const int* __restrict__ sids, const int* __restrict__ oids,
    const int* __restrict__ labels,
    float4* __restrict__ pn, float* __restrict__ dist_arr, int b0)
{
    int wave = threadIdx.x >> 6, lane = threadIdx.x & 63;
    int r = blockIdx.x * 4 + wave;
    int rg = b0 * PAIRS + r;
    int b = b0 + r / PAIRS;
    int p = r % PAIRS;

    const short* srow = so_ext + (size_t)r * NEXT;
    const short* rrow = re_ext + (size_t)r * NEXT;
    bf16x8 sv = *(const bf16x8*)(srow + lane * 8);
    bf16x8 uv = *(const bf16x8*)(rrow + lane * 8);
    float s[8], u[8];
#pragma unroll
    for (int i = 0; i < 8; ++i) { s[i] = bf2f(sv[i]); u[i] = bf2f(uv[i]); }

    const float* tsrc = (lane < 32)
        ? (traj + (size_t)(b * NDET + sids[p]) * EHALF + lane * 8)
        : (traj + (size_t)(b * NDET + oids[p]) * EHALF + (lane - 32) * 8);
    float4 t0 = ((const float4*)tsrc)[0], t1 = ((const float4*)tsrc)[1];
    float t[8] = {t0.x, t0.y, t0.z, t0.w, t1.x, t1.y, t1.z, t1.w};

    float ss = 0.0f, sr = 0.0f, rho = 0.0f, sd = 0.0f;
#pragma unroll
    for (int i = 0; i < 8; ++i) {
        ss  += s[i] * s[i];
        sr  += u[i] * u[i];
        rho += s[i] * u[i];
        sd  += fabsf(t[i] - s[i]);
    }
#pragma unroll
    for (int m = 1; m < 64; m <<= 1) {
        ss  += __shfl_xor(ss, m);
        sr  += __shfl_xor(sr, m);
        rho += __shfl_xor(rho, m);
        sd  += __shfl_xor(sd, m);
    }
    float inv_s = 1.0f / fmaxf(sqrtf(ss), 1e-12f);
    float inv_r = 1.0f / fmaxf(sqrtf(sr), 1e-12f);
    float ncomb = sqrtf(fmaxf(2.0f + 2.0f * rho * inv_s * inv_r, 0.0f));
    float scale = 1.0f / (fmaxf(ncomb, 1e-12f) * temperature[0]);

    float flp = 0.0f, fln = 0.0f, fm = 0.0f;
    size_t labbase = (size_t)rg * LABW;
#pragma unroll
    for (int h = 0; h < 2; ++h) {
        int c = lane + h * 64;
        if (c < NCLS) {
            float l = (bf2f(srow[DE + c]) * inv_s + bf2f(rrow[DE + c]) * inv_r) * scale;
            int tl = labels[labbase + 1 + c];
            if (tl > 0) fm = 1.0f;
            float tf = (float)tl;
            float pr = 1.0f / (1.0f + expf(-l));
            float lg = log1pf(expf(-fabsf(l)));
            float ce = fmaxf(l, 0.0f) - l * tf + lg;
            float pt = pr * tf + (1.0f - pr) * (1.0f - tf);
            float om = 1.0f - pt;
            float at = 0.25f * tf + 0.75f * (1.0f - tf);
            flp += at * ce * om * om;
            float ce0 = fmaxf(l, 0.0f) + lg;
            fln += 0.75f * ce0 * pr * pr;
        }
    }
#pragma unroll
    for (int m = 1; m < 64; m <<= 1) {
        flp += __shfl_xor(flp, m);
        fln += __shfl_xor(fln, m);
        fm  += __shfl_xor(fm, m);
    }
    if (lane == 0) {
        int posf = (fm > 0.5f) ? 1 : 0;
        int negf = (labels[labbase] > 0) ? 1 : 0;
        pn[rg] = make_float4(posf ? flp : 0.0f, negf ? fln : 0.0f, 0.0f,
                             (float)(posf + 2 * negf));
        dist_arr[rg] = sd;
    }
}

// ---------------------------------------------------------------------------
// Two-stage final reduce.
// ---------------------------------------------------------------------------
struct RedRec { double sp, sn, sd; int cp, cn; };
constexpr int RED1 = 64;
constexpr int ROWS_PER_RED = ROWS / RED1;           // 564

__global__ __launch_bounds__(256) void reduce1_kernel(
    const float4* __restrict__ pn, const float* __restrict__ dist_arr,
    RedRec* __restrict__ scratch)
{
    int tid = threadIdx.x;
    int base = blockIdx.x * ROWS_PER_RED;
    double sp = 0.0, sn = 0.0, sd = 0.0;
    int cp = 0, cn = 0;
    for (int i = tid; i < ROWS_PER_RED; i += 256) {
        float4 v = pn[base + i];
        sp += (double)v.x; sn += (double)v.y; sd += (double)dist_arr[base + i];
        int f = (int)v.w;
        cp += f & 1; cn += (f >> 1) & 1;
    }
    __shared__ double A[256], B[256], C[256];
    __shared__ int I[256], J[256];
    A[tid] = sp; B[tid] = sn; C[tid] = sd; I[tid] = cp; J[tid] = cn;
    __syncthreads();
    for (int st = 128; st > 0; st >>= 1) {
        if (tid < st) { A[tid] += A[tid + st]; B[tid] += B[tid + st]; C[tid] += C[tid + st];
                        I[tid] += I[tid + st]; J[tid] += J[tid + st]; }
        __syncthreads();
    }
    if (tid == 0) {
        RedRec rec; rec.sp = A[0]; rec.sn = B[0]; rec.sd = C[0];
        rec.cp = I[0]; rec.cn = J[0];
        scratch[blockIdx.x] = rec;
    }
}

__global__ __launch_bounds__(64) void reduce2_kernel(
    const RedRec* __restrict__ scratch, float* __restrict__ out)
{
    int lane = threadIdx.x;
    RedRec rec = scratch[lane];
    double sp = rec.sp, sn = rec.sn, sd = rec.sd;
    int cp = rec.cp, cn = rec.cn;
#pragma unroll
    for (int m = 1; m < 64; m <<= 1) {
        sp += __shfl_xor(sp, m);
        sn += __shfl_xor(sn, m);
        sd += __shfl_xor(sd, m);
        cp += __shfl_xor(cp, m);
        cn += __shfl_xor(cn, m);
    }
    if (lane == 0) {
        int cpv = cp < 1 ? 1 : cp;
        int cnv = cn < 1 ? 1 : cn;
        out[0] = (float)(sp / ((double)cpv * NCLS) +
                         sn / ((double)cnv * NCLS) +
                         sd / ((double)ROWS * DE));
    }
}

static inline int pad8(int x) { return (x + 7) & ~7; }

extern "C" void kernel_launch(void* const* d_in, const int* in_sizes, int n_in,
                              void* d_out, int out_size, void* d_ws, size_t ws_size,
                              hipStream_t stream)
{
    const float* det    = (const float*)d_in[0];
    const float* traj   = (const float*)d_in[1];
    const float* relpos = (const float*)d_in[2];
    const float* cw     = (const float*)d_in[3];
    const float* W1     = (const float*)d_in[4];
    const float* b1     = (const float*)d_in[5];
    const float* W2     = (const float*)d_in[6];
    const float* b2     = (const float*)d_in[7];
    const float* W3     = (const float*)d_in[8];
    const float* R1     = (const float*)d_in[9];
    const float* rb1    = (const float*)d_in[10];
    const float* R2     = (const float*)d_in[11];
    const float* temp   = (const float*)d_in[12];
    const int*   labels = (const int*)d_in[13];
    const int*   sids   = (const int*)d_in[14];
    const int*   oids   = (const int*)d_in[15];
    float* out = (float*)d_out;

    // ---- Workspace carve --------------------------------------------------
    char* ws = (char*)d_ws;
    size_t off = 0;
    auto carve = [&](size_t bytes) -> char* {
        char* p = ws + off;
        off = (off + bytes + 255) & ~(size_t)255;
        return p;
    };
    float4* pn       = (float4*)carve((size_t)ROWS * 16);
    float*  dist_arr = (float*)carve((size_t)ROWS * 4);
    short*  det_bf   = (short*)carve((size_t)BSZ * NDET * DF * 2);
    short*  W1t      = (short*)carve((size_t)2048 * 2048 * 2);
    short*  W2t      = (short*)carve((size_t)DH * DH * 2);
    short*  W3t      = (short*)carve((size_t)NEXT * DH * 2);      // [640][1024]
    short*  R2t      = (short*)carve((size_t)NEXT * 256 * 2);     // [640][256]
    short*  cwt      = (short*)carve((size_t)128 * DE * 2);
    short*  W3bf     = (short*)carve((size_t)DH * DE * 2);
    short*  R2bf     = (short*)carve((size_t)256 * DE * 2);
    short*  UVa      = (short*)carve((size_t)BSZ * NDET * 2048 * 2);
    short*  UVb      = (short*)carve((size_t)BSZ * NDET * 2048 * 2);
    RedRec* red_scratch = (RedRec*)carve((size_t)RED1 * sizeof(RedRec));
    size_t fixed_off = off;

    int b_ch = 1;
    for (int cand : {16, 8, 4, 2, 1}) {
        size_t rows  = (size_t)cand * PAIRS;
        size_t bytes = fixed_off + rows * 2048 + 256 + rows * 2048 + 256
                     + rows * 512 + 256 + rows * 1280 + 256;
        if (bytes <= ws_size) { b_ch = cand; break; }
    }
    const int chunk_rows = b_ch * PAIRS;
    const int n_chunks = BSZ / b_ch;
    char* reg1 = carve((size_t)chunk_rows * 2048);
    char* reg2 = carve((size_t)chunk_rows * 2048);
    char* reg3 = carve((size_t)chunk_rows * 512);
    char* reg4 = carve((size_t)chunk_rows * 1280);

    short* h2     = (short*)reg2;
    short* so_ext = (short*)reg1;
    short* rh     = (short*)reg3;
    short* re_ext = (short*)reg4;     // own region (R10 race fix)

    // ---- Prep (1 launch) --------------------------------------------------
    TransJobs tj;
    tj.src[0] = W1;                    tj.dst[0] = W1t;                   tj.K[0] = DF;  tj.N[0] = DH;
    tj.src[1] = W1 + (size_t)DF * DH;  tj.dst[1] = W1t + (size_t)DH * DF; tj.K[1] = DF;  tj.N[1] = DH;
    tj.src[2] = W2;                    tj.dst[2] = W2t;                   tj.K[2] = DH;  tj.N[2] = DH;
    tj.src[3] = W3;                    tj.dst[3] = W3t;                   tj.K[3] = DH;  tj.N[3] = DE;
    tj.src[4] = R2;                    tj.dst[4] = R2t;                   tj.K[4] = 256; tj.N[4] = DE;
    tj.cum[0] = 0;
    for (int i = 0; i < 5; ++i)
        tj.cum[i + 1] = tj.cum[i] + (tj.K[i] / 32) * (tj.N[i] / 32);
    prep_kernel<<<NCONVB + tj.cum[5], 256, 0, stream>>>(
        det, det_bf, cw, cwt, W3, W3bf, R2, R2bf, tj);

    // One multi-job GEMM launch: UV split-K halves + classifier projections.
    GemmJobs gj;
    gj.A[0] = det_bf;        gj.Bt[0] = W1t;        gj.C[0] = UVa;
    gj.M[0] = BSZ * NDET;    gj.N[0] = 2048;        gj.K[0] = 1024;
    gj.lda[0] = 2048;        gj.ldb[0] = 2048;
    gj.A[1] = det_bf + 1024; gj.Bt[1] = W1t + 1024; gj.C[1] = UVb;
    gj.M[1] = BSZ * NDET;    gj.N[1] = 2048;        gj.K[1] = 1024;
    gj.lda[1] = 2048;        gj.ldb[1] = 2048;
    gj.A[2] = cwt;           gj.Bt[2] = W3bf;       gj.C[2] = W3t + (size_t)512 * DH;
    gj.M[2] = 128;           gj.N[2] = 1024;        gj.K[2] = 512;
    gj.lda[2] = 512;         gj.ldb[2] = 512;
    gj.A[3] = cwt;           gj.Bt[3] = R2bf;       gj.C[3] = R2t + (size_t)512 * 256;
    gj.M[3] = 128;           gj.N[3] = 256;         gj.K[3] = 512;
    gj.lda[3] = 512;         gj.ldb[3] = 512;
    gj.cum[0] = 0;
    for (int i = 0; i < 4; ++i)
        gj.cum[i + 1] = gj.cum[i] + (gj.N[i] / 128) * ((gj.M[i] + 127) / 128);
    mfma_gemm_multi<<<gj.cum[4], 256, 0, stream>>>(gj);   // 202 blocks

    // Merge: UVa += UVb + b1 (in-place); must precede gemm_h2f (reads UVa)
    uvmerge_kernel<<<(N4UV + 255) / 256, 256, 0, stream>>>(UVa, UVb, b1);

    const int mg  = (chunk_rows + 127) / 128;
    const int mgp = pad8(mg);

    for (int c = 0; c < n_chunks; ++c) {
        int b0 = c * b_ch;

        rh_kernel<<<chunk_rows / 4, 256, 0, stream>>>(
            relpos, R1, rb1, rh, b0);

        // h2 = bf16(relu(h1 @ W2 + b2)) with h1 = relu(U[s]+V[o]) fused into
        // A-staging (h1 never materialized).
        gemm_h2f<<<dim3(DH / 128, mgp), 256, 0, stream>>>(
            UVa, sids, oids, W2t, b2, h2, chunk_rows, b0 * PAIRS);

        // so_ext = bf16(h2 @ [W3 | W3·cw^T]) + re_ext = bf16(rh @ [R2 | R2·cw^T])
        mfma_gemm<false, false, true, true, true>
            <<<dim3(10, mgp), 256, 0, stream>>>(
            h2, W3t, nullptr, so_ext, chunk_rows, NEXT, DH, DH, DH,
            rh, R2t, re_ext, 5, 256, 256, 256, NEXT);

        rowprep_focal_kernel<<<chunk_rows / 4, 256, 0, stream>>>(
            so_ext, re_ext, traj, temp, sids, oids, labels, pn, dist_arr, b0);
    }

    reduce1_kernel<<<RED1, 256, 0, stream>>>(pn, dist_arr, red_scratch);
    reduce2_kernel<<<1, 64, 0, stream>>>(red_scratch, out);
}

// Round 4
// 383.548 us; speedup vs baseline: 1.0366x; 1.0055x over previous
//
#include <hip/hip_runtime.h>
#include <math.h>

// Problem constants
constexpr int BSZ   = 16;
constexpr int NDET  = 48;
constexpr int PAIRS = NDET * (NDET - 1);      // 2256
constexpr int ROWS  = BSZ * PAIRS;            // 36096
constexpr int DF    = 2048;
constexpr int DH    = 1024;
constexpr int DE    = 512;
constexpr int EHALF = 256;
constexpr int NCLS  = 92;
constexpr int NEXT  = DE + 128;               // 640: so/re GEMM width incl. classifier cols
constexpr int LABW  = 1 + 92 + 40;            // 133

typedef __attribute__((ext_vector_type(8))) short bf16x8;   // 8 bf16 in 4 VGPRs
typedef __attribute__((ext_vector_type(4))) float f32x4;

__device__ __forceinline__ short f2bf(float f) {
    union { float f; unsigned u; } a; a.f = f;
    unsigned r = a.u + 0x7fffu + ((a.u >> 16) & 1u);   // RNE
    return (short)(r >> 16);
}
__device__ __forceinline__ float bf2f(short h) {
    union { unsigned u; float f; } x;
    x.u = ((unsigned)(unsigned short)h) << 16;
    return x.f;
}

// ---------------------------------------------------------------------------
// Merged prep. Elementwise ranges: det conv | cwt build | W3->bf16 | R2->bf16;
// then 5-job transpose (W1 top/bot, W2, W3, R2).
// ---------------------------------------------------------------------------
constexpr int N4DET = BSZ * NDET * DF / 4;    // 393216
constexpr int N4CWT = 128 * DE / 4;           // 16384
constexpr int N4W3  = DH * DE / 4;            // 131072
constexpr int N4R2  = 256 * DE / 4;           // 32768
constexpr int NCONVB = (N4DET + N4CWT + N4W3 + N4R2) / 256;   // 2240

struct TransJobs {
    const float* src[5];
    short*       dst[5];
    int K[5], N[5];
    int cum[6];
};

__global__ __launch_bounds__(256) void prep_kernel(
    const float* __restrict__ det, short* __restrict__ det_bf,
    const float* __restrict__ cw, short* __restrict__ cwt,
    const float* __restrict__ W3, short* __restrict__ W3bf,
    const float* __restrict__ R2, short* __restrict__ R2bf,
    TransJobs jobs)
{
    if (blockIdx.x < NCONVB) {
        int i = blockIdx.x * 256 + threadIdx.x;
        const float* src; short* dst; int k;
        if (i < N4DET) { src = det; dst = det_bf; k = i; }
        else if (i < N4DET + N4CWT) {
            k = i - N4DET;
            int n = (k * 4) >> 9;
            short4 o = {0, 0, 0, 0};
            if (n < NCLS) {
                float4 v = ((const float4*)cw)[k];
                o.x = f2bf(v.x); o.y = f2bf(v.y); o.z = f2bf(v.z); o.w = f2bf(v.w);
            }
            ((short4*)cwt)[k] = o;
            return;
        }
        else if (i < N4DET + N4CWT + N4W3) { src = W3; dst = W3bf; k = i - N4DET - N4CWT; }
        else { src = R2; dst = R2bf; k = i - N4DET - N4CWT - N4W3; }
        float4 v = ((const float4*)src)[k];
        short4 o;
        o.x = f2bf(v.x); o.y = f2bf(v.y); o.z = f2bf(v.z); o.w = f2bf(v.w);
        ((short4*)dst)[k] = o;
        return;
    }
    __shared__ float tile[32][33];
    int t = blockIdx.x - NCONVB;
    int j = 0;
    while (t >= jobs.cum[j + 1]) ++j;
    int lt = t - jobs.cum[j];
    int K = jobs.K[j], N = jobs.N[j];
    int nx = N >> 5;
    int ky = lt / nx, nxi = lt - ky * nx;
    int n0 = nxi * 32, k0 = ky * 32;
    const float* src = jobs.src[j];
    short* dst = jobs.dst[j];
    int tx = threadIdx.x & 31, ty = threadIdx.x >> 5;
#pragma unroll
    for (int i = ty; i < 32; i += 8)
        tile[i][tx] = src[(size_t)(k0 + i) * N + n0 + tx];
    __syncthreads();
#pragma unroll
    for (int i = ty; i < 32; i += 8)
        dst[(size_t)(n0 + i) * K + k0 + tx] = f2bf(tile[tx][i]);
}

// ---------------------------------------------------------------------------
// MFMA GEMM (BK=64 as two 128x32 halves; R9-verified 2-phase 128^2 structure).
// ---------------------------------------------------------------------------
__device__ __forceinline__ void load16_lds(const void* g, void* l) {
    __builtin_amdgcn_global_load_lds(
        (const __attribute__((address_space(1))) unsigned int*)g,
        (__attribute__((address_space(3))) unsigned int*)l, 16, 0, 0);
}

#define MFMA16 __builtin_amdgcn_mfma_f32_16x16x32_bf16

template <bool BIAS, bool RELU, bool OUTBF16, bool SWIZZLE, bool DUAL>
__global__ __launch_bounds__(256, 4) void mfma_gemm(
    const short* __restrict__ A, const short* __restrict__ Bt,
    const float* __restrict__ bias, void* __restrict__ C,
    int M, int N, int K, int lda, int ldb,
    const short* A2, const short* Bt2, void* C2, int nsplit,
    int K2, int lda2, int ldb2, int N2)
{
    __shared__ __align__(16) char smem_raw[32768];   // As 16KB | Bs 16KB
    short* As = (short*)smem_raw;
    short* Bs = As + 128 * 64;

    int bx, by;
    if (SWIZZLE) {
        int nb  = gridDim.x;
        int gid = blockIdx.y * nb + blockIdx.x;
        int xcd = gid & 7;
        int j   = gid >> 3;
        int rows_per = gridDim.y >> 3;
        int lr  = j / nb;
        bx = j - lr * nb;
        by = xcd * rows_per + lr;
    } else {
        bx = blockIdx.x; by = blockIdx.y;
    }
    if (DUAL && bx >= nsplit) {
        bx -= nsplit; A = A2; Bt = Bt2; C = C2;
        K = K2; lda = lda2; ldb = ldb2; N = N2;
    }
    if (by * 128 >= M) return;                      // padded tail

    const int tid  = threadIdx.x;
    const int wave = tid >> 6;
    const int lane = tid & 63;
    const int m0 = by * 128;
    const int n0 = bx * 128;
    const int wm = (wave & 1) * 64;
    const int wn = (wave >> 1) * 64;

    f32x4 acc[4][4] = {};

    const int q  = lane >> 4;
    const int lm = lane & 15;

    for (int k0 = 0; k0 < K; k0 += 64) {
#pragma unroll
        for (int it = 0; it < 4; ++it) {
            int c    = (it & 1) * 256 + tid;
            int half = it >> 1;
            int row  = c >> 2;
            int kk   = (c & 3) * 8 + half * 32;
            int ldsc = half * 4096 + ((it & 1) * 256 + wave * 64) * 8;
            int gm = m0 + row; if (gm >= M) gm = M - 1;
            load16_lds(A + (size_t)gm * lda + k0 + kk, As + ldsc);
            int gn = n0 + row;                       // N%128==0: no tail
            load16_lds(Bt + (size_t)gn * ldb + k0 + kk, Bs + ldsc);
        }
        __syncthreads();

#pragma unroll
        for (int half = 0; half < 2; ++half) {
            const short* Ah = As + half * 4096;
            const short* Bh = Bs + half * 4096;
            bf16x8 af[4], bfr[4];
#pragma unroll
            for (int t = 0; t < 4; ++t) {
                af[t]  = *(const bf16x8*)(Ah + (wm + t * 16 + lm) * 32 + q * 8);
                bfr[t] = *(const bf16x8*)(Bh + (wn + t * 16 + lm) * 32 + q * 8);
            }
#pragma unroll
            for (int tm = 0; tm < 4; ++tm)
#pragma unroll
                for (int tn = 0; tn < 4; ++tn)
                    acc[tm][tn] = MFMA16(af[tm], bfr[tn], acc[tm][tn], 0, 0, 0);
        }
        __syncthreads();
    }

    // C/D layout: col=lane&15, row=(lane>>4)*4+reg (m89-verified)
    if (OUTBF16) {
        float* scratch = (float*)smem_raw + wave * (16 * 68);
#pragma unroll
        for (int tm = 0; tm < 4; ++tm) {
            __syncthreads();
#pragma unroll
            for (int tn = 0; tn < 4; ++tn) {
                float bv = BIAS ? bias[n0 + wn + tn * 16 + lm] : 0.0f;
#pragma unroll
                for (int r = 0; r < 4; ++r) {
                    float v = acc[tm][tn][r] + bv;
                    if (RELU) v = fmaxf(v, 0.0f);
                    scratch[(q * 4 + r) * 68 + tn * 16 + lm] = v;
                }
            }
            __syncthreads();
#pragma unroll
            for (int p = 0; p < 2; ++p) {
                int row16 = (lane >> 3) + p * 8;
                int c0 = (lane & 7) * 8;
                float4 v0 = *(float4*)&scratch[row16 * 68 + c0];
                float4 v1 = *(float4*)&scratch[row16 * 68 + c0 + 4];
                bf16x8 o;
                o[0] = f2bf(v0.x); o[1] = f2bf(v0.y); o[2] = f2bf(v0.z); o[3] = f2bf(v0.w);
                o[4] = f2bf(v1.x); o[5] = f2bf(v1.y); o[6] = f2bf(v1.z); o[7] = f2bf(v1.w);
                int grow = m0 + wm + tm * 16 + row16;
                if (grow < M)
                    *(bf16x8*)((short*)C + (size_t)grow * N + n0 + wn + c0) = o;
            }
        }
    } else {
#pragma unroll
        for (int tm = 0; tm < 4; ++tm)
#pragma unroll
            for (int tn = 0; tn < 4; ++tn) {
                int col = n0 + wn + tn * 16 + lm;
#pragma unroll
                for (int r = 0; r < 4; ++r) {
                    int row = m0 + wm + tm * 16 + q * 4 + r;
                    if (row < M) {
                        float v = acc[tm][tn][r];
                        if (BIAS) v += bias[col];
                        if (RELU) v = fmaxf(v, 0.0f);
                        ((float*)C)[(size_t)row * N + col] = v;
                    }
                }
            }
    }
}

// ---------------------------------------------------------------------------
// R17: fused h2 GEMM, v2. Fix for R16's VALU-bound regression (56% VALUBusy):
//  - BN=256 per block (4 column-blocks, was 8): halves chip-wide A-fusion
//    recompute. Per wave per K-step: 64 MFMAs (~310cy) vs A-VALU ~290cy.
//  - v_cvt_pk_bf16_f32 (HW RNE pack, 1 inst / 2 elems) replaces the 5-op
//    manual f2bf. Bit-identical for finite values (same RNE).
//  - 4 waves (2M x 2N-subtile), acc[4][8] = 128 VGPR; LDS A 16K + B 32K;
//    __launch_bounds__(256,2) -> 2 blocks/CU so VALU/MFMA overlap across
//    blocks (m114).
// ---------------------------------------------------------------------------
__device__ __forceinline__ unsigned cvtpk(float lo, float hi) {
    unsigned r;
    asm("v_cvt_pk_bf16_f32 %0, %1, %2" : "=v"(r) : "v"(lo), "v"(hi));
    return r;
}
__device__ __forceinline__ bf16x8 addrelu_pack(bf16x8 u, bf16x8 v) {
    float f[8];
#pragma unroll
    for (int e = 0; e < 8; ++e)
        f[e] = fmaxf(bf2f(u[e]) + bf2f(v[e]), 0.0f);
    union { unsigned w[4]; bf16x8 o; } r;
#pragma unroll
    for (int j = 0; j < 4; ++j)
        r.w[j] = cvtpk(f[2 * j], f[2 * j + 1]);
    return r.o;
}

__global__ __launch_bounds__(256, 2) void gemm_h2f(
    const short* __restrict__ UV,
    const int* __restrict__ sids, const int* __restrict__ oids,
    const short* __restrict__ Bt, const float* __restrict__ bias,
    short* __restrict__ C, int M, int rowbase)
{
    __shared__ __align__(16) char smem_raw[49152];   // As 16KB | Bs 32KB
    short* As = (short*)smem_raw;
    short* Bs = As + 128 * 64;

    int nb  = gridDim.x;                             // 4
    int gid = blockIdx.y * nb + blockIdx.x;
    int xcd = gid & 7;
    int j   = gid >> 3;
    int rows_per = gridDim.y >> 3;
    int lr  = j / nb;
    int bx = j - lr * nb;
    int by = xcd * rows_per + lr;
    if (by * 128 >= M) return;

    const int tid  = threadIdx.x;
    const int wave = tid >> 6;
    const int lane = tid & 63;
    const int m0 = by * 128;
    const int n0 = bx * 256;
    const int wm   = (wave & 1) * 64;                // M-half
    const int wsub = wave >> 1;                      // which 128-col subtile

    // fused-A setup: thread owns tile rows (tid>>2), (tid>>2)+64 at k-chunk
    // cq = tid&3 (kk = cq*8 and cq*8+32 per 64-wide K-step).
    const int cq = tid & 3;
    int lr0 = m0 + (tid >> 2); if (lr0 >= M) lr0 = M - 1;
    int lr1 = lr0 + 64;        if (lr1 >= M) lr1 = M - 1;
    int rg0 = rowbase + lr0, rg1 = rowbase + lr1;
    int b0 = rg0 / PAIRS, p0 = rg0 - b0 * PAIRS;
    int b1 = rg1 / PAIRS, p1 = rg1 - b1 * PAIRS;
    const short* u0 = UV + (size_t)(b0 * NDET + sids[p0]) * 2048;
    const short* v0 = UV + (size_t)(b0 * NDET + oids[p0]) * 2048 + 1024;
    const short* u1 = UV + (size_t)(b1 * NDET + sids[p1]) * 2048;
    const short* v1 = UV + (size_t)(b1 * NDET + oids[p1]) * 2048 + 1024;

    f32x4 acc[4][8] = {};
    const int q  = lane >> 4;
    const int lm = lane & 15;

    for (int k0 = 0; k0 < DH; k0 += 64) {
        // B staging: two 128x64 subtiles, 4x load16_lds each.
#pragma unroll
        for (int sub = 0; sub < 2; ++sub)
#pragma unroll
            for (int it = 0; it < 4; ++it) {
                int c    = (it & 1) * 256 + tid;
                int half = it >> 1;
                int row  = c >> 2;
                int kk   = (c & 3) * 8 + half * 32;
                int ldsc = sub * 8192 + half * 4096 + ((it & 1) * 256 + wave * 64) * 8;
                load16_lds(Bt + (size_t)(n0 + sub * 128 + row) * DH + k0 + kk,
                           Bs + ldsc);
            }
        // A fused: 8 reg loads (L2-hot UV), add+relu+cvt_pk, 4 ds_writes.
        int ka = k0 + cq * 8;
        *(bf16x8*)(As + tid * 8) =
            addrelu_pack(*(const bf16x8*)(u0 + ka), *(const bf16x8*)(v0 + ka));
        *(bf16x8*)(As + (256 + tid) * 8) =
            addrelu_pack(*(const bf16x8*)(u1 + ka), *(const bf16x8*)(v1 + ka));
        *(bf16x8*)(As + 4096 + tid * 8) =
            addrelu_pack(*(const bf16x8*)(u0 + ka + 32), *(const bf16x8*)(v0 + ka + 32));
        *(bf16x8*)(As + 4096 + (256 + tid) * 8) =
            addrelu_pack(*(const bf16x8*)(u1 + ka + 32), *(const bf16x8*)(v1 + ka + 32));
        __syncthreads();

#pragma unroll
        for (int half = 0; half < 2; ++half) {
            const short* Ah = As + half * 4096;
            const short* Bh = Bs + wsub * 8192 + half * 4096;
            bf16x8 af[4], bfr[8];
#pragma unroll
            for (int t = 0; t < 4; ++t)
                af[t] = *(const bf16x8*)(Ah + (wm + t * 16 + lm) * 32 + q * 8);
#pragma unroll
            for (int t = 0; t < 8; ++t)
                bfr[t] = *(const bf16x8*)(Bh + (t * 16 + lm) * 32 + q * 8);
#pragma unroll
            for (int tm = 0; tm < 4; ++tm)
#pragma unroll
                for (int tn = 0; tn < 8; ++tn)
                    acc[tm][tn] = MFMA16(af[tm], bfr[tn], acc[tm][tn], 0, 0, 0);
        }
        __syncthreads();
    }

    // epilogue: bias+relu, bf16 out. Per-wave scratch 16 x 132 floats.
    float* scratch = (float*)smem_raw + wave * (16 * 132);
    const int csub = n0 + wsub * 128;
#pragma unroll
    for (int tm = 0; tm < 4; ++tm) {
        __syncthreads();
#pragma unroll
        for (int tn = 0; tn < 8; ++tn) {
            float bv = bias[csub + tn * 16 + lm];
#pragma unroll
            for (int r = 0; r < 4; ++r) {
                float v = fmaxf(acc[tm][tn][r] + bv, 0.0f);
                scratch[(q * 4 + r) * 132 + tn * 16 + lm] = v;
            }
        }
        __syncthreads();
#pragma unroll
        for (int p = 0; p < 2; ++p) {
            int row16 = (lane >> 3) + p * 8;
            int grow  = m0 + wm + tm * 16 + row16;
            if (grow >= M) continue;
#pragma unroll
            for (int cc = 0; cc < 2; ++cc) {
                int c0 = (lane & 7) * 16 + cc * 8;
                float4 x0 = *(float4*)&scratch[row16 * 132 + c0];
                float4 x1 = *(float4*)&scratch[row16 * 132 + c0 + 4];
                bf16x8 o;
                o[0] = f2bf(x0.x); o[1] = f2bf(x0.y); o[2] = f2bf(x0.z); o[3] = f2bf(x0.w);
                o[4] = f2bf(x1.x); o[5] = f2bf(x1.y); o[6] = f2bf(x1.z); o[7] = f2bf(x1.w);
                *(bf16x8*)(C + (size_t)grow * DH + csub + c0) = o;
            }
        }
    }
}

// ---------------------------------------------------------------------------
// Multi-job GEMM (up to 4 independent bf16-out jobs, flat 1-D grid).
// ---------------------------------------------------------------------------
struct GemmJobs {
    const short* A[4]; const short* Bt[4]; short* C[4];
    int M[4], N[4], K[4], lda[4], ldb[4];
    int cum[5];
};

__global__ __launch_bounds__(256, 4) void mfma_gemm_multi(GemmJobs jobs)
{
    __shared__ __align__(16) char smem_raw[32768];
    short* As = (short*)smem_raw;
    short* Bs = As + 128 * 64;

    int bid = blockIdx.x;
    int j = 0;
    while (bid >= jobs.cum[j + 1]) ++j;             // <=4, block-uniform
    int lt = bid - jobs.cum[j];
    const short* A  = jobs.A[j];
    const short* Bt = jobs.Bt[j];
    short* C = jobs.C[j];
    int M = jobs.M[j], N = jobs.N[j], K = jobs.K[j];
    int lda = jobs.lda[j], ldb = jobs.ldb[j];
    int ncols = N >> 7;
    int by = lt / ncols;
    int bx = lt - by * ncols;

    const int tid  = threadIdx.x;
    const int wave = tid >> 6;
    const int lane = tid & 63;
    const int m0 = by * 128;
    const int n0 = bx * 128;
    const int wm = (wave & 1) * 64;
    const int wn = (wave >> 1) * 64;

    f32x4 acc[4][4] = {};
    const int q  = lane >> 4;
    const int lm = lane & 15;

    for (int k0 = 0; k0 < K; k0 += 64) {
#pragma unroll
        for (int it = 0; it < 4; ++it) {
            int c    = (it & 1) * 256 + tid;
            int half = it >> 1;
            int row  = c >> 2;
            int kk   = (c & 3) * 8 + half * 32;
            int ldsc = half * 4096 + ((it & 1) * 256 + wave * 64) * 8;
            int gm = m0 + row; if (gm >= M) gm = M - 1;
            load16_lds(A + (size_t)gm * lda + k0 + kk, As + ldsc);
            load16_lds(Bt + (size_t)(n0 + row) * ldb + k0 + kk, Bs + ldsc);
        }
        __syncthreads();
#pragma unroll
        for (int half = 0; half < 2; ++half) {
            const short* Ah = As + half * 4096;
            const short* Bh = Bs + half * 4096;
            bf16x8 af[4], bfr[4];
#pragma unroll
            for (int t = 0; t < 4; ++t) {
                af[t]  = *(const bf16x8*)(Ah + (wm + t * 16 + lm) * 32 + q * 8);
                bfr[t] = *(const bf16x8*)(Bh + (wn + t * 16 + lm) * 32 + q * 8);
            }
#pragma unroll
            for (int tm = 0; tm < 4; ++tm)
#pragma unroll
                for (int tn = 0; tn < 4; ++tn)
                    acc[tm][tn] = MFMA16(af[tm], bfr[tn], acc[tm][tn], 0, 0, 0);
        }
        __syncthreads();
    }

    float* scratch = (float*)smem_raw + wave * (16 * 68);
#pragma unroll
    for (int tm = 0; tm < 4; ++tm) {
        __syncthreads();
#pragma unroll
        for (int tn = 0; tn < 4; ++tn)
#pragma unroll
            for (int r = 0; r < 4; ++r)
                scratch[(q * 4 + r) * 68 + tn * 16 + lm] = acc[tm][tn][r];
        __syncthreads();
#pragma unroll
        for (int p = 0; p < 2; ++p) {
            int row16 = (lane >> 3) + p * 8;
            int c0 = (lane & 7) * 8;
            float4 v0 = *(float4*)&scratch[row16 * 68 + c0];
            float4 v1 = *(float4*)&scratch[row16 * 68 + c0 + 4];
            bf16x8 o;
            o[0] = f2bf(v0.x); o[1] = f2bf(v0.y); o[2] = f2bf(v0.z); o[3] = f2bf(v0.w);
            o[4] = f2bf(v1.x); o[5] = f2bf(v1.y); o[6] = f2bf(v1.z); o[7] = f2bf(v1.w);
            int grow = m0 + wm + tm * 16 + row16;
            if (grow < M)
                *(bf16x8*)(C + (size_t)grow * N + n0 + wn + c0) = o;
        }
    }
}

// ---------------------------------------------------------------------------
// UV merge (in-place): UVa = UVa + UVb + b1 (U-half cols only).
// ---------------------------------------------------------------------------
constexpr int N4UV = BSZ * NDET * 2048 / 4;   // 393216 short4s
__global__ __launch_bounds__(256) void uvmerge_kernel(
    short* __restrict__ UVa, const short* __restrict__ UVb,
    const float* __restrict__ b1)
{
    int i = blockIdx.x * 256 + threadIdx.x;
    if (i >= N4UV) return;
    short4 a = ((const short4*)UVa)[i];
    short4 b = ((const short4*)UVb)[i];
    int col4 = i & 511;
    float4 bb = {0.0f, 0.0f, 0.0f, 0.0f};
    if (col4 < 256) bb = ((const float4*)b1)[col4];
    short4 o;
    o.x = f2bf(bf2f(a.x) + bf2f(b.x) + bb.x);
    o.y = f2bf(bf2f(a.y) + bf2f(b.y) + bb.y);
    o.z = f2bf(bf2f(a.z) + bf2f(b.z) + bb.z);
    o.w = f2bf(bf2f(a.w) + bf2f(b.w) + bb.w);
    ((short4*)UVa)[i] = o;
}

// ---------------------------------------------------------------------------
// rh only (h1 fused into gemm_h2f): wave-per-row R1 matvec.
// ---------------------------------------------------------------------------
__global__ __launch_bounds__(256) void rh_kernel(
    const float* __restrict__ rp, const float* __restrict__ R1,
    const float* __restrict__ rb1, short* __restrict__ rh, int b0)
{
    int wave = threadIdx.x >> 6, lane = threadIdx.x & 63;
    int r = blockIdx.x * 4 + wave;
    int rg = b0 * PAIRS + r;

    const float* rowp = rp + (size_t)rg * 12;
    float4 acc = ((const float4*)rb1)[lane];
#pragma unroll
    for (int k = 0; k < 12; ++k) {
        float rv = rowp[k];
        float4 w = ((const float4*)(R1 + k * 256))[lane];
        acc.x = fmaf(rv, w.x, acc.x);
        acc.y = fmaf(rv, w.y, acc.y);
        acc.z = fmaf(rv, w.z, acc.z);
        acc.w = fmaf(rv, w.w, acc.w);
    }
    short4 o;
    o.x = f2bf(fmaxf(acc.x, 0.0f));
    o.y = f2bf(fmaxf(acc.y, 0.0f));
    o.z = f2bf(fmaxf(acc.z, 0.0f));
    o.w = f2bf(fmaxf(acc.w, 0.0f));
    ((short4*)(rh + (size_t)r * 256))[lane] = o;
}

// ---------------------------------------------------------------------------
// Fused row_prep + focal: wave-per-row (logits from extended GEMM columns;
// ||comb||^2 = 2 + 2*rho/(||so||*||re||)).
// ---------------------------------------------------------------------------
__global__ __launch_bounds__(256) void rowprep_focal_kernel(
    const short* __restrict__ so_ext, const short* __restrict__ re_ext,
    const float* __restrict__ traj, const float* __restrict__ temperature,
    const int* __restrict__ sids, const int* __restrict__ oids,
    const int* __restrict__ labels,
    float4* __restrict__ pn, float* __restrict__ dist_arr, int b0)
{
    int wave = threadIdx.x >> 6, lane = threadIdx.x & 63;
    int r = blockIdx.x * 4 + wave;
    int rg = b0 * PAIRS + r;
    int b = b0 + r / PAIRS;
    int p = r % PAIRS;

    const short* srow = so_ext + (size_t)r * NEXT;
    const short* rrow = re_ext + (size_t)r * NEXT;
    bf16x8 sv = *(const bf16x8*)(srow + lane * 8);
    bf16x8 uv = *(const bf16x8*)(rrow + lane * 8);
    float s[8], u[8];
#pragma unroll
    for (int i = 0; i < 8; ++i) { s[i] = bf2f(sv[i]); u[i] = bf2f(uv[i]); }

    const float* tsrc = (lane < 32)
        ? (traj + (size_t)(b * NDET + sids[p]) * EHALF + lane * 8)
        : (traj + (size_t)(b * NDET + oids[p]) * EHALF + (lane - 32) * 8);
    float4 t0 = ((const float4*)tsrc)[0], t1 = ((const float4*)tsrc)[1];
    float t[8] = {t0.x, t0.y, t0.z, t0.w, t1.x, t1.y, t1.z, t1.w};

    float ss = 0.0f, sr = 0.0f, rho = 0.0f, sd = 0.0f;
#pragma unroll
    for (int i = 0; i < 8; ++i) {
        ss  += s[i] * s[i];
        sr  += u[i] * u[i];
        rho += s[i] * u[i];
        sd  += fabsf(t[i] - s[i]);
    }
#pragma unroll
    for (int m = 1; m < 64; m <<= 1) {
        ss  += __shfl_xor(ss, m);
        sr  += __shfl_xor(sr, m);
        rho += __shfl_xor(rho, m);
        sd  += __shfl_xor(sd, m);
    }
    float inv_s = 1.0f / fmaxf(sqrtf(ss), 1e-12f);
    float inv_r = 1.0f / fmaxf(sqrtf(sr), 1e-12f);
    float ncomb = sqrtf(fmaxf(2.0f + 2.0f * rho * inv_s * inv_r, 0.0f));
    float scale = 1.0f / (fmaxf(ncomb, 1e-12f) * temperature[0]);

    float flp = 0.0f, fln = 0.0f, fm = 0.0f;
    size_t labbase = (size_t)rg * LABW;
#pragma unroll
    for (int h = 0; h < 2; ++h) {
        int c = lane + h * 64;
        if (c < NCLS) {
            float l = (bf2f(srow[DE + c]) * inv_s + bf2f(rrow[DE + c]) * inv_r) * scale;
            int tl = labels[labbase + 1 + c];
            if (tl > 0) fm = 1.0f;
            float tf = (float)tl;
            float pr = 1.0f / (1.0f + expf(-l));
            float lg = log1pf(expf(-fabsf(l)));
            float ce = fmaxf(l, 0.0f) - l * tf + lg;
            float pt = pr * tf + (1.0f - pr) * (1.0f - tf);
            float om = 1.0f - pt;
            float at = 0.25f * tf + 0.75f * (1.0f - tf);
            flp += at * ce * om * om;
            float ce0 = fmaxf(l, 0.0f) + lg;
            fln += 0.75f * ce0 * pr * pr;
        }
    }
#pragma unroll
    for (int m = 1; m < 64; m <<= 1) {
        flp += __shfl_xor(flp, m);
        fln += __shfl_xor(fln, m);
        fm  += __shfl_xor(fm, m);
    }
    if (lane == 0) {
        int posf = (fm > 0.5f) ? 1 : 0;
        int negf = (labels[labbase] > 0) ? 1 : 0;
        pn[rg] = make_float4(posf ? flp : 0.0f, negf ? fln : 0.0f, 0.0f,
                             (float)(posf + 2 * negf));
        dist_arr[rg] = sd;
    }
}

// ---------------------------------------------------------------------------
// Two-stage final reduce.
// ---------------------------------------------------------------------------
struct RedRec { double sp, sn, sd; int cp, cn; };
constexpr int RED1 = 64;
constexpr int ROWS_PER_RED = ROWS / RED1;           // 564

__global__ __launch_bounds__(256) void reduce1_kernel(
    const float4* __restrict__ pn, const float* __restrict__ dist_arr,
    RedRec* __restrict__ scratch)
{
    int tid = threadIdx.x;
    int base = blockIdx.x * ROWS_PER_RED;
    double sp = 0.0, sn = 0.0, sd = 0.0;
    int cp = 0, cn = 0;
    for (int i = tid; i < ROWS_PER_RED; i += 256) {
        float4 v = pn[base + i];
        sp += (double)v.x; sn += (double)v.y; sd += (double)dist_arr[base + i];
        int f = (int)v.w;
        cp += f & 1; cn += (f >> 1) & 1;
    }
    __shared__ double A[256], B[256], C[256];
    __shared__ int I[256], J[256];
    A[tid] = sp; B[tid] = sn; C[tid] = sd; I[tid] = cp; J[tid] = cn;
    __syncthreads();
    for (int st = 128; st > 0; st >>= 1) {
        if (tid < st) { A[tid] += A[tid + st]; B[tid] += B[tid + st]; C[tid] += C[tid + st];
                        I[tid] += I[tid + st]; J[tid] += J[tid + st]; }
        __syncthreads();
    }
    if (tid == 0) {
        RedRec rec; rec.sp = A[0]; rec.sn = B[0]; rec.sd = C[0];
        rec.cp = I[0]; rec.cn = J[0];
        scratch[blockIdx.x] = rec;
    }
}

__global__ __launch_bounds__(64) void reduce2_kernel(
    const RedRec* __restrict__ scratch, float* __restrict__ out)
{
    int lane = threadIdx.x;
    RedRec rec = scratch[lane];
    double sp = rec.sp, sn = rec.sn, sd = rec.sd;
    int cp = rec.cp, cn = rec.cn;
#pragma unroll
    for (int m = 1; m < 64; m <<= 1) {
        sp += __shfl_xor(sp, m);
        sn += __shfl_xor(sn, m);
        sd += __shfl_xor(sd, m);
        cp += __shfl_xor(cp, m);
        cn += __shfl_xor(cn, m);
    }
    if (lane == 0) {
        int cpv = cp < 1 ? 1 : cp;
        int cnv = cn < 1 ? 1 : cn;
        out[0] = (float)(sp / ((double)cpv * NCLS) +
                         sn / ((double)cnv * NCLS) +
                         sd / ((double)ROWS * DE));
    }
}

static inline int pad8(int x) { return (x + 7) & ~7; }

extern "C" void kernel_launch(void* const* d_in, const int* in_sizes, int n_in,
                              void* d_out, int out_size, void* d_ws, size_t ws_size,
                              hipStream_t stream)
{
    const float* det    = (const float*)d_in[0];
    const float* traj   = (const float*)d_in[1];
    const float* relpos = (const float*)d_in[2];
    const float* cw     = (const float*)d_in[3];
    const float* W1     = (const float*)d_in[4];
    const float* b1     = (const float*)d_in[5];
    const float* W2     = (const float*)d_in[6];
    const float* b2     = (const float*)d_in[7];
    const float* W3     = (const float*)d_in[8];
    const float* R1     = (const float*)d_in[9];
    const float* rb1    = (const float*)d_in[10];
    const float* R2     = (const float*)d_in[11];
    const float* temp   = (const float*)d_in[12];
    const int*   labels = (const int*)d_in[13];
    const int*   sids   = (const int*)d_in[14];
    const int*   oids   = (const int*)d_in[15];
    float* out = (float*)d_out;

    // ---- Workspace carve --------------------------------------------------
    char* ws = (char*)d_ws;
    size_t off = 0;
    auto carve = [&](size_t bytes) -> char* {
        char* p = ws + off;
        off = (off + bytes + 255) & ~(size_t)255;
        return p;
    };
    float4* pn       = (float4*)carve((size_t)ROWS * 16);
    float*  dist_arr = (float*)carve((size_t)ROWS * 4);
    short*  det_bf   = (short*)carve((size_t)BSZ * NDET * DF * 2);
    short*  W1t      = (short*)carve((size_t)2048 * 2048 * 2);
    short*  W2t      = (short*)carve((size_t)DH * DH * 2);
    short*  W3t      = (short*)carve((size_t)NEXT * DH * 2);      // [640][1024]
    short*  R2t      = (short*)carve((size_t)NEXT * 256 * 2);     // [640][256]
    short*  cwt      = (short*)carve((size_t)128 * DE * 2);
    short*  W3bf     = (short*)carve((size_t)DH * DE * 2);
    short*  R2bf     = (short*)carve((size_t)256 * DE * 2);
    short*  UVa      = (short*)carve((size_t)BSZ * NDET * 2048 * 2);
    short*  UVb      = (short*)carve((size_t)BSZ * NDET * 2048 * 2);
    RedRec* red_scratch = (RedRec*)carve((size_t)RED1 * sizeof(RedRec));
    size_t fixed_off = off;

    int b_ch = 1;
    for (int cand : {16, 8, 4, 2, 1}) {
        size_t rows  = (size_t)cand * PAIRS;
        size_t bytes = fixed_off + rows * 2048 + 256 + rows * 2048 + 256
                     + rows * 512 + 256 + rows * 1280 + 256;
        if (bytes <= ws_size) { b_ch = cand; break; }
    }
    const int chunk_rows = b_ch * PAIRS;
    const int n_chunks = BSZ / b_ch;
    char* reg1 = carve((size_t)chunk_rows * 2048);
    char* reg2 = carve((size_t)chunk_rows * 2048);
    char* reg3 = carve((size_t)chunk_rows * 512);
    char* reg4 = carve((size_t)chunk_rows * 1280);

    short* h2     = (short*)reg2;
    short* so_ext = (short*)reg1;
    short* rh     = (short*)reg3;
    short* re_ext = (short*)reg4;     // own region (R10 race fix)

    // ---- Prep (1 launch) --------------------------------------------------
    TransJobs tj;
    tj.src[0] = W1;                    tj.dst[0] = W1t;                   tj.K[0] = DF;  tj.N[0] = DH;
    tj.src[1] = W1 + (size_t)DF * DH;  tj.dst[1] = W1t + (size_t)DH * DF; tj.K[1] = DF;  tj.N[1] = DH;
    tj.src[2] = W2;                    tj.dst[2] = W2t;                   tj.K[2] = DH;  tj.N[2] = DH;
    tj.src[3] = W3;                    tj.dst[3] = W3t;                   tj.K[3] = DH;  tj.N[3] = DE;
    tj.src[4] = R2;                    tj.dst[4] = R2t;                   tj.K[4] = 256; tj.N[4] = DE;
    tj.cum[0] = 0;
    for (int i = 0; i < 5; ++i)
        tj.cum[i + 1] = tj.cum[i] + (tj.K[i] / 32) * (tj.N[i] / 32);
    prep_kernel<<<NCONVB + tj.cum[5], 256, 0, stream>>>(
        det, det_bf, cw, cwt, W3, W3bf, R2, R2bf, tj);

    // One multi-job GEMM launch: UV split-K halves + classifier projections.
    GemmJobs gj;
    gj.A[0] = det_bf;        gj.Bt[0] = W1t;        gj.C[0] = UVa;
    gj.M[0] = BSZ * NDET;    gj.N[0] = 2048;        gj.K[0] = 1024;
    gj.lda[0] = 2048;        gj.ldb[0] = 2048;
    gj.A[1] = det_bf + 1024; gj.Bt[1] = W1t + 1024; gj.C[1] = UVb;
    gj.M[1] = BSZ * NDET;    gj.N[1] = 2048;        gj.K[1] = 1024;
    gj.lda[1] = 2048;        gj.ldb[1] = 2048;
    gj.A[2] = cwt;           gj.Bt[2] = W3bf;       gj.C[2] = W3t + (size_t)512 * DH;
    gj.M[2] = 128;           gj.N[2] = 1024;        gj.K[2] = 512;
    gj.lda[2] = 512;         gj.ldb[2] = 512;
    gj.A[3] = cwt;           gj.Bt[3] = R2bf;       gj.C[3] = R2t + (size_t)512 * 256;
    gj.M[3] = 128;           gj.N[3] = 256;         gj.K[3] = 512;
    gj.lda[3] = 512;         gj.ldb[3] = 512;
    gj.cum[0] = 0;
    for (int i = 0; i < 4; ++i)
        gj.cum[i + 1] = gj.cum[i] + (gj.N[i] / 128) * ((gj.M[i] + 127) / 128);
    mfma_gemm_multi<<<gj.cum[4], 256, 0, stream>>>(gj);   // 202 blocks

    // Merge: UVa += UVb + b1 (in-place); must precede gemm_h2f (reads UVa)
    uvmerge_kernel<<<(N4UV + 255) / 256, 256, 0, stream>>>(UVa, UVb, b1);

    const int mg  = (chunk_rows + 127) / 128;
    const int mgp = pad8(mg);

    for (int c = 0; c < n_chunks; ++c) {
        int b0 = c * b_ch;

        rh_kernel<<<chunk_rows / 4, 256, 0, stream>>>(
            relpos, R1, rb1, rh, b0);

        // h2 = bf16(relu(h1 @ W2 + b2)) with h1 = relu(U[s]+V[o]) fused into
        // A-staging (h1 never materialized). BN=256: 4 column-blocks.
        gemm_h2f<<<dim3(DH / 256, mgp), 256, 0, stream>>>(
            UVa, sids, oids, W2t, b2, h2, chunk_rows, b0 * PAIRS);

        // so_ext = bf16(h2 @ [W3 | W3·cw^T]) + re_ext = bf16(rh @ [R2 | R2·cw^T])
        mfma_gemm<false, false, true, true, true>
            <<<dim3(10, mgp), 256, 0, stream>>>(
            h2, W3t, nullptr, so_ext, chunk_rows, NEXT, DH, DH, DH,
            rh, R2t, re_ext, 5, 256, 256, 256, NEXT);

        rowprep_focal_kernel<<<chunk_rows / 4, 256, 0, stream>>>(
            so_ext, re_ext, traj, temp, sids, oids, labels, pn, dist_arr, b0);
    }

    reduce1_kernel<<<RED1, 256, 0, stream>>>(pn, dist_arr, red_scratch);
    reduce2_kernel<<<1, 64, 0, stream>>>(red_scratch, out);
}

// Round 5
// 381.359 us; speedup vs baseline: 1.0425x; 1.0057x over previous
//
#include <hip/hip_runtime.h>
#include <math.h>

// Problem constants
constexpr int BSZ   = 16;
constexpr int NDET  = 48;
constexpr int PAIRS = NDET * (NDET - 1);      // 2256
constexpr int ROWS  = BSZ * PAIRS;            // 36096
constexpr int DF    = 2048;
constexpr int DH    = 1024;
constexpr int DE    = 512;
constexpr int EHALF = 256;
constexpr int NCLS  = 92;
constexpr int NEXT  = DE + 128;               // 640: so/re GEMM width incl. classifier cols
constexpr int LABW  = 1 + 92 + 40;            // 133

typedef __attribute__((ext_vector_type(8))) short bf16x8;   // 8 bf16 in 4 VGPRs
typedef __attribute__((ext_vector_type(4))) float f32x4;

__device__ __forceinline__ short f2bf(float f) {
    union { float f; unsigned u; } a; a.f = f;
    unsigned r = a.u + 0x7fffu + ((a.u >> 16) & 1u);   // RNE
    return (short)(r >> 16);
}
__device__ __forceinline__ float bf2f(short h) {
    union { unsigned u; float f; } x;
    x.u = ((unsigned)(unsigned short)h) << 16;
    return x.f;
}

// ---------------------------------------------------------------------------
// Merged prep. Elementwise ranges: det conv | cwt build | W3->bf16 | R2->bf16;
// then 5-job transpose (W1 top/bot, W2, W3, R2).
// ---------------------------------------------------------------------------
constexpr int N4DET = BSZ * NDET * DF / 4;    // 393216
constexpr int N4CWT = 128 * DE / 4;           // 16384
constexpr int N4W3  = DH * DE / 4;            // 131072
constexpr int N4R2  = 256 * DE / 4;           // 32768
constexpr int NCONVB = (N4DET + N4CWT + N4W3 + N4R2) / 256;   // 2240

struct TransJobs {
    const float* src[5];
    short*       dst[5];
    int K[5], N[5];
    int cum[6];
};

__global__ __launch_bounds__(256) void prep_kernel(
    const float* __restrict__ det, short* __restrict__ det_bf,
    const float* __restrict__ cw, short* __restrict__ cwt,
    const float* __restrict__ W3, short* __restrict__ W3bf,
    const float* __restrict__ R2, short* __restrict__ R2bf,
    TransJobs jobs)
{
    if (blockIdx.x < NCONVB) {
        int i = blockIdx.x * 256 + threadIdx.x;
        const float* src; short* dst; int k;
        if (i < N4DET) { src = det; dst = det_bf; k = i; }
        else if (i < N4DET + N4CWT) {
            k = i - N4DET;
            int n = (k * 4) >> 9;
            short4 o = {0, 0, 0, 0};
            if (n < NCLS) {
                float4 v = ((const float4*)cw)[k];
                o.x = f2bf(v.x); o.y = f2bf(v.y); o.z = f2bf(v.z); o.w = f2bf(v.w);
            }
            ((short4*)cwt)[k] = o;
            return;
        }
        else if (i < N4DET + N4CWT + N4W3) { src = W3; dst = W3bf; k = i - N4DET - N4CWT; }
        else { src = R2; dst = R2bf; k = i - N4DET - N4CWT - N4W3; }
        float4 v = ((const float4*)src)[k];
        short4 o;
        o.x = f2bf(v.x); o.y = f2bf(v.y); o.z = f2bf(v.z); o.w = f2bf(v.w);
        ((short4*)dst)[k] = o;
        return;
    }
    __shared__ float tile[32][33];
    int t = blockIdx.x - NCONVB;
    int j = 0;
    while (t >= jobs.cum[j + 1]) ++j;
    int lt = t - jobs.cum[j];
    int K = jobs.K[j], N = jobs.N[j];
    int nx = N >> 5;
    int ky = lt / nx, nxi = lt - ky * nx;
    int n0 = nxi * 32, k0 = ky * 32;
    const float* src = jobs.src[j];
    short* dst = jobs.dst[j];
    int tx = threadIdx.x & 31, ty = threadIdx.x >> 5;
#pragma unroll
    for (int i = ty; i < 32; i += 8)
        tile[i][tx] = src[(size_t)(k0 + i) * N + n0 + tx];
    __syncthreads();
#pragma unroll
    for (int i = ty; i < 32; i += 8)
        dst[(size_t)(n0 + i) * K + k0 + tx] = f2bf(tile[tx][i]);
}

// ---------------------------------------------------------------------------
// MFMA GEMM (BK=64 as two 128x32 halves; R9-verified 2-phase 128^2 structure).
// ---------------------------------------------------------------------------
__device__ __forceinline__ void load16_lds(const void* g, void* l) {
    __builtin_amdgcn_global_load_lds(
        (const __attribute__((address_space(1))) unsigned int*)g,
        (__attribute__((address_space(3))) unsigned int*)l, 16, 0, 0);
}

#define MFMA16 __builtin_amdgcn_mfma_f32_16x16x32_bf16

template <bool BIAS, bool RELU, bool OUTBF16, bool SWIZZLE, bool DUAL>
__global__ __launch_bounds__(256, 4) void mfma_gemm(
    const short* __restrict__ A, const short* __restrict__ Bt,
    const float* __restrict__ bias, void* __restrict__ C,
    int M, int N, int K, int lda, int ldb,
    const short* A2, const short* Bt2, void* C2, int nsplit,
    int K2, int lda2, int ldb2, int N2)
{
    __shared__ __align__(16) char smem_raw[32768];   // As 16KB | Bs 16KB
    short* As = (short*)smem_raw;
    short* Bs = As + 128 * 64;

    int bx, by;
    if (SWIZZLE) {
        int nb  = gridDim.x;
        int gid = blockIdx.y * nb + blockIdx.x;
        int xcd = gid & 7;
        int j   = gid >> 3;
        int rows_per = gridDim.y >> 3;
        int lr  = j / nb;
        bx = j - lr * nb;
        by = xcd * rows_per + lr;
    } else {
        bx = blockIdx.x; by = blockIdx.y;
    }
    if (DUAL && bx >= nsplit) {
        bx -= nsplit; A = A2; Bt = Bt2; C = C2;
        K = K2; lda = lda2; ldb = ldb2; N = N2;
    }
    if (by * 128 >= M) return;                      // padded tail

    const int tid  = threadIdx.x;
    const int wave = tid >> 6;
    const int lane = tid & 63;
    const int m0 = by * 128;
    const int n0 = bx * 128;
    const int wm = (wave & 1) * 64;
    const int wn = (wave >> 1) * 64;

    f32x4 acc[4][4] = {};

    const int q  = lane >> 4;
    const int lm = lane & 15;

    for (int k0 = 0; k0 < K; k0 += 64) {
#pragma unroll
        for (int it = 0; it < 4; ++it) {
            int c    = (it & 1) * 256 + tid;
            int half = it >> 1;
            int row  = c >> 2;
            int kk   = (c & 3) * 8 + half * 32;
            int ldsc = half * 4096 + ((it & 1) * 256 + wave * 64) * 8;
            int gm = m0 + row; if (gm >= M) gm = M - 1;
            load16_lds(A + (size_t)gm * lda + k0 + kk, As + ldsc);
            int gn = n0 + row;                       // N%128==0: no tail
            load16_lds(Bt + (size_t)gn * ldb + k0 + kk, Bs + ldsc);
        }
        __syncthreads();

#pragma unroll
        for (int half = 0; half < 2; ++half) {
            const short* Ah = As + half * 4096;
            const short* Bh = Bs + half * 4096;
            bf16x8 af[4], bfr[4];
#pragma unroll
            for (int t = 0; t < 4; ++t) {
                af[t]  = *(const bf16x8*)(Ah + (wm + t * 16 + lm) * 32 + q * 8);
                bfr[t] = *(const bf16x8*)(Bh + (wn + t * 16 + lm) * 32 + q * 8);
            }
#pragma unroll
            for (int tm = 0; tm < 4; ++tm)
#pragma unroll
                for (int tn = 0; tn < 4; ++tn)
                    acc[tm][tn] = MFMA16(af[tm], bfr[tn], acc[tm][tn], 0, 0, 0);
        }
        __syncthreads();
    }

    // C/D layout: col=lane&15, row=(lane>>4)*4+reg (m89-verified)
    if (OUTBF16) {
        float* scratch = (float*)smem_raw + wave * (16 * 68);
#pragma unroll
        for (int tm = 0; tm < 4; ++tm) {
            __syncthreads();
#pragma unroll
            for (int tn = 0; tn < 4; ++tn) {
                float bv = BIAS ? bias[n0 + wn + tn * 16 + lm] : 0.0f;
#pragma unroll
                for (int r = 0; r < 4; ++r) {
                    float v = acc[tm][tn][r] + bv;
                    if (RELU) v = fmaxf(v, 0.0f);
                    scratch[(q * 4 + r) * 68 + tn * 16 + lm] = v;
                }
            }
            __syncthreads();
#pragma unroll
            for (int p = 0; p < 2; ++p) {
                int row16 = (lane >> 3) + p * 8;
                int c0 = (lane & 7) * 8;
                float4 v0 = *(float4*)&scratch[row16 * 68 + c0];
                float4 v1 = *(float4*)&scratch[row16 * 68 + c0 + 4];
                bf16x8 o;
                o[0] = f2bf(v0.x); o[1] = f2bf(v0.y); o[2] = f2bf(v0.z); o[3] = f2bf(v0.w);
                o[4] = f2bf(v1.x); o[5] = f2bf(v1.y); o[6] = f2bf(v1.z); o[7] = f2bf(v1.w);
                int grow = m0 + wm + tm * 16 + row16;
                if (grow < M)
                    *(bf16x8*)((short*)C + (size_t)grow * N + n0 + wn + c0) = o;
            }
        }
    } else {
#pragma unroll
        for (int tm = 0; tm < 4; ++tm)
#pragma unroll
            for (int tn = 0; tn < 4; ++tn) {
                int col = n0 + wn + tn * 16 + lm;
#pragma unroll
                for (int r = 0; r < 4; ++r) {
                    int row = m0 + wm + tm * 16 + q * 4 + r;
                    if (row < M) {
                        float v = acc[tm][tn][r];
                        if (BIAS) v += bias[col];
                        if (RELU) v = fmaxf(v, 0.0f);
                        ((float*)C)[(size_t)row * N + col] = v;
                    }
                }
            }
    }
}

// ---------------------------------------------------------------------------
// R19: fused h2 GEMM, v3 — software pipeline. R17 measured latency-bound
// (MfmaUtil 25%, VALUBusy 29%, both pipes idle): the serial chain was
// UV-load -> pack -> syncthreads(vmcnt0 drain) -> MFMA. Changes:
//  - UV(t+1) prefetched into registers during iter t (issued after pack(t),
//    so the ~600cy MFMA section hides the L2 latency).
//  - barrier1 = raw s_barrier with s_waitcnt vmcnt(8) lgkmcnt(0): the 8
//    oldest VM ops are exactly the B-side global_load_lds (order pinned by
//    sched_barrier(0) right after the B-stage issue), so B staging is
//    complete at the barrier while the 8 UV prefetch loads stay in flight.
//  - barrier2 stays __syncthreads: its full drain lands after MFMA, when
//    the prefetch is complete anyway.
// Race audit: every wave does vmcnt(8)+lgkm(0) before barrier1 => all LDS
// staging visible before any wave's MFMA ds_reads; pack(t) reads regs that
// barrier2(t-1)'s drain already completed; ds_writes of pack(t) hit As only
// after barrier2(t-1) (program order, barrier = fence).
// ---------------------------------------------------------------------------
__device__ __forceinline__ unsigned cvtpk(float lo, float hi) {
    unsigned r;
    asm("v_cvt_pk_bf16_f32 %0, %1, %2" : "=v"(r) : "v"(lo), "v"(hi));
    return r;
}
__device__ __forceinline__ bf16x8 addrelu_pack(bf16x8 u, bf16x8 v) {
    float f[8];
#pragma unroll
    for (int e = 0; e < 8; ++e)
        f[e] = fmaxf(bf2f(u[e]) + bf2f(v[e]), 0.0f);
    union { unsigned w[4]; bf16x8 o; } r;
#pragma unroll
    for (int j = 0; j < 4; ++j)
        r.w[j] = cvtpk(f[2 * j], f[2 * j + 1]);
    return r.o;
}

__global__ __launch_bounds__(256, 2) void gemm_h2f(
    const short* __restrict__ UV,
    const int* __restrict__ sids, const int* __restrict__ oids,
    const short* __restrict__ Bt, const float* __restrict__ bias,
    short* __restrict__ C, int M, int rowbase)
{
    __shared__ __align__(16) char smem_raw[49152];   // As 16KB | Bs 32KB
    short* As = (short*)smem_raw;
    short* Bs = As + 128 * 64;

    int nb  = gridDim.x;                             // 4
    int gid = blockIdx.y * nb + blockIdx.x;
    int xcd = gid & 7;
    int j   = gid >> 3;
    int rows_per = gridDim.y >> 3;
    int lr  = j / nb;
    int bx = j - lr * nb;
    int by = xcd * rows_per + lr;
    if (by * 128 >= M) return;

    const int tid  = threadIdx.x;
    const int wave = tid >> 6;
    const int lane = tid & 63;
    const int m0 = by * 128;
    const int n0 = bx * 256;
    const int wm   = (wave & 1) * 64;                // M-half
    const int wsub = wave >> 1;                      // which 128-col subtile

    // fused-A setup: thread owns tile rows (tid>>2), (tid>>2)+64 at k-chunk
    // cq = tid&3 (kk = cq*8 and cq*8+32 per 64-wide K-step).
    const int cq = tid & 3;
    int lr0 = m0 + (tid >> 2); if (lr0 >= M) lr0 = M - 1;
    int lr1 = lr0 + 64;        if (lr1 >= M) lr1 = M - 1;
    int rg0 = rowbase + lr0, rg1 = rowbase + lr1;
    int b0 = rg0 / PAIRS, p0 = rg0 - b0 * PAIRS;
    int b1 = rg1 / PAIRS, p1 = rg1 - b1 * PAIRS;
    const short* u0 = UV + (size_t)(b0 * NDET + sids[p0]) * 2048;
    const short* v0 = UV + (size_t)(b0 * NDET + oids[p0]) * 2048 + 1024;
    const short* u1 = UV + (size_t)(b1 * NDET + sids[p1]) * 2048;
    const short* v1 = UV + (size_t)(b1 * NDET + oids[p1]) * 2048 + 1024;

    f32x4 acc[4][8] = {};
    const int q  = lane >> 4;
    const int lm = lane & 15;

    // UV register double-buffer (named scalars; rotation copies SSA-renamed
    // away by the compiler). Prologue: load UV(0).
    int ka0 = cq * 8;
    bf16x8 ua0 = *(const bf16x8*)(u0 + ka0),      va0 = *(const bf16x8*)(v0 + ka0);
    bf16x8 ua1 = *(const bf16x8*)(u1 + ka0),      va1 = *(const bf16x8*)(v1 + ka0);
    bf16x8 ub0 = *(const bf16x8*)(u0 + ka0 + 32), vb0 = *(const bf16x8*)(v0 + ka0 + 32);
    bf16x8 ub1 = *(const bf16x8*)(u1 + ka0 + 32), vb1 = *(const bf16x8*)(v1 + ka0 + 32);

    for (int k0 = 0; k0 < DH; k0 += 64) {
        // ---- B staging: two 128x64 subtiles, 4x load16_lds each ----
#pragma unroll
        for (int sub = 0; sub < 2; ++sub)
#pragma unroll
            for (int it = 0; it < 4; ++it) {
                int c    = (it & 1) * 256 + tid;
                int half = it >> 1;
                int row  = c >> 2;
                int kk   = (c & 3) * 8 + half * 32;
                int ldsc = sub * 8192 + half * 4096 + ((it & 1) * 256 + wave * 64) * 8;
                load16_lds(Bt + (size_t)(n0 + sub * 128 + row) * DH + k0 + kk,
                           Bs + ldsc);
            }
        // pin: all 8 B-stage VM ops issue BEFORE anything below (vmcnt order)
        __builtin_amdgcn_sched_barrier(0);

        // ---- A pack from current UV regs (drained by prev barrier2) ----
        *(bf16x8*)(As + tid * 8)                = addrelu_pack(ua0, va0);
        *(bf16x8*)(As + (256 + tid) * 8)        = addrelu_pack(ua1, va1);
        *(bf16x8*)(As + 4096 + tid * 8)         = addrelu_pack(ub0, vb0);
        *(bf16x8*)(As + 4096 + (256 + tid) * 8) = addrelu_pack(ub1, vb1);

        // ---- UV prefetch for t+1 (8 VM ops, youngest; stay in flight
        //      across barrier1; last iter reads u-row tail = harmless) ----
        int ka = k0 + 64 + cq * 8;
        bf16x8 nua0 = *(const bf16x8*)(u0 + ka),      nva0 = *(const bf16x8*)(v0 + ka);
        bf16x8 nua1 = *(const bf16x8*)(u1 + ka),      nva1 = *(const bf16x8*)(v1 + ka);
        bf16x8 nub0 = *(const bf16x8*)(u0 + ka + 32), nvb0 = *(const bf16x8*)(v0 + ka + 32);
        bf16x8 nub1 = *(const bf16x8*)(u1 + ka + 32), nvb1 = *(const bf16x8*)(v1 + ka + 32);

        // ---- barrier1: B staging + A ds_writes visible; UV still flying ----
        asm volatile("s_waitcnt vmcnt(8) lgkmcnt(0)" ::: "memory");
        __builtin_amdgcn_sched_barrier(0);
        __builtin_amdgcn_s_barrier();

        // ---- MFMA section ----
#pragma unroll
        for (int half = 0; half < 2; ++half) {
            const short* Ah = As + half * 4096;
            const short* Bh = Bs + wsub * 8192 + half * 4096;
            bf16x8 af[4], bfr[8];
#pragma unroll
            for (int t = 0; t < 4; ++t)
                af[t] = *(const bf16x8*)(Ah + (wm + t * 16 + lm) * 32 + q * 8);
#pragma unroll
            for (int t = 0; t < 8; ++t)
                bfr[t] = *(const bf16x8*)(Bh + (t * 16 + lm) * 32 + q * 8);
#pragma unroll
            for (int tm = 0; tm < 4; ++tm)
#pragma unroll
                for (int tn = 0; tn < 8; ++tn)
                    acc[tm][tn] = MFMA16(af[tm], bfr[tn], acc[tm][tn], 0, 0, 0);
        }
        // ---- barrier2: full drain (UV prefetch done by now — it had the
        //      whole MFMA section to complete) ----
        __syncthreads();

        // rotate UV double-buffer
        ua0 = nua0; va0 = nva0; ua1 = nua1; va1 = nva1;
        ub0 = nub0; vb0 = nvb0; ub1 = nub1; vb1 = nvb1;
    }

    // epilogue: bias+relu, bf16 out. Per-wave scratch 16 x 132 floats.
    float* scratch = (float*)smem_raw + wave * (16 * 132);
    const int csub = n0 + wsub * 128;
#pragma unroll
    for (int tm = 0; tm < 4; ++tm) {
        __syncthreads();
#pragma unroll
        for (int tn = 0; tn < 8; ++tn) {
            float bv = bias[csub + tn * 16 + lm];
#pragma unroll
            for (int r = 0; r < 4; ++r) {
                float v = fmaxf(acc[tm][tn][r] + bv, 0.0f);
                scratch[(q * 4 + r) * 132 + tn * 16 + lm] = v;
            }
        }
        __syncthreads();
#pragma unroll
        for (int p = 0; p < 2; ++p) {
            int row16 = (lane >> 3) + p * 8;
            int grow  = m0 + wm + tm * 16 + row16;
            if (grow >= M) continue;
#pragma unroll
            for (int cc = 0; cc < 2; ++cc) {
                int c0 = (lane & 7) * 16 + cc * 8;
                float4 x0 = *(float4*)&scratch[row16 * 132 + c0];
                float4 x1 = *(float4*)&scratch[row16 * 132 + c0 + 4];
                bf16x8 o;
                o[0] = f2bf(x0.x); o[1] = f2bf(x0.y); o[2] = f2bf(x0.z); o[3] = f2bf(x0.w);
                o[4] = f2bf(x1.x); o[5] = f2bf(x1.y); o[6] = f2bf(x1.z); o[7] = f2bf(x1.w);
                *(bf16x8*)(C + (size_t)grow * DH + csub + c0) = o;
            }
        }
    }
}

// ---------------------------------------------------------------------------
// Multi-job GEMM (up to 4 independent bf16-out jobs, flat 1-D grid).
// ---------------------------------------------------------------------------
struct GemmJobs {
    const short* A[4]; const short* Bt[4]; short* C[4];
    int M[4], N[4], K[4], lda[4], ldb[4];
    int cum[5];
};

__global__ __launch_bounds__(256, 4) void mfma_gemm_multi(GemmJobs jobs)
{
    __shared__ __align__(16) char smem_raw[32768];
    short* As = (short*)smem_raw;
    short* Bs = As + 128 * 64;

    int bid = blockIdx.x;
    int j = 0;
    while (bid >= jobs.cum[j + 1]) ++j;             // <=4, block-uniform
    int lt = bid - jobs.cum[j];
    const short* A  = jobs.A[j];
    const short* Bt = jobs.Bt[j];
    short* C = jobs.C[j];
    int M = jobs.M[j], N = jobs.N[j], K = jobs.K[j];
    int lda = jobs.lda[j], ldb = jobs.ldb[j];
    int ncols = N >> 7;
    int by = lt / ncols;
    int bx = lt - by * ncols;

    const int tid  = threadIdx.x;
    const int wave = tid >> 6;
    const int lane = tid & 63;
    const int m0 = by * 128;
    const int n0 = bx * 128;
    const int wm = (wave & 1) * 64;
    const int wn = (wave >> 1) * 64;

    f32x4 acc[4][4] = {};
    const int q  = lane >> 4;
    const int lm = lane & 15;

    for (int k0 = 0; k0 < K; k0 += 64) {
#pragma unroll
        for (int it = 0; it < 4; ++it) {
            int c    = (it & 1) * 256 + tid;
            int half = it >> 1;
            int row  = c >> 2;
            int kk   = (c & 3) * 8 + half * 32;
            int ldsc = half * 4096 + ((it & 1) * 256 + wave * 64) * 8;
            int gm = m0 + row; if (gm >= M) gm = M - 1;
            load16_lds(A + (size_t)gm * lda + k0 + kk, As + ldsc);
            load16_lds(Bt + (size_t)(n0 + row) * ldb + k0 + kk, Bs + ldsc);
        }
        __syncthreads();
#pragma unroll
        for (int half = 0; half < 2; ++half) {
            const short* Ah = As + half * 4096;
            const short* Bh = Bs + half * 4096;
            bf16x8 af[4], bfr[4];
#pragma unroll
            for (int t = 0; t < 4; ++t) {
                af[t]  = *(const bf16x8*)(Ah + (wm + t * 16 + lm) * 32 + q * 8);
                bfr[t] = *(const bf16x8*)(Bh + (wn + t * 16 + lm) * 32 + q * 8);
            }
#pragma unroll
            for (int tm = 0; tm < 4; ++tm)
#pragma unroll
                for (int tn = 0; tn < 4; ++tn)
                    acc[tm][tn] = MFMA16(af[tm], bfr[tn], acc[tm][tn], 0, 0, 0);
        }
        __syncthreads();
    }

    float* scratch = (float*)smem_raw + wave * (16 * 68);
#pragma unroll
    for (int tm = 0; tm < 4; ++tm) {
        __syncthreads();
#pragma unroll
        for (int tn = 0; tn < 4; ++tn)
#pragma unroll
            for (int r = 0; r < 4; ++r)
                scratch[(q * 4 + r) * 68 + tn * 16 + lm] = acc[tm][tn][r];
        __syncthreads();
#pragma unroll
        for (int p = 0; p < 2; ++p) {
            int row16 = (lane >> 3) + p * 8;
            int c0 = (lane & 7) * 8;
            float4 v0 = *(float4*)&scratch[row16 * 68 + c0];
            float4 v1 = *(float4*)&scratch[row16 * 68 + c0 + 4];
            bf16x8 o;
            o[0] = f2bf(v0.x); o[1] = f2bf(v0.y); o[2] = f2bf(v0.z); o[3] = f2bf(v0.w);
            o[4] = f2bf(v1.x); o[5] = f2bf(v1.y); o[6] = f2bf(v1.z); o[7] = f2bf(v1.w);
            int grow = m0 + wm + tm * 16 + row16;
            if (grow < M)
                *(bf16x8*)(C + (size_t)grow * N + n0 + wn + c0) = o;
        }
    }
}

// ---------------------------------------------------------------------------
// UV merge (in-place): UVa = UVa + UVb + b1 (U-half cols only).
// ---------------------------------------------------------------------------
constexpr int N4UV = BSZ * NDET * 2048 / 4;   // 393216 short4s
__global__ __launch_bounds__(256) void uvmerge_kernel(
    short* __restrict__ UVa, const short* __restrict__ UVb,
    const float* __restrict__ b1)
{
    int i = blockIdx.x * 256 + threadIdx.x;
    if (i >= N4UV) return;
    short4 a = ((const short4*)UVa)[i];
    short4 b = ((const short4*)UVb)[i];
    int col4 = i & 511;
    float4 bb = {0.0f, 0.0f, 0.0f, 0.0f};
    if (col4 < 256) bb = ((const float4*)b1)[col4];
    short4 o;
    o.x = f2bf(bf2f(a.x) + bf2f(b.x) + bb.x);
    o.y = f2bf(bf2f(a.y) + bf2f(b.y) + bb.y);
    o.z = f2bf(bf2f(a.z) + bf2f(b.z) + bb.z);
    o.w = f2bf(bf2f(a.w) + bf2f(b.w) + bb.w);
    ((short4*)UVa)[i] = o;
}

// ---------------------------------------------------------------------------
// rh only (h1 fused into gemm_h2f): wave-per-row R1 matvec.
// ---------------------------------------------------------------------------
__global__ __launch_bounds__(256) void rh_kernel(
    const float* __restrict__ rp, const float* __restrict__ R1,
    const float* __restrict__ rb1, short* __restrict__ rh, int b0)
{
    int wave = threadIdx.x >> 6, lane = threadIdx.x & 63;
    int r = blockIdx.x * 4 + wave;
    int rg = b0 * PAIRS + r;

    const float* rowp = rp + (size_t)rg * 12;
    float4 acc = ((const float4*)rb1)[lane];
#pragma unroll
    for (int k = 0; k < 12; ++k) {
        float rv = rowp[k];
        float4 w = ((const float4*)(R1 + k * 256))[lane];
        acc.x = fmaf(rv, w.x, acc.x);
        acc.y = fmaf(rv, w.y, acc.y);
        acc.z = fmaf(rv, w.z, acc.z);
        acc.w = fmaf(rv, w.w, acc.w);
    }
    short4 o;
    o.x = f2bf(fmaxf(acc.x, 0.0f));
    o.y = f2bf(fmaxf(acc.y, 0.0f));
    o.z = f2bf(fmaxf(acc.z, 0.0f));
    o.w = f2bf(fmaxf(acc.w, 0.0f));
    ((short4*)(rh + (size_t)r * 256))[lane] = o;
}

// ---------------------------------------------------------------------------
// Fused row_prep + focal: wave-per-row (logits from extended GEMM columns;
// ||comb||^2 = 2 + 2*rho/(||so||*||re||)).
// ---------------------------------------------------------------------------
__global__ __launch_bounds__(256) void rowprep_focal_kernel(
    const short* __restrict__ so_ext, const short* __restrict__ re_ext,
    const float* __restrict__ traj, const float* __restrict__ temperature,
    const int* __restrict__ sids, const int* __restrict__ oids,
    const int* __restrict__ labels,
    float4* __restrict__ pn, float* __restrict__ dist_arr, int b0)
{
    int wave = threadIdx.x >> 6, lane = threadIdx.x & 63;
    int r = blockIdx.x * 4 + wave;
    int rg = b0 * PAIRS + r;
    int b = b0 + r / PAIRS;
    int p = r % PAIRS;

    const short* srow = so_ext + (size_t)r * NEXT;
    const short* rrow = re_ext + (size_t)r * NEXT;
    bf16x8 sv = *(const bf16x8*)(srow + lane * 8);
    bf16x8 uv = *(const bf16x8*)(rrow + lane * 8);
    float s[8], u[8];
#pragma unroll
    for (int i = 0; i < 8; ++i) { s[i] = bf2f(sv[i]); u[i] = bf2f(uv[i]); }

    const float* tsrc = (lane < 32)
        ? (traj + (size_t)(b * NDET + sids[p]) * EHALF + lane * 8)
        : (traj + (size_t)(b * NDET + oids[p]) * EHALF + (lane - 32) * 8);
    float4 t0 = ((const float4*)tsrc)[0], t1 = ((const float4*)tsrc)[1];
    float t[8] = {t0.x, t0.y, t0.z, t0.w, t1.x, t1.y, t1.z, t1.w};

    float ss = 0.0f, sr = 0.0f, rho = 0.0f, sd = 0.0f;
#pragma unroll
    for (int i = 0; i < 8; ++i) {
        ss  += s[i] * s[i];
        sr  += u[i] * u[i];
        rho += s[i] * u[i];
        sd  += fabsf(t[i] - s[i]);
    }
#pragma unroll
    for (int m = 1; m < 64; m <<= 1) {
        ss  += __shfl_xor(ss, m);
        sr  += __shfl_xor(sr, m);
        rho += __shfl_xor(rho, m);
        sd  += __shfl_xor(sd, m);
    }
    float inv_s = 1.0f / fmaxf(sqrtf(ss), 1e-12f);
    float inv_r = 1.0f / fmaxf(sqrtf(sr), 1e-12f);
    float ncomb = sqrtf(fmaxf(2.0f + 2.0f * rho * inv_s * inv_r, 0.0f));
    float scale = 1.0f / (fmaxf(ncomb, 1e-12f) * temperature[0]);

    float flp = 0.0f, fln = 0.0f, fm = 0.0f;
    size_t labbase = (size_t)rg * LABW;
#pragma unroll
    for (int h = 0; h < 2; ++h) {
        int c = lane + h * 64;
        if (c < NCLS) {
            float l = (bf2f(srow[DE + c]) * inv_s + bf2f(rrow[DE + c]) * inv_r) * scale;
            int tl = labels[labbase + 1 + c];
            if (tl > 0) fm = 1.0f;
            float tf = (float)tl;
            float pr = 1.0f / (1.0f + expf(-l));
            float lg = log1pf(expf(-fabsf(l)));
            float ce = fmaxf(l, 0.0f) - l * tf + lg;
            float pt = pr * tf + (1.0f - pr) * (1.0f - tf);
            float om = 1.0f - pt;
            float at = 0.25f * tf + 0.75f * (1.0f - tf);
            flp += at * ce * om * om;
            float ce0 = fmaxf(l, 0.0f) + lg;
            fln += 0.75f * ce0 * pr * pr;
        }
    }
#pragma unroll
    for (int m = 1; m < 64; m <<= 1) {
        flp += __shfl_xor(flp, m);
        fln += __shfl_xor(fln, m);
        fm  += __shfl_xor(fm, m);
    }
    if (lane == 0) {
        int posf = (fm > 0.5f) ? 1 : 0;
        int negf = (labels[labbase] > 0) ? 1 : 0;
        pn[rg] = make_float4(posf ? flp : 0.0f, negf ? fln : 0.0f, 0.0f,
                             (float)(posf + 2 * negf));
        dist_arr[rg] = sd;
    }
}

// ---------------------------------------------------------------------------
// Two-stage final reduce.
// ---------------------------------------------------------------------------
struct RedRec { double sp, sn, sd; int cp, cn; };
constexpr int RED1 = 64;
constexpr int ROWS_PER_RED = ROWS / RED1;           // 564

__global__ __launch_bounds__(256) void reduce1_kernel(
    const float4* __restrict__ pn, const float* __restrict__ dist_arr,
    RedRec* __restrict__ scratch)
{
    int tid = threadIdx.x;
    int base = blockIdx.x * ROWS_PER_RED;
    double sp = 0.0, sn = 0.0, sd = 0.0;
    int cp = 0, cn = 0;
    for (int i = tid; i < ROWS_PER_RED; i += 256) {
        float4 v = pn[base + i];
        sp += (double)v.x; sn += (double)v.y; sd += (double)dist_arr[base + i];
        int f = (int)v.w;
        cp += f & 1; cn += (f >> 1) & 1;
    }
    __shared__ double A[256], B[256], C[256];
    __shared__ int I[256], J[256];
    A[tid] = sp; B[tid] = sn; C[tid] = sd; I[tid] = cp; J[tid] = cn;
    __syncthreads();
    for (int st = 128; st > 0; st >>= 1) {
        if (tid < st) { A[tid] += A[tid + st]; B[tid] += B[tid + st]; C[tid] += C[tid + st];
                        I[tid] += I[tid + st]; J[tid] += J[tid + st]; }
        __syncthreads();
    }
    if (tid == 0) {
        RedRec rec; rec.sp = A[0]; rec.sn = B[0]; rec.sd = C[0];
        rec.cp = I[0]; rec.cn = J[0];
        scratch[blockIdx.x] = rec;
    }
}

__global__ __launch_bounds__(64) void reduce2_kernel(
    const RedRec* __restrict__ scratch, float* __restrict__ out)
{
    int lane = threadIdx.x;
    RedRec rec = scratch[lane];
    double sp = rec.sp, sn = rec.sn, sd = rec.sd;
    int cp = rec.cp, cn = rec.cn;
#pragma unroll
    for (int m = 1; m < 64; m <<= 1) {
        sp += __shfl_xor(sp, m);
        sn += __shfl_xor(sn, m);
        sd += __shfl_xor(sd, m);
        cp += __shfl_xor(cp, m);
        cn += __shfl_xor(cn, m);
    }
    if (lane == 0) {
        int cpv = cp < 1 ? 1 : cp;
        int cnv = cn < 1 ? 1 : cn;
        out[0] = (float)(sp / ((double)cpv * NCLS) +
                         sn / ((double)cnv * NCLS) +
                         sd / ((double)ROWS * DE));
    }
}

static inline int pad8(int x) { return (x + 7) & ~7; }

extern "C" void kernel_launch(void* const* d_in, const int* in_sizes, int n_in,
                              void* d_out, int out_size, void* d_ws, size_t ws_size,
                              hipStream_t stream)
{
    const float* det    = (const float*)d_in[0];
    const float* traj   = (const float*)d_in[1];
    const float* relpos = (const float*)d_in[2];
    const float* cw     = (const float*)d_in[3];
    const float* W1     = (const float*)d_in[4];
    const float* b1     = (const float*)d_in[5];
    const float* W2     = (const float*)d_in[6];
    const float* b2     = (const float*)d_in[7];
    const float* W3     = (const float*)d_in[8];
    const float* R1     = (const float*)d_in[9];
    const float* rb1    = (const float*)d_in[10];
    const float* R2     = (const float*)d_in[11];
    const float* temp   = (const float*)d_in[12];
    const int*   labels = (const int*)d_in[13];
    const int*   sids   = (const int*)d_in[14];
    const int*   oids   = (const int*)d_in[15];
    float* out = (float*)d_out;

    // ---- Workspace carve --------------------------------------------------
    char* ws = (char*)d_ws;
    size_t off = 0;
    auto carve = [&](size_t bytes) -> char* {
        char* p = ws + off;
        off = (off + bytes + 255) & ~(size_t)255;
        return p;
    };
    float4* pn       = (float4*)carve((size_t)ROWS * 16);
    float*  dist_arr = (float*)carve((size_t)ROWS * 4);
    short*  det_bf   = (short*)carve((size_t)BSZ * NDET * DF * 2);
    short*  W1t      = (short*)carve((size_t)2048 * 2048 * 2);
    short*  W2t      = (short*)carve((size_t)DH * DH * 2);
    short*  W3t      = (short*)carve((size_t)NEXT * DH * 2);      // [640][1024]
    short*  R2t      = (short*)carve((size_t)NEXT * 256 * 2);     // [640][256]
    short*  cwt      = (short*)carve((size_t)128 * DE * 2);
    short*  W3bf     = (short*)carve((size_t)DH * DE * 2);
    short*  R2bf     = (short*)carve((size_t)256 * DE * 2);
    short*  UVa      = (short*)carve((size_t)BSZ * NDET * 2048 * 2);
    short*  UVb      = (short*)carve((size_t)BSZ * NDET * 2048 * 2);
    RedRec* red_scratch = (RedRec*)carve((size_t)RED1 * sizeof(RedRec));
    size_t fixed_off = off;

    int b_ch = 1;
    for (int cand : {16, 8, 4, 2, 1}) {
        size_t rows  = (size_t)cand * PAIRS;
        size_t bytes = fixed_off + rows * 2048 + 256 + rows * 2048 + 256
                     + rows * 512 + 256 + rows * 1280 + 256;
        if (bytes <= ws_size) { b_ch = cand; break; }
    }
    const int chunk_rows = b_ch * PAIRS;
    const int n_chunks = BSZ / b_ch;
    char* reg1 = carve((size_t)chunk_rows * 2048);
    char* reg2 = carve((size_t)chunk_rows * 2048);
    char* reg3 = carve((size_t)chunk_rows * 512);
    char* reg4 = carve((size_t)chunk_rows * 1280);

    short* h2     = (short*)reg2;
    short* so_ext = (short*)reg1;
    short* rh     = (short*)reg3;
    short* re_ext = (short*)reg4;     // own region (R10 race fix)

    // ---- Prep (1 launch) --------------------------------------------------
    TransJobs tj;
    tj.src[0] = W1;                    tj.dst[0] = W1t;                   tj.K[0] = DF;  tj.N[0] = DH;
    tj.src[1] = W1 + (size_t)DF * DH;  tj.dst[1] = W1t + (size_t)DH * DF; tj.K[1] = DF;  tj.N[1] = DH;
    tj.src[2] = W2;                    tj.dst[2] = W2t;                   tj.K[2] = DH;  tj.N[2] = DH;
    tj.src[3] = W3;                    tj.dst[3] = W3t;                   tj.K[3] = DH;  tj.N[3] = DE;
    tj.src[4] = R2;                    tj.dst[4] = R2t;                   tj.K[4] = 256; tj.N[4] = DE;
    tj.cum[0] = 0;
    for (int i = 0; i < 5; ++i)
        tj.cum[i + 1] = tj.cum[i] + (tj.K[i] / 32) * (tj.N[i] / 32);
    prep_kernel<<<NCONVB + tj.cum[5], 256, 0, stream>>>(
        det, det_bf, cw, cwt, W3, W3bf, R2, R2bf, tj);

    // One multi-job GEMM launch: UV split-K halves + classifier projections.
    GemmJobs gj;
    gj.A[0] = det_bf;        gj.Bt[0] = W1t;        gj.C[0] = UVa;
    gj.M[0] = BSZ * NDET;    gj.N[0] = 2048;        gj.K[0] = 1024;
    gj.lda[0] = 2048;        gj.ldb[0] = 2048;
    gj.A[1] = det_bf + 1024; gj.Bt[1] = W1t + 1024; gj.C[1] = UVb;
    gj.M[1] = BSZ * NDET;    gj.N[1] = 2048;        gj.K[1] = 1024;
    gj.lda[1] = 2048;        gj.ldb[1] = 2048;
    gj.A[2] = cwt;           gj.Bt[2] = W3bf;       gj.C[2] = W3t + (size_t)512 * DH;
    gj.M[2] = 128;           gj.N[2] = 1024;        gj.K[2] = 512;
    gj.lda[2] = 512;         gj.ldb[2] = 512;
    gj.A[3] = cwt;           gj.Bt[3] = R2bf;       gj.C[3] = R2t + (size_t)512 * 256;
    gj.M[3] = 128;           gj.N[3] = 256;         gj.K[3] = 512;
    gj.lda[3] = 512;         gj.ldb[3] = 512;
    gj.cum[0] = 0;
    for (int i = 0; i < 4; ++i)
        gj.cum[i + 1] = gj.cum[i] + (gj.N[i] / 128) * ((gj.M[i] + 127) / 128);
    mfma_gemm_multi<<<gj.cum[4], 256, 0, stream>>>(gj);   // 202 blocks

    // Merge: UVa += UVb + b1 (in-place); must precede gemm_h2f (reads UVa)
    uvmerge_kernel<<<(N4UV + 255) / 256, 256, 0, stream>>>(UVa, UVb, b1);

    const int mg  = (chunk_rows + 127) / 128;
    const int mgp = pad8(mg);

    for (int c = 0; c < n_chunks; ++c) {
        int b0 = c * b_ch;

        rh_kernel<<<chunk_rows / 4, 256, 0, stream>>>(
            relpos, R1, rb1, rh, b0);

        // h2 = bf16(relu(h1 @ W2 + b2)) with h1 = relu(U[s]+V[o]) fused into
        // A-staging, software-pipelined (UV prefetch + counted vmcnt).
        gemm_h2f<<<dim3(DH / 256, mgp), 256, 0, stream>>>(
            UVa, sids, oids, W2t, b2, h2, chunk_rows, b0 * PAIRS);

        // so_ext = bf16(h2 @ [W3 | W3·cw^T]) + re_ext = bf16(rh @ [R2 | R2·cw^T])
        mfma_gemm<false, false, true, true, true>
            <<<dim3(10, mgp), 256, 0, stream>>>(
            h2, W3t, nullptr, so_ext, chunk_rows, NEXT, DH, DH, DH,
            rh, R2t, re_ext, 5, 256, 256, 256, NEXT);

        rowprep_focal_kernel<<<chunk_rows / 4, 256, 0, stream>>>(
            so_ext, re_ext, traj, temp, sids, oids, labels, pn, dist_arr, b0);
    }

    reduce1_kernel<<<RED1, 256, 0, stream>>>(pn, dist_arr, red_scratch);
    reduce2_kernel<<<1, 64, 0, stream>>>(red_scratch, out);
}

// Round 6
// 372.364 us; speedup vs baseline: 1.0677x; 1.0242x over previous
//
#include <hip/hip_runtime.h>
#include <math.h>

// Problem constants
constexpr int BSZ   = 16;
constexpr int NDET  = 48;
constexpr int PAIRS = NDET * (NDET - 1);      // 2256
constexpr int ROWS  = BSZ * PAIRS;            // 36096
constexpr int DF    = 2048;
constexpr int DH    = 1024;
constexpr int DE    = 512;
constexpr int EHALF = 256;
constexpr int NCLS  = 92;
constexpr int NEXT  = DE + 128;               // 640: so/re GEMM width incl. classifier cols
constexpr int LABW  = 1 + 92 + 40;            // 133

typedef __attribute__((ext_vector_type(8))) short bf16x8;   // 8 bf16 in 4 VGPRs
typedef __attribute__((ext_vector_type(4))) float f32x4;

__device__ __forceinline__ short f2bf(float f) {
    union { float f; unsigned u; } a; a.f = f;
    unsigned r = a.u + 0x7fffu + ((a.u >> 16) & 1u);   // RNE
    return (short)(r >> 16);
}
__device__ __forceinline__ float bf2f(short h) {
    union { unsigned u; float f; } x;
    x.u = ((unsigned)(unsigned short)h) << 16;
    return x.f;
}
__device__ __forceinline__ unsigned cvtpk(float lo, float hi) {
    unsigned r;
    asm("v_cvt_pk_bf16_f32 %0, %1, %2" : "=v"(r) : "v"(lo), "v"(hi));
    return r;
}

// ---------------------------------------------------------------------------
// Merged prep. Elementwise ranges: det conv | cwt build | W3->bf16 | R2->bf16;
// then 5-job transpose (W1 top/bot, W2, W3, R2).
// ---------------------------------------------------------------------------
constexpr int N4DET = BSZ * NDET * DF / 4;    // 393216
constexpr int N4CWT = 128 * DE / 4;           // 16384
constexpr int N4W3  = DH * DE / 4;            // 131072
constexpr int N4R2  = 256 * DE / 4;           // 32768
constexpr int NCONVB = (N4DET + N4CWT + N4W3 + N4R2) / 256;   // 2240

struct TransJobs {
    const float* src[5];
    short*       dst[5];
    int K[5], N[5];
    int cum[6];
};

__global__ __launch_bounds__(256) void prep_kernel(
    const float* __restrict__ det, short* __restrict__ det_bf,
    const float* __restrict__ cw, short* __restrict__ cwt,
    const float* __restrict__ W3, short* __restrict__ W3bf,
    const float* __restrict__ R2, short* __restrict__ R2bf,
    TransJobs jobs)
{
    if (blockIdx.x < NCONVB) {
        int i = blockIdx.x * 256 + threadIdx.x;
        const float* src; short* dst; int k;
        if (i < N4DET) { src = det; dst = det_bf; k = i; }
        else if (i < N4DET + N4CWT) {
            k = i - N4DET;
            int n = (k * 4) >> 9;
            short4 o = {0, 0, 0, 0};
            if (n < NCLS) {
                float4 v = ((const float4*)cw)[k];
                o.x = f2bf(v.x); o.y = f2bf(v.y); o.z = f2bf(v.z); o.w = f2bf(v.w);
            }
            ((short4*)cwt)[k] = o;
            return;
        }
        else if (i < N4DET + N4CWT + N4W3) { src = W3; dst = W3bf; k = i - N4DET - N4CWT; }
        else { src = R2; dst = R2bf; k = i - N4DET - N4CWT - N4W3; }
        float4 v = ((const float4*)src)[k];
        short4 o;
        o.x = f2bf(v.x); o.y = f2bf(v.y); o.z = f2bf(v.z); o.w = f2bf(v.w);
        ((short4*)dst)[k] = o;
        return;
    }
    __shared__ float tile[32][33];
    int t = blockIdx.x - NCONVB;
    int j = 0;
    while (t >= jobs.cum[j + 1]) ++j;
    int lt = t - jobs.cum[j];
    int K = jobs.K[j], N = jobs.N[j];
    int nx = N >> 5;
    int ky = lt / nx, nxi = lt - ky * nx;
    int n0 = nxi * 32, k0 = ky * 32;
    const float* src = jobs.src[j];
    short* dst = jobs.dst[j];
    int tx = threadIdx.x & 31, ty = threadIdx.x >> 5;
#pragma unroll
    for (int i = ty; i < 32; i += 8)
        tile[i][tx] = src[(size_t)(k0 + i) * N + n0 + tx];
    __syncthreads();
#pragma unroll
    for (int i = ty; i < 32; i += 8)
        dst[(size_t)(n0 + i) * K + k0 + tx] = f2bf(tile[tx][i]);
}

// ---------------------------------------------------------------------------
// MFMA GEMM (BK=64 as two 128x32 halves; R9/R13-verified 2-phase 128^2
// structure — measured 847 TF on the h2 shape; proven baseline).
// ---------------------------------------------------------------------------
__device__ __forceinline__ void load16_lds(const void* g, void* l) {
    __builtin_amdgcn_global_load_lds(
        (const __attribute__((address_space(1))) unsigned int*)g,
        (__attribute__((address_space(3))) unsigned int*)l, 16, 0, 0);
}

#define MFMA16 __builtin_amdgcn_mfma_f32_16x16x32_bf16

template <bool BIAS, bool RELU, bool OUTBF16, bool SWIZZLE, bool DUAL>
__global__ __launch_bounds__(256, 4) void mfma_gemm(
    const short* __restrict__ A, const short* __restrict__ Bt,
    const float* __restrict__ bias, void* __restrict__ C,
    int M, int N, int K, int lda, int ldb,
    const short* A2, const short* Bt2, void* C2, int nsplit,
    int K2, int lda2, int ldb2, int N2)
{
    __shared__ __align__(16) char smem_raw[32768];   // As 16KB | Bs 16KB
    short* As = (short*)smem_raw;
    short* Bs = As + 128 * 64;

    int bx, by;
    if (SWIZZLE) {
        int nb  = gridDim.x;
        int gid = blockIdx.y * nb + blockIdx.x;
        int xcd = gid & 7;
        int j   = gid >> 3;
        int rows_per = gridDim.y >> 3;
        int lr  = j / nb;
        bx = j - lr * nb;
        by = xcd * rows_per + lr;
    } else {
        bx = blockIdx.x; by = blockIdx.y;
    }
    if (DUAL && bx >= nsplit) {
        bx -= nsplit; A = A2; Bt = Bt2; C = C2;
        K = K2; lda = lda2; ldb = ldb2; N = N2;
    }
    if (by * 128 >= M) return;                      // padded tail

    const int tid  = threadIdx.x;
    const int wave = tid >> 6;
    const int lane = tid & 63;
    const int m0 = by * 128;
    const int n0 = bx * 128;
    const int wm = (wave & 1) * 64;
    const int wn = (wave >> 1) * 64;

    f32x4 acc[4][4] = {};

    const int q  = lane >> 4;
    const int lm = lane & 15;

    for (int k0 = 0; k0 < K; k0 += 64) {
#pragma unroll
        for (int it = 0; it < 4; ++it) {
            int c    = (it & 1) * 256 + tid;
            int half = it >> 1;
            int row  = c >> 2;
            int kk   = (c & 3) * 8 + half * 32;
            int ldsc = half * 4096 + ((it & 1) * 256 + wave * 64) * 8;
            int gm = m0 + row; if (gm >= M) gm = M - 1;
            load16_lds(A + (size_t)gm * lda + k0 + kk, As + ldsc);
            int gn = n0 + row;                       // N%128==0: no tail
            load16_lds(Bt + (size_t)gn * ldb + k0 + kk, Bs + ldsc);
        }
        __syncthreads();

#pragma unroll
        for (int half = 0; half < 2; ++half) {
            const short* Ah = As + half * 4096;
            const short* Bh = Bs + half * 4096;
            bf16x8 af[4], bfr[4];
#pragma unroll
            for (int t = 0; t < 4; ++t) {
                af[t]  = *(const bf16x8*)(Ah + (wm + t * 16 + lm) * 32 + q * 8);
                bfr[t] = *(const bf16x8*)(Bh + (wn + t * 16 + lm) * 32 + q * 8);
            }
#pragma unroll
            for (int tm = 0; tm < 4; ++tm)
#pragma unroll
                for (int tn = 0; tn < 4; ++tn)
                    acc[tm][tn] = MFMA16(af[tm], bfr[tn], acc[tm][tn], 0, 0, 0);
        }
        __syncthreads();
    }

    // C/D layout: col=lane&15, row=(lane>>4)*4+reg (m89-verified)
    if (OUTBF16) {
        float* scratch = (float*)smem_raw + wave * (16 * 68);
#pragma unroll
        for (int tm = 0; tm < 4; ++tm) {
            __syncthreads();
#pragma unroll
            for (int tn = 0; tn < 4; ++tn) {
                float bv = BIAS ? bias[n0 + wn + tn * 16 + lm] : 0.0f;
#pragma unroll
                for (int r = 0; r < 4; ++r) {
                    float v = acc[tm][tn][r] + bv;
                    if (RELU) v = fmaxf(v, 0.0f);
                    scratch[(q * 4 + r) * 68 + tn * 16 + lm] = v;
                }
            }
            __syncthreads();
#pragma unroll
            for (int p = 0; p < 2; ++p) {
                int row16 = (lane >> 3) + p * 8;
                int c0 = (lane & 7) * 8;
                float4 v0 = *(float4*)&scratch[row16 * 68 + c0];
                float4 v1 = *(float4*)&scratch[row16 * 68 + c0 + 4];
                bf16x8 o;
                o[0] = f2bf(v0.x); o[1] = f2bf(v0.y); o[2] = f2bf(v0.z); o[3] = f2bf(v0.w);
                o[4] = f2bf(v1.x); o[5] = f2bf(v1.y); o[6] = f2bf(v1.z); o[7] = f2bf(v1.w);
                int grow = m0 + wm + tm * 16 + row16;
                if (grow < M)
                    *(bf16x8*)((short*)C + (size_t)grow * N + n0 + wn + c0) = o;
            }
        }
    } else {
#pragma unroll
        for (int tm = 0; tm < 4; ++tm)
#pragma unroll
            for (int tn = 0; tn < 4; ++tn) {
                int col = n0 + wn + tn * 16 + lm;
#pragma unroll
                for (int r = 0; r < 4; ++r) {
                    int row = m0 + wm + tm * 16 + q * 4 + r;
                    if (row < M) {
                        float v = acc[tm][tn][r];
                        if (BIAS) v += bias[col];
                        if (RELU) v = fmaxf(v, 0.0f);
                        ((float*)C)[(size_t)row * N + col] = v;
                    }
                }
            }
    }
}

// ---------------------------------------------------------------------------
// Multi-job GEMM (up to 4 independent bf16-out jobs, flat 1-D grid).
// ---------------------------------------------------------------------------
struct GemmJobs {
    const short* A[4]; const short* Bt[4]; short* C[4];
    int M[4], N[4], K[4], lda[4], ldb[4];
    int cum[5];
};

__global__ __launch_bounds__(256, 4) void mfma_gemm_multi(GemmJobs jobs)
{
    __shared__ __align__(16) char smem_raw[32768];
    short* As = (short*)smem_raw;
    short* Bs = As + 128 * 64;

    int bid = blockIdx.x;
    int j = 0;
    while (bid >= jobs.cum[j + 1]) ++j;             // <=4, block-uniform
    int lt = bid - jobs.cum[j];
    const short* A  = jobs.A[j];
    const short* Bt = jobs.Bt[j];
    short* C = jobs.C[j];
    int M = jobs.M[j], N = jobs.N[j], K = jobs.K[j];
    int lda = jobs.lda[j], ldb = jobs.ldb[j];
    int ncols = N >> 7;
    int by = lt / ncols;
    int bx = lt - by * ncols;

    const int tid  = threadIdx.x;
    const int wave = tid >> 6;
    const int lane = tid & 63;
    const int m0 = by * 128;
    const int n0 = bx * 128;
    const int wm = (wave & 1) * 64;
    const int wn = (wave >> 1) * 64;

    f32x4 acc[4][4] = {};
    const int q  = lane >> 4;
    const int lm = lane & 15;

    for (int k0 = 0; k0 < K; k0 += 64) {
#pragma unroll
        for (int it = 0; it < 4; ++it) {
            int c    = (it & 1) * 256 + tid;
            int half = it >> 1;
            int row  = c >> 2;
            int kk   = (c & 3) * 8 + half * 32;
            int ldsc = half * 4096 + ((it & 1) * 256 + wave * 64) * 8;
            int gm = m0 + row; if (gm >= M) gm = M - 1;
            load16_lds(A + (size_t)gm * lda + k0 + kk, As + ldsc);
            load16_lds(Bt + (size_t)(n0 + row) * ldb + k0 + kk, Bs + ldsc);
        }
        __syncthreads();
#pragma unroll
        for (int half = 0; half < 2; ++half) {
            const short* Ah = As + half * 4096;
            const short* Bh = Bs + half * 4096;
            bf16x8 af[4], bfr[4];
#pragma unroll
            for (int t = 0; t < 4; ++t) {
                af[t]  = *(const bf16x8*)(Ah + (wm + t * 16 + lm) * 32 + q * 8);
                bfr[t] = *(const bf16x8*)(Bh + (wn + t * 16 + lm) * 32 + q * 8);
            }
#pragma unroll
            for (int tm = 0; tm < 4; ++tm)
#pragma unroll
                for (int tn = 0; tn < 4; ++tn)
                    acc[tm][tn] = MFMA16(af[tm], bfr[tn], acc[tm][tn], 0, 0, 0);
        }
        __syncthreads();
    }

    float* scratch = (float*)smem_raw + wave * (16 * 68);
#pragma unroll
    for (int tm = 0; tm < 4; ++tm) {
        __syncthreads();
#pragma unroll
        for (int tn = 0; tn < 4; ++tn)
#pragma unroll
            for (int r = 0; r < 4; ++r)
                scratch[(q * 4 + r) * 68 + tn * 16 + lm] = acc[tm][tn][r];
        __syncthreads();
#pragma unroll
        for (int p = 0; p < 2; ++p) {
            int row16 = (lane >> 3) + p * 8;
            int c0 = (lane & 7) * 8;
            float4 v0 = *(float4*)&scratch[row16 * 68 + c0];
            float4 v1 = *(float4*)&scratch[row16 * 68 + c0 + 4];
            bf16x8 o;
            o[0] = f2bf(v0.x); o[1] = f2bf(v0.y); o[2] = f2bf(v0.z); o[3] = f2bf(v0.w);
            o[4] = f2bf(v1.x); o[5] = f2bf(v1.y); o[6] = f2bf(v1.z); o[7] = f2bf(v1.w);
            int grow = m0 + wm + tm * 16 + row16;
            if (grow < M)
                *(bf16x8*)(C + (size_t)grow * N + n0 + wn + c0) = o;
        }
    }
}

// ---------------------------------------------------------------------------
// R20: pairs + rh with UV-merge FOLDED IN. Raw UVa/UVb are read directly
// (both L2/L3-hot, 12 MB total) and b1 (4 KB, L1-broadcast) added inline:
//   h1 = bf16(relu(Ua[s]+Ub[s]+b1 + Va[o]+Vb[o]))   (fp32 accumulate)
// This removes the uvmerge kernel (launch + 18 MB round trip) and one
// intermediate bf16 rounding vs R13. Pack via v_cvt_pk_bf16_f32 (RNE,
// validated bit-identical through R17/R19 passes).
// ---------------------------------------------------------------------------
__global__ __launch_bounds__(256) void pairs_rh_kernel(
    const short* __restrict__ UVa, const short* __restrict__ UVb,
    const float* __restrict__ b1,
    const int* __restrict__ sids, const int* __restrict__ oids,
    short* __restrict__ h1,
    const float* __restrict__ rp, const float* __restrict__ R1,
    const float* __restrict__ rb1, short* __restrict__ rh, int b0)
{
    int wave = threadIdx.x >> 6, lane = threadIdx.x & 63;
    int r = blockIdx.x * 4 + wave;
    int b = b0 + r / PAIRS;
    int p = r % PAIRS;

    size_t srow = (size_t)(b * NDET + sids[p]) * 2048;          // U half
    size_t orow = (size_t)(b * NDET + oids[p]) * 2048 + 1024;   // V half
    const bf16x8* usa = (const bf16x8*)(UVa + srow);
    const bf16x8* usb = (const bf16x8*)(UVb + srow);
    const bf16x8* uoa = (const bf16x8*)(UVa + orow);
    const bf16x8* uob = (const bf16x8*)(UVb + orow);
    bf16x8* hrow = (bf16x8*)(h1 + (size_t)r * DH);
#pragma unroll
    for (int i = 0; i < 2; ++i) {
        int idx = lane + i * 64;            // 128 bf16x8 per 1024-elem row
        bf16x8 a1 = usa[idx], a2 = usb[idx];
        bf16x8 c1 = uoa[idx], c2 = uob[idx];
        float4 bb0 = ((const float4*)b1)[idx * 2];
        float4 bb1 = ((const float4*)b1)[idx * 2 + 1];
        float bv[8] = {bb0.x, bb0.y, bb0.z, bb0.w, bb1.x, bb1.y, bb1.z, bb1.w};
        float f[8];
#pragma unroll
        for (int e = 0; e < 8; ++e)
            f[e] = fmaxf(bf2f(a1[e]) + bf2f(a2[e]) + bv[e]
                         + bf2f(c1[e]) + bf2f(c2[e]), 0.0f);
        union { unsigned w[4]; bf16x8 o; } h;
#pragma unroll
        for (int jj = 0; jj < 4; ++jj)
            h.w[jj] = cvtpk(f[2 * jj], f[2 * jj + 1]);
        hrow[idx] = h.o;
    }

    int rg = b0 * PAIRS + r;
    const float* rowp = rp + (size_t)rg * 12;
    float4 acc = ((const float4*)rb1)[lane];
#pragma unroll
    for (int k = 0; k < 12; ++k) {
        float rv = rowp[k];
        float4 w = ((const float4*)(R1 + k * 256))[lane];
        acc.x = fmaf(rv, w.x, acc.x);
        acc.y = fmaf(rv, w.y, acc.y);
        acc.z = fmaf(rv, w.z, acc.z);
        acc.w = fmaf(rv, w.w, acc.w);
    }
    short4 o;
    o.x = f2bf(fmaxf(acc.x, 0.0f));
    o.y = f2bf(fmaxf(acc.y, 0.0f));
    o.z = f2bf(fmaxf(acc.z, 0.0f));
    o.w = f2bf(fmaxf(acc.w, 0.0f));
    ((short4*)(rh + (size_t)r * 256))[lane] = o;
}

// ---------------------------------------------------------------------------
// Fused row_prep + focal: wave-per-row (logits from extended GEMM columns;
// ||comb||^2 = 2 + 2*rho/(||so||*||re||)).
// ---------------------------------------------------------------------------
__global__ __launch_bounds__(256) void rowprep_focal_kernel(
    const short* __restrict__ so_ext, const short* __restrict__ re_ext,
    const float* __restrict__ traj, const float* __restrict__ temperature,
    const int* __restrict__ sids, const int* __restrict__ oids,
    const int* __restrict__ labels,
    float4* __restrict__ pn, float* __restrict__ dist_arr, int b0)
{
    int wave = threadIdx.x >> 6, lane = threadIdx.x & 63;
    int r = blockIdx.x * 4 + wave;
    int rg = b0 * PAIRS + r;
    int b = b0 + r / PAIRS;
    int p = r % PAIRS;

    const short* srow = so_ext + (size_t)r * NEXT;
    const short* rrow = re_ext + (size_t)r * NEXT;
    bf16x8 sv = *(const bf16x8*)(srow + lane * 8);
    bf16x8 uv = *(const bf16x8*)(rrow + lane * 8);
    float s[8], u[8];
#pragma unroll
    for (int i = 0; i < 8; ++i) { s[i] = bf2f(sv[i]); u[i] = bf2f(uv[i]); }

    const float* tsrc = (lane < 32)
        ? (traj + (size_t)(b * NDET + sids[p]) * EHALF + lane * 8)
        : (traj + (size_t)(b * NDET + oids[p]) * EHALF + (lane - 32) * 8);
    float4 t0 = ((const float4*)tsrc)[0], t1 = ((const float4*)tsrc)[1];
    float t[8] = {t0.x, t0.y, t0.z, t0.w, t1.x, t1.y, t1.z, t1.w};

    float ss = 0.0f, sr = 0.0f, rho = 0.0f, sd = 0.0f;
#pragma unroll
    for (int i = 0; i < 8; ++i) {
        ss  += s[i] * s[i];
        sr  += u[i] * u[i];
        rho += s[i] * u[i];
        sd  += fabsf(t[i] - s[i]);
    }
#pragma unroll
    for (int m = 1; m < 64; m <<= 1) {
        ss  += __shfl_xor(ss, m);
        sr  += __shfl_xor(sr, m);
        rho += __shfl_xor(rho, m);
        sd  += __shfl_xor(sd, m);
    }
    float inv_s = 1.0f / fmaxf(sqrtf(ss), 1e-12f);
    float inv_r = 1.0f / fmaxf(sqrtf(sr), 1e-12f);
    float ncomb = sqrtf(fmaxf(2.0f + 2.0f * rho * inv_s * inv_r, 0.0f));
    float scale = 1.0f / (fmaxf(ncomb, 1e-12f) * temperature[0]);

    float flp = 0.0f, fln = 0.0f, fm = 0.0f;
    size_t labbase = (size_t)rg * LABW;
#pragma unroll
    for (int h = 0; h < 2; ++h) {
        int c = lane + h * 64;
        if (c < NCLS) {
            float l = (bf2f(srow[DE + c]) * inv_s + bf2f(rrow[DE + c]) * inv_r) * scale;
            int tl = labels[labbase + 1 + c];
            if (tl > 0) fm = 1.0f;
            float tf = (float)tl;
            float pr = 1.0f / (1.0f + expf(-l));
            float lg = log1pf(expf(-fabsf(l)));
            float ce = fmaxf(l, 0.0f) - l * tf + lg;
            float pt = pr * tf + (1.0f - pr) * (1.0f - tf);
            float om = 1.0f - pt;
            float at = 0.25f * tf + 0.75f * (1.0f - tf);
            flp += at * ce * om * om;
            float ce0 = fmaxf(l, 0.0f) + lg;
            fln += 0.75f * ce0 * pr * pr;
        }
    }
#pragma unroll
    for (int m = 1; m < 64; m <<= 1) {
        flp += __shfl_xor(flp, m);
        fln += __shfl_xor(fln, m);
        fm  += __shfl_xor(fm, m);
    }
    if (lane == 0) {
        int posf = (fm > 0.5f) ? 1 : 0;
        int negf = (labels[labbase] > 0) ? 1 : 0;
        pn[rg] = make_float4(posf ? flp : 0.0f, negf ? fln : 0.0f, 0.0f,
                             (float)(posf + 2 * negf));
        dist_arr[rg] = sd;
    }
}

// ---------------------------------------------------------------------------
// Two-stage final reduce.
// ---------------------------------------------------------------------------
struct RedRec { double sp, sn, sd; int cp, cn; };
constexpr int RED1 = 64;
constexpr int ROWS_PER_RED = ROWS / RED1;           // 564

__global__ __launch_bounds__(256) void reduce1_kernel(
    const float4* __restrict__ pn, const float* __restrict__ dist_arr,
    RedRec* __restrict__ scratch)
{
    int tid = threadIdx.x;
    int base = blockIdx.x * ROWS_PER_RED;
    double sp = 0.0, sn = 0.0, sd = 0.0;
    int cp = 0, cn = 0;
    for (int i = tid; i < ROWS_PER_RED; i += 256) {
        float4 v = pn[base + i];
        sp += (double)v.x; sn += (double)v.y; sd += (double)dist_arr[base + i];
        int f = (int)v.w;
        cp += f & 1; cn += (f >> 1) & 1;
    }
    __shared__ double A[256], B[256], C[256];
    __shared__ int I[256], J[256];
    A[tid] = sp; B[tid] = sn; C[tid] = sd; I[tid] = cp; J[tid] = cn;
    __syncthreads();
    for (int st = 128; st > 0; st >>= 1) {
        if (tid < st) { A[tid] += A[tid + st]; B[tid] += B[tid + st]; C[tid] += C[tid + st];
                        I[tid] += I[tid + st]; J[tid] += J[tid + st]; }
        __syncthreads();
    }
    if (tid == 0) {
        RedRec rec; rec.sp = A[0]; rec.sn = B[0]; rec.sd = C[0];
        rec.cp = I[0]; rec.cn = J[0];
        scratch[blockIdx.x] = rec;
    }
}

__global__ __launch_bounds__(64) void reduce2_kernel(
    const RedRec* __restrict__ scratch, float* __restrict__ out)
{
    int lane = threadIdx.x;
    RedRec rec = scratch[lane];
    double sp = rec.sp, sn = rec.sn, sd = rec.sd;
    int cp = rec.cp, cn = rec.cn;
#pragma unroll
    for (int m = 1; m < 64; m <<= 1) {
        sp += __shfl_xor(sp, m);
        sn += __shfl_xor(sn, m);
        sd += __shfl_xor(sd, m);
        cp += __shfl_xor(cp, m);
        cn += __shfl_xor(cn, m);
    }
    if (lane == 0) {
        int cpv = cp < 1 ? 1 : cp;
        int cnv = cn < 1 ? 1 : cn;
        out[0] = (float)(sp / ((double)cpv * NCLS) +
                         sn / ((double)cnv * NCLS) +
                         sd / ((double)ROWS * DE));
    }
}

static inline int pad8(int x) { return (x + 7) & ~7; }

extern "C" void kernel_launch(void* const* d_in, const int* in_sizes, int n_in,
                              void* d_out, int out_size, void* d_ws, size_t ws_size,
                              hipStream_t stream)
{
    const float* det    = (const float*)d_in[0];
    const float* traj   = (const float*)d_in[1];
    const float* relpos = (const float*)d_in[2];
    const float* cw     = (const float*)d_in[3];
    const float* W1     = (const float*)d_in[4];
    const float* b1     = (const float*)d_in[5];
    const float* W2     = (const float*)d_in[6];
    const float* b2     = (const float*)d_in[7];
    const float* W3     = (const float*)d_in[8];
    const float* R1     = (const float*)d_in[9];
    const float* rb1    = (const float*)d_in[10];
    const float* R2     = (const float*)d_in[11];
    const float* temp   = (const float*)d_in[12];
    const int*   labels = (const int*)d_in[13];
    const int*   sids   = (const int*)d_in[14];
    const int*   oids   = (const int*)d_in[15];
    float* out = (float*)d_out;

    // ---- Workspace carve --------------------------------------------------
    char* ws = (char*)d_ws;
    size_t off = 0;
    auto carve = [&](size_t bytes) -> char* {
        char* p = ws + off;
        off = (off + bytes + 255) & ~(size_t)255;
        return p;
    };
    float4* pn       = (float4*)carve((size_t)ROWS * 16);
    float*  dist_arr = (float*)carve((size_t)ROWS * 4);
    short*  det_bf   = (short*)carve((size_t)BSZ * NDET * DF * 2);
    short*  W1t      = (short*)carve((size_t)2048 * 2048 * 2);
    short*  W2t      = (short*)carve((size_t)DH * DH * 2);
    short*  W3t      = (short*)carve((size_t)NEXT * DH * 2);      // [640][1024]
    short*  R2t      = (short*)carve((size_t)NEXT * 256 * 2);     // [640][256]
    short*  cwt      = (short*)carve((size_t)128 * DE * 2);
    short*  W3bf     = (short*)carve((size_t)DH * DE * 2);
    short*  R2bf     = (short*)carve((size_t)256 * DE * 2);
    short*  UVa      = (short*)carve((size_t)BSZ * NDET * 2048 * 2);
    short*  UVb      = (short*)carve((size_t)BSZ * NDET * 2048 * 2);
    RedRec* red_scratch = (RedRec*)carve((size_t)RED1 * sizeof(RedRec));
    size_t fixed_off = off;

    int b_ch = 1;
    for (int cand : {16, 8, 4, 2, 1}) {
        size_t rows  = (size_t)cand * PAIRS;
        size_t bytes = fixed_off + rows * 2048 + 256 + rows * 2048 + 256
                     + rows * 512 + 256 + rows * 1280 + 256;
        if (bytes <= ws_size) { b_ch = cand; break; }
    }
    const int chunk_rows = b_ch * PAIRS;
    const int n_chunks = BSZ / b_ch;
    char* reg1 = carve((size_t)chunk_rows * 2048);
    char* reg2 = carve((size_t)chunk_rows * 2048);
    char* reg3 = carve((size_t)chunk_rows * 512);
    char* reg4 = carve((size_t)chunk_rows * 1280);

    short* h1     = (short*)reg1;
    short* h2     = (short*)reg2;
    short* so_ext = (short*)reg1;     // overwrites h1 (dead after h2 GEMM)
    short* rh     = (short*)reg3;
    short* re_ext = (short*)reg4;     // own region (R10 race fix)

    // ---- Prep (1 launch) --------------------------------------------------
    TransJobs tj;
    tj.src[0] = W1;                    tj.dst[0] = W1t;                   tj.K[0] = DF;  tj.N[0] = DH;
    tj.src[1] = W1 + (size_t)DF * DH;  tj.dst[1] = W1t + (size_t)DH * DF; tj.K[1] = DF;  tj.N[1] = DH;
    tj.src[2] = W2;                    tj.dst[2] = W2t;                   tj.K[2] = DH;  tj.N[2] = DH;
    tj.src[3] = W3;                    tj.dst[3] = W3t;                   tj.K[3] = DH;  tj.N[3] = DE;
    tj.src[4] = R2;                    tj.dst[4] = R2t;                   tj.K[4] = 256; tj.N[4] = DE;
    tj.cum[0] = 0;
    for (int i = 0; i < 5; ++i)
        tj.cum[i + 1] = tj.cum[i] + (tj.K[i] / 32) * (tj.N[i] / 32);
    prep_kernel<<<NCONVB + tj.cum[5], 256, 0, stream>>>(
        det, det_bf, cw, cwt, W3, W3bf, R2, R2bf, tj);

    // One multi-job GEMM launch: UV split-K halves + classifier projections.
    GemmJobs gj;
    gj.A[0] = det_bf;        gj.Bt[0] = W1t;        gj.C[0] = UVa;
    gj.M[0] = BSZ * NDET;    gj.N[0] = 2048;        gj.K[0] = 1024;
    gj.lda[0] = 2048;        gj.ldb[0] = 2048;
    gj.A[1] = det_bf + 1024; gj.Bt[1] = W1t + 1024; gj.C[1] = UVb;
    gj.M[1] = BSZ * NDET;    gj.N[1] = 2048;        gj.K[1] = 1024;
    gj.lda[1] = 2048;        gj.ldb[1] = 2048;
    gj.A[2] = cwt;           gj.Bt[2] = W3bf;       gj.C[2] = W3t + (size_t)512 * DH;
    gj.M[2] = 128;           gj.N[2] = 1024;        gj.K[2] = 512;
    gj.lda[2] = 512;         gj.ldb[2] = 512;
    gj.A[3] = cwt;           gj.Bt[3] = R2bf;       gj.C[3] = R2t + (size_t)512 * 256;
    gj.M[3] = 128;           gj.N[3] = 256;         gj.K[3] = 512;
    gj.lda[3] = 512;         gj.ldb[3] = 512;
    gj.cum[0] = 0;
    for (int i = 0; i < 4; ++i)
        gj.cum[i + 1] = gj.cum[i] + (gj.N[i] / 128) * ((gj.M[i] + 127) / 128);
    mfma_gemm_multi<<<gj.cum[4], 256, 0, stream>>>(gj);   // 202 blocks

    const int mg  = (chunk_rows + 127) / 128;
    const int mgp = pad8(mg);

    for (int c = 0; c < n_chunks; ++c) {
        int b0 = c * b_ch;

        // h1 = bf16(relu(Ua[s]+Ub[s]+b1 + Va[o]+Vb[o])) + rh matvec
        // (uvmerge folded in; UVa/UVb read raw)
        pairs_rh_kernel<<<chunk_rows / 4, 256, 0, stream>>>(
            UVa, UVb, b1, sids, oids, h1, relpos, R1, rb1, rh, b0);

        // h2 = bf16(relu(h1 @ W2 + b2))
        mfma_gemm<true, true, true, true, false>
            <<<dim3(DH / 128, mgp), 256, 0, stream>>>(
            h1, W2t, b2, h2, chunk_rows, DH, DH, DH, DH,
            nullptr, nullptr, nullptr, 0, 0, 0, 0, 0);

        // so_ext = bf16(h2 @ [W3 | W3·cw^T]) + re_ext = bf16(rh @ [R2 | R2·cw^T])
        mfma_gemm<false, false, true, true, true>
            <<<dim3(10, mgp), 256, 0, stream>>>(
            h2, W3t, nullptr, so_ext, chunk_rows, NEXT, DH, DH, DH,
            rh, R2t, re_ext, 5, 256, 256, 256, NEXT);

        rowprep_focal_kernel<<<chunk_rows / 4, 256, 0, stream>>>(
            so_ext, re_ext, traj, temp, sids, oids, labels, pn, dist_arr, b0);
    }

    reduce1_kernel<<<RED1, 256, 0, stream>>>(pn, dist_arr, red_scratch);
    reduce2_kernel<<<1, 64, 0, stream>>>(red_scratch, out);
}